// Round 7
// baseline (467.093 us; speedup 1.0000x reference)
//
#include <hip/hip_runtime.h>
#include <math.h>

#define D 64

typedef _Float16 hf;
typedef _Float16 hf2 __attribute__((ext_vector_type(2)));

__device__ inline float fdot2f(hf2 a, hf2 b, float c) {
#if __has_builtin(__builtin_amdgcn_fdot2)
    return __builtin_amdgcn_fdot2(a, b, c, false);
#else
    return (float)a[0] * (float)b[0] + (float)a[1] * (float)b[1] + c;
#endif
}

// ---------------- Kernel 1: per-node linear transforms (fp16 weights, fdot2) ----------------
__global__ __launch_bounds__(512) void node_pre_kernel(
    const float* __restrict__ h,
    const float* __restrict__ W_att,
    const float* __restrict__ W_p,
    const float* __restrict__ W_pp,
    const float* __restrict__ phi_w,
    const float* __restrict__ phi_b,
    const float* __restrict__ fdef_w,
    const float* __restrict__ fdef_b,
    hf* __restrict__ A16,
    hf* __restrict__ P16,
    hf* __restrict__ PP16,
    hf* __restrict__ PHI16,
    hf* __restrict__ s6,
    float* __restrict__ psi,
    int nNodes)
{
    __shared__ hf2 sW2[4][32][D];        // 32 KB
    __shared__ hf  hrowh[8][D];
    __shared__ float sPhib[D];
    __shared__ float sFdef[D];

    const int tid = threadIdx.x;
    const float* Wm[4] = { W_att, W_p, W_pp, phi_w };
    for (int idx = tid; idx < 4 * 32 * D; idx += 512) {
        const int m  = idx >> 11;
        const int k2 = (idx >> 6) & 31;
        const int j  = idx & 63;
        sW2[m][k2][j] = hf2{(hf)Wm[m][(2 * k2) * D + j], (hf)Wm[m][(2 * k2 + 1) * D + j]};
    }
    if (tid < D) { sPhib[tid] = phi_b[tid]; sFdef[tid] = fdef_w[tid]; }
    __syncthreads();
    const float fb = fdef_b[0];

    const int g = tid >> 6;
    const int j = tid & 63;

    for (int n0 = blockIdx.x * 8; n0 < nNodes; n0 += gridDim.x * 8) {
        const int n = n0 + g;
        float hj = 0.f;
        __syncthreads();
        if (n < nNodes) {
            hj = h[(size_t)n * D + j];
            hrowh[g][j] = (hf)hj;
        }
        __syncthreads();
        if (n < nNodes) {
            float a = 0.f, p = 0.f, pp = 0.f, ph = sPhib[j];
            const hf2* hr = (const hf2*)hrowh[g];
            #pragma unroll
            for (int k2 = 0; k2 < 32; ++k2) {
                const hf2 hb = hr[k2];
                a  = fdot2f(sW2[0][k2][j], hb, a);
                p  = fdot2f(sW2[1][k2][j], hb, p);
                pp = fdot2f(sW2[2][k2][j], hb, pp);
                ph = fdot2f(sW2[3][k2][j], hb, ph);
            }
            const size_t base = (size_t)n * D + j;
            A16[base]   = (hf)a;
            P16[base]   = (hf)p;
            PP16[base]  = (hf)pp;
            PHI16[base] = (hf)ph;
            if (j < 8) s6[(size_t)n * 8 + j] = (hf)(j < 6 ? hj : 0.f);
            float ps = hj * sFdef[j];
            #pragma unroll
            for (int off = 32; off >= 1; off >>= 1) ps += __shfl_xor(ps, off, 64);
            if (j == 0) psi[n] = ps + fb;
        }
    }
}

// ---------------- CSR build: dual histogram + rank ----------------
__global__ __launch_bounds__(256) void hist2_kernel(
    const int* __restrict__ srcI, const int* __restrict__ tgtI,
    int* __restrict__ cnt_t, int* __restrict__ cnt_s,
    int* __restrict__ rank_t, int* __restrict__ rank_s, int nEdges)
{
    const int e = blockIdx.x * 256 + threadIdx.x;
    if (e >= nEdges) return;
    rank_t[e] = atomicAdd(&cnt_t[tgtI[e]], 1);
    rank_s[e] = atomicAdd(&cnt_s[srcI[e]], 1);
}

// ---------------- CSR build: dual exclusive scan (one block) ----------------
__global__ __launch_bounds__(1024) void scan2_kernel(
    const int* __restrict__ cnt_t, const int* __restrict__ cnt_s,
    int* __restrict__ rowstart_t, int* __restrict__ rowstart_s,
    int nNodes, int nEdges)
{
    __shared__ int sums[1024];
    const int tid = threadIdx.x;
    const int per = (nNodes + 1023) / 1024;
    for (int pass = 0; pass < 2; ++pass) {
        const int* cnt = pass ? cnt_s : cnt_t;
        int* rs = pass ? rowstart_s : rowstart_t;
        const int beg = tid * per;
        const int end = min(beg + per, nNodes);
        int s = 0;
        for (int i = beg; i < end; ++i) s += cnt[i];
        sums[tid] = s;
        __syncthreads();
        for (int off = 1; off < 1024; off <<= 1) {
            int add = (tid >= off) ? sums[tid - off] : 0;
            __syncthreads();
            sums[tid] += add;
            __syncthreads();
        }
        int run = sums[tid] - s;
        for (int i = beg; i < end; ++i) { rs[i] = run; run += cnt[i]; }
        if (tid == 1023) rs[nNodes] = nEdges;
        __syncthreads();
    }
}

// ---------------- CSR build: dual scatter ----------------
__global__ __launch_bounds__(256) void scatter2_kernel(
    const int* __restrict__ srcI, const int* __restrict__ tgtI,
    const int* __restrict__ rank_t, const int* __restrict__ rank_s,
    const int* __restrict__ rowstart_t, const int* __restrict__ rowstart_s,
    int* __restrict__ src_sorted, int* __restrict__ tgt_sorted, int nEdges)
{
    const int e = blockIdx.x * 256 + threadIdx.x;
    if (e >= nEdges) return;
    const int s = srcI[e];
    const int t = tgtI[e];
    src_sorted[rowstart_t[t] + rank_t[e]] = s;
    tgt_sorted[rowstart_s[s] + rank_s[e]] = t;
}

// ---------------- Pass tgt: score -> alpha_sorted, inv_den. 16-lane group per node. ----------------
__global__ __launch_bounds__(256) void pass_tgt_kernel(
    const int* __restrict__ rowstart_t,
    const int* __restrict__ src_sorted,
    const float* __restrict__ h,
    const hf* __restrict__ A16,
    const hf* __restrict__ s6,
    float* __restrict__ alpha_sorted,
    float* __restrict__ inv_den,
    int nNodes)
{
    const int grp = threadIdx.x >> 4;   // 16 groups per block
    const int l = threadIdx.x & 15;     // 16 lanes per group: dims 4l..4l+3

    for (int n = blockIdx.x * 16 + grp; n < nNodes; n += gridDim.x * 16) {
        const int beg = rowstart_t[n];
        const int end = rowstart_t[n + 1];
        const float4 htv = ((const float4*)(h + (size_t)n * D))[l];
        float aden = 0.f;

        int k = beg;
        for (; k + 1 < end; k += 2) {
            const int sA = src_sorted[k];
            const int sB = src_sorted[k + 1];
            const float2 rA = ((const float2*)(A16 + (size_t)sA * D))[l];
            const float2 rB = ((const float2*)(A16 + (size_t)sB * D))[l];
            float sdA = 0.f, sdB = 0.f;
            if (l < 2) {
                const float2 s6A = ((const float2*)(s6 + (size_t)sA * 8))[l];
                const float2 s6B = ((const float2*)(s6 + (size_t)sB * 8))[l];
                const hf* qa = (const hf*)&s6A;
                const hf* qb = (const hf*)&s6B;
                sdA = (float)qa[0] * htv.x + (float)qa[1] * htv.y
                    + (float)qa[2] * htv.z + (float)qa[3] * htv.w;
                sdB = (float)qb[0] * htv.x + (float)qb[1] * htv.y
                    + (float)qb[2] * htv.z + (float)qb[3] * htv.w;
            }
            const hf* qA = (const hf*)&rA;
            const hf* qB = (const hf*)&rB;
            float a1 = sdA + (float)qA[0] * htv.x + (float)qA[1] * htv.y
                           + (float)qA[2] * htv.z + (float)qA[3] * htv.w;
            float b1 = sdB + (float)qB[0] * htv.x + (float)qB[1] * htv.y
                           + (float)qB[2] * htv.z + (float)qB[3] * htv.w;
            #pragma unroll
            for (int off = 8; off >= 1; off >>= 1) {
                a1 += __shfl_xor(a1, off, 64);
                b1 += __shfl_xor(b1, off, 64);
            }
            if (l == 0) {
                const float anA = __expf(a1);
                const float anB = __expf(b1);
                alpha_sorted[k]     = anA;
                alpha_sorted[k + 1] = anB;
                aden += anA + anB;
            }
        }
        if (k < end) {
            const int s = src_sorted[k];
            const float2 r = ((const float2*)(A16 + (size_t)s * D))[l];
            float sd = 0.f;
            if (l < 2) {
                const float2 s6r = ((const float2*)(s6 + (size_t)s * 8))[l];
                const hf* q = (const hf*)&s6r;
                sd = (float)q[0] * htv.x + (float)q[1] * htv.y
                   + (float)q[2] * htv.z + (float)q[3] * htv.w;
            }
            const hf* q = (const hf*)&r;
            float a1 = sd + (float)q[0] * htv.x + (float)q[1] * htv.y
                          + (float)q[2] * htv.z + (float)q[3] * htv.w;
            #pragma unroll
            for (int off = 8; off >= 1; off >>= 1) a1 += __shfl_xor(a1, off, 64);
            if (l == 0) {
                const float an = __expf(a1);
                alpha_sorted[k] = an;
                aden += an;
            }
        }
        if (l == 0) inv_den[n] = 1.0f / (aden + 1e-9f);
    }
}

// ---------------- Pass src: pair/beta -> w1m. 16-lane group per node. No atomics. ----------------
__global__ __launch_bounds__(256) void pass_src_kernel(
    const int* __restrict__ rowstart_s,
    const int* __restrict__ tgt_sorted,
    const hf* __restrict__ P16,
    const hf* __restrict__ PP16,
    const float* __restrict__ psi,
    float* __restrict__ w1m,
    int nNodes)
{
    const int grp = threadIdx.x >> 4;
    const int l = threadIdx.x & 15;

    for (int n = blockIdx.x * 16 + grp; n < nNodes; n += gridDim.x * 16) {
        const int beg = rowstart_s[n];
        const int end = rowstart_s[n + 1];
        const float2 pr = ((const float2*)(P16 + (size_t)n * D))[l];
        const hf* pq = (const hf*)&pr;
        const float p0 = pq[0], p1 = pq[1], p2 = pq[2], p3 = pq[3];
        float bden = 0.f, ssum = 0.f;

        int k = beg;
        for (; k + 1 < end; k += 2) {
            const int tA = tgt_sorted[k];
            const int tB = tgt_sorted[k + 1];
            const float2 rA = ((const float2*)(PP16 + (size_t)tA * D))[l];
            const float2 rB = ((const float2*)(PP16 + (size_t)tB * D))[l];
            const float psA = psi[tA];
            const float psB = psi[tB];
            const hf* qA = (const hf*)&rA;
            const hf* qB = (const hf*)&rB;
            float a2 = (float)qA[0] * p0 + (float)qA[1] * p1
                     + (float)qA[2] * p2 + (float)qA[3] * p3;
            float b2 = (float)qB[0] * p0 + (float)qB[1] * p1
                     + (float)qB[2] * p2 + (float)qB[3] * p3;
            #pragma unroll
            for (int off = 8; off >= 1; off >>= 1) {
                a2 += __shfl_xor(a2, off, 64);
                b2 += __shfl_xor(b2, off, 64);
            }
            if (l == 0) {
                const float bnA = __expf(a2);
                const float bnB = __expf(b2);
                bden += bnA + bnB;
                ssum += bnA * __expf(-psA) + bnB * __expf(-psB);
            }
        }
        if (k < end) {
            const int t = tgt_sorted[k];
            const float2 r = ((const float2*)(PP16 + (size_t)t * D))[l];
            const float ps = psi[t];
            const hf* q = (const hf*)&r;
            float a2 = (float)q[0] * p0 + (float)q[1] * p1
                     + (float)q[2] * p2 + (float)q[3] * p3;
            #pragma unroll
            for (int off = 8; off >= 1; off >>= 1) a2 += __shfl_xor(a2, off, 64);
            if (l == 0) {
                const float bn = __expf(a2);
                bden += bn;
                ssum += bn * __expf(-ps);
            }
        }
        if (l == 0) {
            const float st = ssum / (bden + 1e-9f);
            const float d = -logf(st + 1e-8f);
            w1m[n] = 1.0f - 1.0f / (1.0f + __expf(-(d - 0.5f)));
        }
    }
}

// ---------------- Node mid: PHIw16 = PHI16 * w1m ----------------
__global__ __launch_bounds__(256) void node_mid_kernel(
    const float* __restrict__ w1m,
    const hf* __restrict__ PHI16,
    hf* __restrict__ PHIw16,
    int nNodes)
{
    const int wav = threadIdx.x >> 6;
    const int lane = threadIdx.x & 63;
    for (int n = blockIdx.x * 4 + wav; n < nNodes; n += gridDim.x * 4) {
        const float w = w1m[n];
        const size_t idx = (size_t)n * D + lane;
        PHIw16[idx] = (hf)((float)PHI16[idx] * w);
    }
}

// ---------------- Fused: gather m_att + final matmuls + relu + residual + LN ----------------
__global__ __launch_bounds__(512) void final_fused_kernel(
    const int* __restrict__ rowstart_t,
    const int* __restrict__ src_sorted,
    const float* __restrict__ alpha_sorted,
    const float* __restrict__ inv_den,
    const hf* __restrict__ PHIw16,
    const float* __restrict__ h,
    const float* __restrict__ W_self_w, const float* __restrict__ W_self_b,
    const float* __restrict__ W_A_w,    const float* __restrict__ W_A_b,
    const float* __restrict__ W_str_w,  const float* __restrict__ W_str_b,
    const float* __restrict__ ln_g,     const float* __restrict__ ln_b,
    float* __restrict__ out,
    int nNodes)
{
    __shared__ hf2 sWs2[32][D];
    __shared__ hf2 sWa2[32][D];
    __shared__ float sWstr[6 * D];
    __shared__ float sBias[D];
    __shared__ float sG[D], sB[D];
    __shared__ hf hrowh[8][D];
    __shared__ hf mrowh[8][D];

    const int tid = threadIdx.x;
    for (int idx = tid; idx < 32 * D; idx += 512) {
        const int k2 = idx >> 6, j = idx & 63;
        sWs2[k2][j] = hf2{(hf)W_self_w[(2 * k2) * D + j], (hf)W_self_w[(2 * k2 + 1) * D + j]};
        sWa2[k2][j] = hf2{(hf)W_A_w[(2 * k2) * D + j],    (hf)W_A_w[(2 * k2 + 1) * D + j]};
    }
    for (int i = tid; i < 6 * D; i += 512) sWstr[i] = W_str_w[i];
    if (tid < D) {
        sBias[tid] = W_self_b[tid] + W_A_b[tid] + W_str_b[tid];
        sG[tid] = ln_g[tid];
        sB[tid] = ln_b[tid];
    }
    __syncthreads();

    const int g = tid >> 6, j = tid & 63;
    for (int n0 = blockIdx.x * 8; n0 < nNodes; n0 += gridDim.x * 8) {
        const int n = n0 + g;
        float hj = 0.f;
        __syncthreads();
        if (n < nNodes) {
            const int beg = rowstart_t[n];
            const int end = rowstart_t[n + 1];
            float acc = 0.f;
            int k = beg;
            for (; k + 7 < end; k += 8) {
                const int s0 = src_sorted[k],     s1 = src_sorted[k + 1];
                const int s2 = src_sorted[k + 2], s3 = src_sorted[k + 3];
                const int s4 = src_sorted[k + 4], s5 = src_sorted[k + 5];
                const int s6i = src_sorted[k + 6], s7 = src_sorted[k + 7];
                const float c0 = alpha_sorted[k],     c1 = alpha_sorted[k + 1];
                const float c2 = alpha_sorted[k + 2], c3 = alpha_sorted[k + 3];
                const float c4 = alpha_sorted[k + 4], c5 = alpha_sorted[k + 5];
                const float c6 = alpha_sorted[k + 6], c7 = alpha_sorted[k + 7];
                const float p0 = (float)PHIw16[(size_t)s0 * D + j];
                const float p1 = (float)PHIw16[(size_t)s1 * D + j];
                const float p2 = (float)PHIw16[(size_t)s2 * D + j];
                const float p3 = (float)PHIw16[(size_t)s3 * D + j];
                const float p4 = (float)PHIw16[(size_t)s4 * D + j];
                const float p5 = (float)PHIw16[(size_t)s5 * D + j];
                const float p6 = (float)PHIw16[(size_t)s6i * D + j];
                const float p7 = (float)PHIw16[(size_t)s7 * D + j];
                acc += c0 * p0 + c1 * p1 + c2 * p2 + c3 * p3
                     + c4 * p4 + c5 * p5 + c6 * p6 + c7 * p7;
            }
            for (; k < end; ++k)
                acc += alpha_sorted[k] * (float)PHIw16[(size_t)src_sorted[k] * D + j];

            hj = h[(size_t)n * D + j];
            hrowh[g][j] = (hf)hj;
            mrowh[g][j] = (hf)(acc * inv_den[n]);
        }
        __syncthreads();
        if (n < nNodes) {
            float acc = sBias[j];
            const hf2* hr = (const hf2*)hrowh[g];
            const hf2* mr = (const hf2*)mrowh[g];
            #pragma unroll
            for (int k2 = 0; k2 < 32; ++k2) {
                acc = fdot2f(sWs2[k2][j], hr[k2], acc);
                acc = fdot2f(sWa2[k2][j], mr[k2], acc);
            }
            #pragma unroll
            for (int k = 0; k < 6; ++k)
                acc += (float)hrowh[g][k] * sWstr[k * D + j];

            float pre = fmaxf(acc, 0.f) + hj;

            float mu = pre;
            #pragma unroll
            for (int off = 32; off >= 1; off >>= 1) mu += __shfl_xor(mu, off, 64);
            mu *= (1.0f / 64.0f);
            const float diff = pre - mu;
            float v = diff * diff;
            #pragma unroll
            for (int off = 32; off >= 1; off >>= 1) v += __shfl_xor(v, off, 64);
            v *= (1.0f / 64.0f);
            out[(size_t)n * D + j] = diff * rsqrtf(v + 1e-5f) * sG[j] + sB[j];
        }
    }
}

extern "C" void kernel_launch(void* const* d_in, const int* in_sizes, int n_in,
                              void* d_out, int out_size, void* d_ws, size_t ws_size,
                              hipStream_t stream) {
    const int* edge       = (const int*)d_in[0];
    const float* h        = (const float*)d_in[1];
    const float* W_att    = (const float*)d_in[2];
    const float* phi_w    = (const float*)d_in[3];
    const float* phi_b    = (const float*)d_in[4];
    const float* W_p      = (const float*)d_in[5];
    const float* W_pp     = (const float*)d_in[6];
    const float* fdef_w   = (const float*)d_in[7];
    const float* fdef_b   = (const float*)d_in[8];
    const float* W_self_w = (const float*)d_in[9];
    const float* W_self_b = (const float*)d_in[10];
    const float* W_A_w    = (const float*)d_in[11];
    const float* W_A_b    = (const float*)d_in[12];
    const float* W_str_w  = (const float*)d_in[13];
    const float* W_str_b  = (const float*)d_in[14];
    const float* ln_g     = (const float*)d_in[15];
    const float* ln_b     = (const float*)d_in[16];

    const int E = in_sizes[0] / 2;
    const int nNodes = in_sizes[1] / D;
    const int* srcI = edge;
    const int* tgtI = edge + E;

    char* ws = (char*)d_ws;
    size_t off = 0;
    auto alloc = [&](size_t bytes) { char* p = ws + off; off = (off + bytes + 255) & ~(size_t)255; return p; };

    int*    cnt_t     = (int*)   alloc((size_t)nNodes * 4);
    int*    cnt_s     = (int*)   alloc((size_t)nNodes * 4);
    const size_t zero_bytes = off;
    hf*     A16       = (hf*)    alloc((size_t)nNodes * D * 2);
    hf*     P16       = (hf*)    alloc((size_t)nNodes * D * 2);
    hf*     PP16      = (hf*)    alloc((size_t)nNodes * D * 2);
    hf*     PHI16     = (hf*)    alloc((size_t)nNodes * D * 2);
    hf*     PHIw16    = (hf*)    alloc((size_t)nNodes * D * 2);
    hf*     s6        = (hf*)    alloc((size_t)nNodes * 8 * 2);
    float*  psi       = (float*) alloc((size_t)nNodes * 4);
    float*  inv_den   = (float*) alloc((size_t)nNodes * 4);
    float*  w1m       = (float*) alloc((size_t)nNodes * 4);
    int*    rank_t    = (int*)   alloc((size_t)E * 4);
    int*    rank_s    = (int*)   alloc((size_t)E * 4);
    int*    rowstart_t= (int*)   alloc(((size_t)nNodes + 1) * 4);
    int*    rowstart_s= (int*)   alloc(((size_t)nNodes + 1) * 4);
    int*    src_sorted= (int*)   alloc((size_t)E * 4);
    int*    tgt_sorted= (int*)   alloc((size_t)E * 4);
    float*  alpha_sorted = (float*)alloc((size_t)E * 4);

    hipMemsetAsync(d_ws, 0, zero_bytes, stream);

    node_pre_kernel<<<2048, 512, 0, stream>>>(
        h, W_att, W_p, W_pp, phi_w, phi_b, fdef_w, fdef_b,
        A16, P16, PP16, PHI16, s6, psi, nNodes);

    hist2_kernel<<<(E + 255) / 256, 256, 0, stream>>>(
        srcI, tgtI, cnt_t, cnt_s, rank_t, rank_s, E);

    scan2_kernel<<<1, 1024, 0, stream>>>(
        cnt_t, cnt_s, rowstart_t, rowstart_s, nNodes, E);

    scatter2_kernel<<<(E + 255) / 256, 256, 0, stream>>>(
        srcI, tgtI, rank_t, rank_s, rowstart_t, rowstart_s,
        src_sorted, tgt_sorted, E);

    pass_tgt_kernel<<<1024, 256, 0, stream>>>(
        rowstart_t, src_sorted, h, A16, s6, alpha_sorted, inv_den, nNodes);

    pass_src_kernel<<<1024, 256, 0, stream>>>(
        rowstart_s, tgt_sorted, P16, PP16, psi, w1m, nNodes);

    node_mid_kernel<<<2048, 256, 0, stream>>>(
        w1m, PHI16, PHIw16, nNodes);

    final_fused_kernel<<<2048, 512, 0, stream>>>(
        rowstart_t, src_sorted, alpha_sorted, inv_den, PHIw16, h,
        W_self_w, W_self_b, W_A_w, W_A_b, W_str_w, W_str_b,
        ln_g, ln_b, (float*)d_out, nNodes);
}

// Round 8
// 326.123 us; speedup vs baseline: 1.4323x; 1.4323x over previous
//
#include <hip/hip_runtime.h>
#include <math.h>

#define D 64
#define SCAN_NB 256   // blocks per scan pass (2 passes: tgt, src)

typedef _Float16 hf;
typedef _Float16 hf2 __attribute__((ext_vector_type(2)));

__device__ inline float fdot2f(hf2 a, hf2 b, float c) {
#if __has_builtin(__builtin_amdgcn_fdot2)
    return __builtin_amdgcn_fdot2(a, b, c, false);
#else
    return (float)a[0] * (float)b[0] + (float)a[1] * (float)b[1] + c;
#endif
}

// ---------------- Kernel 1: per-node linear transforms (fp16 weights, fdot2) ----------------
__global__ __launch_bounds__(512) void node_pre_kernel(
    const float* __restrict__ h,
    const float* __restrict__ W_att,
    const float* __restrict__ W_p,
    const float* __restrict__ W_pp,
    const float* __restrict__ phi_w,
    const float* __restrict__ phi_b,
    const float* __restrict__ fdef_w,
    const float* __restrict__ fdef_b,
    hf* __restrict__ A16,
    hf* __restrict__ P16,
    hf* __restrict__ PP16,
    hf* __restrict__ PHI16,
    hf* __restrict__ s6,
    float* __restrict__ psi,
    int nNodes)
{
    __shared__ hf2 sW2[4][32][D];        // 32 KB
    __shared__ hf  hrowh[8][D];
    __shared__ float sPhib[D];
    __shared__ float sFdef[D];

    const int tid = threadIdx.x;
    const float* Wm[4] = { W_att, W_p, W_pp, phi_w };
    for (int idx = tid; idx < 4 * 32 * D; idx += 512) {
        const int m  = idx >> 11;
        const int k2 = (idx >> 6) & 31;
        const int j  = idx & 63;
        sW2[m][k2][j] = hf2{(hf)Wm[m][(2 * k2) * D + j], (hf)Wm[m][(2 * k2 + 1) * D + j]};
    }
    if (tid < D) { sPhib[tid] = phi_b[tid]; sFdef[tid] = fdef_w[tid]; }
    __syncthreads();
    const float fb = fdef_b[0];

    const int g = tid >> 6;
    const int j = tid & 63;

    for (int n0 = blockIdx.x * 8; n0 < nNodes; n0 += gridDim.x * 8) {
        const int n = n0 + g;
        float hj = 0.f;
        __syncthreads();
        if (n < nNodes) {
            hj = h[(size_t)n * D + j];
            hrowh[g][j] = (hf)hj;
        }
        __syncthreads();
        if (n < nNodes) {
            float a = 0.f, p = 0.f, pp = 0.f, ph = sPhib[j];
            const hf2* hr = (const hf2*)hrowh[g];
            #pragma unroll
            for (int k2 = 0; k2 < 32; ++k2) {
                const hf2 hb = hr[k2];
                a  = fdot2f(sW2[0][k2][j], hb, a);
                p  = fdot2f(sW2[1][k2][j], hb, p);
                pp = fdot2f(sW2[2][k2][j], hb, pp);
                ph = fdot2f(sW2[3][k2][j], hb, ph);
            }
            const size_t base = (size_t)n * D + j;
            A16[base]   = (hf)a;
            P16[base]   = (hf)p;
            PP16[base]  = (hf)pp;
            PHI16[base] = (hf)ph;
            if (j < 8) s6[(size_t)n * 8 + j] = (hf)(j < 6 ? hj : 0.f);
            float ps = hj * sFdef[j];
            #pragma unroll
            for (int off = 32; off >= 1; off >>= 1) ps += __shfl_xor(ps, off, 64);
            if (j == 0) psi[n] = ps + fb;
        }
    }
}

// ---------------- CSR build: dual histogram + rank ----------------
__global__ __launch_bounds__(256) void hist2_kernel(
    const int* __restrict__ srcI, const int* __restrict__ tgtI,
    int* __restrict__ cnt_t, int* __restrict__ cnt_s,
    int* __restrict__ rank_t, int* __restrict__ rank_s, int nEdges)
{
    const int e = blockIdx.x * 256 + threadIdx.x;
    if (e >= nEdges) return;
    rank_t[e] = atomicAdd(&cnt_t[tgtI[e]], 1);
    rank_s[e] = atomicAdd(&cnt_s[srcI[e]], 1);
}

// ---------------- Multi-block scan, step 1: per-block partial sums ----------------
// grid = 2*SCAN_NB blocks; pass = blockIdx.x>>8 (0:tgt, 1:src)
__global__ __launch_bounds__(256) void scan_partial_kernel(
    const int* __restrict__ cnt_t, const int* __restrict__ cnt_s,
    int* __restrict__ bsum, int nNodes)
{
    const int pass = blockIdx.x >> 8;
    const int b = blockIdx.x & (SCAN_NB - 1);
    const int* cnt = pass ? cnt_s : cnt_t;
    const int C = (nNodes + SCAN_NB - 1) / SCAN_NB;
    const int K = (C + 255) / 256;
    const int base = b * C;
    const int lim = min(base + C, nNodes);
    const int tbeg = base + threadIdx.x * K;
    const int tend = min(tbeg + K, lim);
    int tsum = 0;
    for (int i = tbeg; i < tend; ++i) tsum += cnt[i];
    __shared__ int red[256];
    red[threadIdx.x] = tsum;
    __syncthreads();
    for (int off = 128; off >= 1; off >>= 1) {
        if (threadIdx.x < off) red[threadIdx.x] += red[threadIdx.x + off];
        __syncthreads();
    }
    if (threadIdx.x == 0) bsum[pass * SCAN_NB + b] = red[0];
}

// ---------------- Multi-block scan, step 2: scan the 2*SCAN_NB block sums ----------------
__global__ __launch_bounds__(512) void scan_bsum_kernel(int* __restrict__ bsum)
{
    __shared__ int s[2 * SCAN_NB];
    const int tid = threadIdx.x;
    const int orig = bsum[tid];
    s[tid] = orig;
    __syncthreads();
    const int seg = tid & (SCAN_NB - 1);
    for (int off = 1; off < SCAN_NB; off <<= 1) {
        const int add = (seg >= off) ? s[tid - off] : 0;
        __syncthreads();
        s[tid] += add;
        __syncthreads();
    }
    bsum[tid] = s[tid] - orig;   // exclusive prefix within its pass
}

// ---------------- Multi-block scan, step 3: intra-chunk scan + offset -> rowstart ----------------
__global__ __launch_bounds__(256) void scan_final_kernel(
    const int* __restrict__ cnt_t, const int* __restrict__ cnt_s,
    const int* __restrict__ bsum,
    int* __restrict__ rowstart_t, int* __restrict__ rowstart_s,
    int nNodes, int nEdges)
{
    const int pass = blockIdx.x >> 8;
    const int b = blockIdx.x & (SCAN_NB - 1);
    const int* cnt = pass ? cnt_s : cnt_t;
    int* rs = pass ? rowstart_s : rowstart_t;
    const int C = (nNodes + SCAN_NB - 1) / SCAN_NB;
    const int K = (C + 255) / 256;
    const int base = b * C;
    const int lim = min(base + C, nNodes);
    const int tbeg = base + threadIdx.x * K;
    const int tend = min(tbeg + K, lim);
    int tsum = 0;
    for (int i = tbeg; i < tend; ++i) tsum += cnt[i];
    __shared__ int s[256];
    s[threadIdx.x] = tsum;
    __syncthreads();
    for (int off = 1; off < 256; off <<= 1) {
        const int add = (threadIdx.x >= off) ? s[threadIdx.x - off] : 0;
        __syncthreads();
        s[threadIdx.x] += add;
        __syncthreads();
    }
    int run = s[threadIdx.x] - tsum + bsum[pass * SCAN_NB + b];
    for (int i = tbeg; i < tend; ++i) { rs[i] = run; run += cnt[i]; }
    if (blockIdx.x == 0 && threadIdx.x == 0) {
        rowstart_t[nNodes] = nEdges;
        rowstart_s[nNodes] = nEdges;
    }
}

// ---------------- CSR build: dual scatter ----------------
__global__ __launch_bounds__(256) void scatter2_kernel(
    const int* __restrict__ srcI, const int* __restrict__ tgtI,
    const int* __restrict__ rank_t, const int* __restrict__ rank_s,
    const int* __restrict__ rowstart_t, const int* __restrict__ rowstart_s,
    int* __restrict__ src_sorted, int* __restrict__ tgt_sorted, int nEdges)
{
    const int e = blockIdx.x * 256 + threadIdx.x;
    if (e >= nEdges) return;
    const int s = srcI[e];
    const int t = tgtI[e];
    src_sorted[rowstart_t[t] + rank_t[e]] = s;
    tgt_sorted[rowstart_s[s] + rank_s[e]] = t;
}

// ---------------- Pass tgt: score -> alpha_sorted, inv_den. 16-lane group per node. ----------------
__global__ __launch_bounds__(256) void pass_tgt_kernel(
    const int* __restrict__ rowstart_t,
    const int* __restrict__ src_sorted,
    const float* __restrict__ h,
    const hf* __restrict__ A16,
    const hf* __restrict__ s6,
    float* __restrict__ alpha_sorted,
    float* __restrict__ inv_den,
    int nNodes)
{
    const int grp = threadIdx.x >> 4;
    const int l = threadIdx.x & 15;

    for (int n = blockIdx.x * 16 + grp; n < nNodes; n += gridDim.x * 16) {
        const int beg = rowstart_t[n];
        const int end = rowstart_t[n + 1];
        const float4 htv = ((const float4*)(h + (size_t)n * D))[l];
        float aden = 0.f;

        int k = beg;
        for (; k + 1 < end; k += 2) {
            const int sA = src_sorted[k];
            const int sB = src_sorted[k + 1];
            const float2 rA = ((const float2*)(A16 + (size_t)sA * D))[l];
            const float2 rB = ((const float2*)(A16 + (size_t)sB * D))[l];
            float sdA = 0.f, sdB = 0.f;
            if (l < 2) {
                const float2 s6A = ((const float2*)(s6 + (size_t)sA * 8))[l];
                const float2 s6B = ((const float2*)(s6 + (size_t)sB * 8))[l];
                const hf* qa = (const hf*)&s6A;
                const hf* qb = (const hf*)&s6B;
                sdA = (float)qa[0] * htv.x + (float)qa[1] * htv.y
                    + (float)qa[2] * htv.z + (float)qa[3] * htv.w;
                sdB = (float)qb[0] * htv.x + (float)qb[1] * htv.y
                    + (float)qb[2] * htv.z + (float)qb[3] * htv.w;
            }
            const hf* qA = (const hf*)&rA;
            const hf* qB = (const hf*)&rB;
            float a1 = sdA + (float)qA[0] * htv.x + (float)qA[1] * htv.y
                           + (float)qA[2] * htv.z + (float)qA[3] * htv.w;
            float b1 = sdB + (float)qB[0] * htv.x + (float)qB[1] * htv.y
                           + (float)qB[2] * htv.z + (float)qB[3] * htv.w;
            #pragma unroll
            for (int off = 8; off >= 1; off >>= 1) {
                a1 += __shfl_xor(a1, off, 64);
                b1 += __shfl_xor(b1, off, 64);
            }
            if (l == 0) {
                const float anA = __expf(a1);
                const float anB = __expf(b1);
                alpha_sorted[k]     = anA;
                alpha_sorted[k + 1] = anB;
                aden += anA + anB;
            }
        }
        if (k < end) {
            const int s = src_sorted[k];
            const float2 r = ((const float2*)(A16 + (size_t)s * D))[l];
            float sd = 0.f;
            if (l < 2) {
                const float2 s6r = ((const float2*)(s6 + (size_t)s * 8))[l];
                const hf* q = (const hf*)&s6r;
                sd = (float)q[0] * htv.x + (float)q[1] * htv.y
                   + (float)q[2] * htv.z + (float)q[3] * htv.w;
            }
            const hf* q = (const hf*)&r;
            float a1 = sd + (float)q[0] * htv.x + (float)q[1] * htv.y
                          + (float)q[2] * htv.z + (float)q[3] * htv.w;
            #pragma unroll
            for (int off = 8; off >= 1; off >>= 1) a1 += __shfl_xor(a1, off, 64);
            if (l == 0) {
                const float an = __expf(a1);
                alpha_sorted[k] = an;
                aden += an;
            }
        }
        if (l == 0) inv_den[n] = 1.0f / (aden + 1e-9f);
    }
}

// ---------------- Pass src: pair/beta -> w1m. 16-lane group per node. No atomics. ----------------
__global__ __launch_bounds__(256) void pass_src_kernel(
    const int* __restrict__ rowstart_s,
    const int* __restrict__ tgt_sorted,
    const hf* __restrict__ P16,
    const hf* __restrict__ PP16,
    const float* __restrict__ psi,
    float* __restrict__ w1m,
    int nNodes)
{
    const int grp = threadIdx.x >> 4;
    const int l = threadIdx.x & 15;

    for (int n = blockIdx.x * 16 + grp; n < nNodes; n += gridDim.x * 16) {
        const int beg = rowstart_s[n];
        const int end = rowstart_s[n + 1];
        const float2 pr = ((const float2*)(P16 + (size_t)n * D))[l];
        const hf* pq = (const hf*)&pr;
        const float p0 = pq[0], p1 = pq[1], p2 = pq[2], p3 = pq[3];
        float bden = 0.f, ssum = 0.f;

        int k = beg;
        for (; k + 1 < end; k += 2) {
            const int tA = tgt_sorted[k];
            const int tB = tgt_sorted[k + 1];
            const float2 rA = ((const float2*)(PP16 + (size_t)tA * D))[l];
            const float2 rB = ((const float2*)(PP16 + (size_t)tB * D))[l];
            const float psA = psi[tA];
            const float psB = psi[tB];
            const hf* qA = (const hf*)&rA;
            const hf* qB = (const hf*)&rB;
            float a2 = (float)qA[0] * p0 + (float)qA[1] * p1
                     + (float)qA[2] * p2 + (float)qA[3] * p3;
            float b2 = (float)qB[0] * p0 + (float)qB[1] * p1
                     + (float)qB[2] * p2 + (float)qB[3] * p3;
            #pragma unroll
            for (int off = 8; off >= 1; off >>= 1) {
                a2 += __shfl_xor(a2, off, 64);
                b2 += __shfl_xor(b2, off, 64);
            }
            if (l == 0) {
                const float bnA = __expf(a2);
                const float bnB = __expf(b2);
                bden += bnA + bnB;
                ssum += bnA * __expf(-psA) + bnB * __expf(-psB);
            }
        }
        if (k < end) {
            const int t = tgt_sorted[k];
            const float2 r = ((const float2*)(PP16 + (size_t)t * D))[l];
            const float ps = psi[t];
            const hf* q = (const hf*)&r;
            float a2 = (float)q[0] * p0 + (float)q[1] * p1
                     + (float)q[2] * p2 + (float)q[3] * p3;
            #pragma unroll
            for (int off = 8; off >= 1; off >>= 1) a2 += __shfl_xor(a2, off, 64);
            if (l == 0) {
                const float bn = __expf(a2);
                bden += bn;
                ssum += bn * __expf(-ps);
            }
        }
        if (l == 0) {
            const float st = ssum / (bden + 1e-9f);
            const float d = -logf(st + 1e-8f);
            w1m[n] = 1.0f - 1.0f / (1.0f + __expf(-(d - 0.5f)));
        }
    }
}

// ---------------- Node mid: PHIw16 = PHI16 * w1m ----------------
__global__ __launch_bounds__(256) void node_mid_kernel(
    const float* __restrict__ w1m,
    const hf* __restrict__ PHI16,
    hf* __restrict__ PHIw16,
    int nNodes)
{
    const int wav = threadIdx.x >> 6;
    const int lane = threadIdx.x & 63;
    for (int n = blockIdx.x * 4 + wav; n < nNodes; n += gridDim.x * 4) {
        const float w = w1m[n];
        const size_t idx = (size_t)n * D + lane;
        PHIw16[idx] = (hf)((float)PHI16[idx] * w);
    }
}

// ---------------- Fused: gather m_att + final matmuls + relu + residual + LN ----------------
__global__ __launch_bounds__(512) void final_fused_kernel(
    const int* __restrict__ rowstart_t,
    const int* __restrict__ src_sorted,
    const float* __restrict__ alpha_sorted,
    const float* __restrict__ inv_den,
    const hf* __restrict__ PHIw16,
    const float* __restrict__ h,
    const float* __restrict__ W_self_w, const float* __restrict__ W_self_b,
    const float* __restrict__ W_A_w,    const float* __restrict__ W_A_b,
    const float* __restrict__ W_str_w,  const float* __restrict__ W_str_b,
    const float* __restrict__ ln_g,     const float* __restrict__ ln_b,
    float* __restrict__ out,
    int nNodes)
{
    __shared__ hf2 sWs2[32][D];
    __shared__ hf2 sWa2[32][D];
    __shared__ float sWstr[6 * D];
    __shared__ float sBias[D];
    __shared__ float sG[D], sB[D];
    __shared__ hf hrowh[8][D];
    __shared__ hf mrowh[8][D];

    const int tid = threadIdx.x;
    for (int idx = tid; idx < 32 * D; idx += 512) {
        const int k2 = idx >> 6, j = idx & 63;
        sWs2[k2][j] = hf2{(hf)W_self_w[(2 * k2) * D + j], (hf)W_self_w[(2 * k2 + 1) * D + j]};
        sWa2[k2][j] = hf2{(hf)W_A_w[(2 * k2) * D + j],    (hf)W_A_w[(2 * k2 + 1) * D + j]};
    }
    for (int i = tid; i < 6 * D; i += 512) sWstr[i] = W_str_w[i];
    if (tid < D) {
        sBias[tid] = W_self_b[tid] + W_A_b[tid] + W_str_b[tid];
        sG[tid] = ln_g[tid];
        sB[tid] = ln_b[tid];
    }
    __syncthreads();

    const int g = tid >> 6, j = tid & 63;
    for (int n0 = blockIdx.x * 8; n0 < nNodes; n0 += gridDim.x * 8) {
        const int n = n0 + g;
        float hj = 0.f;
        __syncthreads();
        if (n < nNodes) {
            const int beg = rowstart_t[n];
            const int end = rowstart_t[n + 1];
            float acc = 0.f;
            int k = beg;
            for (; k + 7 < end; k += 8) {
                const int s0 = src_sorted[k],     s1 = src_sorted[k + 1];
                const int s2 = src_sorted[k + 2], s3 = src_sorted[k + 3];
                const int s4 = src_sorted[k + 4], s5 = src_sorted[k + 5];
                const int s6i = src_sorted[k + 6], s7 = src_sorted[k + 7];
                const float c0 = alpha_sorted[k],     c1 = alpha_sorted[k + 1];
                const float c2 = alpha_sorted[k + 2], c3 = alpha_sorted[k + 3];
                const float c4 = alpha_sorted[k + 4], c5 = alpha_sorted[k + 5];
                const float c6 = alpha_sorted[k + 6], c7 = alpha_sorted[k + 7];
                const float p0 = (float)PHIw16[(size_t)s0 * D + j];
                const float p1 = (float)PHIw16[(size_t)s1 * D + j];
                const float p2 = (float)PHIw16[(size_t)s2 * D + j];
                const float p3 = (float)PHIw16[(size_t)s3 * D + j];
                const float p4 = (float)PHIw16[(size_t)s4 * D + j];
                const float p5 = (float)PHIw16[(size_t)s5 * D + j];
                const float p6 = (float)PHIw16[(size_t)s6i * D + j];
                const float p7 = (float)PHIw16[(size_t)s7 * D + j];
                acc += c0 * p0 + c1 * p1 + c2 * p2 + c3 * p3
                     + c4 * p4 + c5 * p5 + c6 * p6 + c7 * p7;
            }
            for (; k < end; ++k)
                acc += alpha_sorted[k] * (float)PHIw16[(size_t)src_sorted[k] * D + j];

            hj = h[(size_t)n * D + j];
            hrowh[g][j] = (hf)hj;
            mrowh[g][j] = (hf)(acc * inv_den[n]);
        }
        __syncthreads();
        if (n < nNodes) {
            float acc = sBias[j];
            const hf2* hr = (const hf2*)hrowh[g];
            const hf2* mr = (const hf2*)mrowh[g];
            #pragma unroll
            for (int k2 = 0; k2 < 32; ++k2) {
                acc = fdot2f(sWs2[k2][j], hr[k2], acc);
                acc = fdot2f(sWa2[k2][j], mr[k2], acc);
            }
            #pragma unroll
            for (int k = 0; k < 6; ++k)
                acc += (float)hrowh[g][k] * sWstr[k * D + j];

            float pre = fmaxf(acc, 0.f) + hj;

            float mu = pre;
            #pragma unroll
            for (int off = 32; off >= 1; off >>= 1) mu += __shfl_xor(mu, off, 64);
            mu *= (1.0f / 64.0f);
            const float diff = pre - mu;
            float v = diff * diff;
            #pragma unroll
            for (int off = 32; off >= 1; off >>= 1) v += __shfl_xor(v, off, 64);
            v *= (1.0f / 64.0f);
            out[(size_t)n * D + j] = diff * rsqrtf(v + 1e-5f) * sG[j] + sB[j];
        }
    }
}

extern "C" void kernel_launch(void* const* d_in, const int* in_sizes, int n_in,
                              void* d_out, int out_size, void* d_ws, size_t ws_size,
                              hipStream_t stream) {
    const int* edge       = (const int*)d_in[0];
    const float* h        = (const float*)d_in[1];
    const float* W_att    = (const float*)d_in[2];
    const float* phi_w    = (const float*)d_in[3];
    const float* phi_b    = (const float*)d_in[4];
    const float* W_p      = (const float*)d_in[5];
    const float* W_pp     = (const float*)d_in[6];
    const float* fdef_w   = (const float*)d_in[7];
    const float* fdef_b   = (const float*)d_in[8];
    const float* W_self_w = (const float*)d_in[9];
    const float* W_self_b = (const float*)d_in[10];
    const float* W_A_w    = (const float*)d_in[11];
    const float* W_A_b    = (const float*)d_in[12];
    const float* W_str_w  = (const float*)d_in[13];
    const float* W_str_b  = (const float*)d_in[14];
    const float* ln_g     = (const float*)d_in[15];
    const float* ln_b     = (const float*)d_in[16];

    const int E = in_sizes[0] / 2;
    const int nNodes = in_sizes[1] / D;
    const int* srcI = edge;
    const int* tgtI = edge + E;

    char* ws = (char*)d_ws;
    size_t off = 0;
    auto alloc = [&](size_t bytes) { char* p = ws + off; off = (off + bytes + 255) & ~(size_t)255; return p; };

    int*    cnt_t     = (int*)   alloc((size_t)nNodes * 4);
    int*    cnt_s     = (int*)   alloc((size_t)nNodes * 4);
    const size_t zero_bytes = off;
    hf*     A16       = (hf*)    alloc((size_t)nNodes * D * 2);
    hf*     P16       = (hf*)    alloc((size_t)nNodes * D * 2);
    hf*     PP16      = (hf*)    alloc((size_t)nNodes * D * 2);
    hf*     PHI16     = (hf*)    alloc((size_t)nNodes * D * 2);
    hf*     PHIw16    = (hf*)    alloc((size_t)nNodes * D * 2);
    hf*     s6        = (hf*)    alloc((size_t)nNodes * 8 * 2);
    float*  psi       = (float*) alloc((size_t)nNodes * 4);
    float*  inv_den   = (float*) alloc((size_t)nNodes * 4);
    float*  w1m       = (float*) alloc((size_t)nNodes * 4);
    int*    rank_t    = (int*)   alloc((size_t)E * 4);
    int*    rank_s    = (int*)   alloc((size_t)E * 4);
    int*    rowstart_t= (int*)   alloc(((size_t)nNodes + 1) * 4);
    int*    rowstart_s= (int*)   alloc(((size_t)nNodes + 1) * 4);
    int*    src_sorted= (int*)   alloc((size_t)E * 4);
    int*    tgt_sorted= (int*)   alloc((size_t)E * 4);
    float*  alpha_sorted = (float*)alloc((size_t)E * 4);
    int*    bsum      = (int*)   alloc((size_t)2 * SCAN_NB * 4);

    hipMemsetAsync(d_ws, 0, zero_bytes, stream);

    node_pre_kernel<<<2048, 512, 0, stream>>>(
        h, W_att, W_p, W_pp, phi_w, phi_b, fdef_w, fdef_b,
        A16, P16, PP16, PHI16, s6, psi, nNodes);

    hist2_kernel<<<(E + 255) / 256, 256, 0, stream>>>(
        srcI, tgtI, cnt_t, cnt_s, rank_t, rank_s, E);

    scan_partial_kernel<<<2 * SCAN_NB, 256, 0, stream>>>(cnt_t, cnt_s, bsum, nNodes);
    scan_bsum_kernel<<<1, 2 * SCAN_NB, 0, stream>>>(bsum);
    scan_final_kernel<<<2 * SCAN_NB, 256, 0, stream>>>(
        cnt_t, cnt_s, bsum, rowstart_t, rowstart_s, nNodes, E);

    scatter2_kernel<<<(E + 255) / 256, 256, 0, stream>>>(
        srcI, tgtI, rank_t, rank_s, rowstart_t, rowstart_s,
        src_sorted, tgt_sorted, E);

    pass_tgt_kernel<<<1024, 256, 0, stream>>>(
        rowstart_t, src_sorted, h, A16, s6, alpha_sorted, inv_den, nNodes);

    pass_src_kernel<<<1024, 256, 0, stream>>>(
        rowstart_s, tgt_sorted, P16, PP16, psi, w1m, nNodes);

    node_mid_kernel<<<2048, 256, 0, stream>>>(
        w1m, PHI16, PHIw16, nNodes);

    final_fused_kernel<<<2048, 512, 0, stream>>>(
        rowstart_t, src_sorted, alpha_sorted, inv_den, PHIw16, h,
        W_self_w, W_self_b, W_A_w, W_A_b, W_str_w, W_str_b,
        ln_g, ln_b, (float*)d_out, nNodes);
}

// Round 9
// 265.239 us; speedup vs baseline: 1.7610x; 1.2295x over previous
//
#include <hip/hip_runtime.h>
#include <math.h>

#define D 64
#define SCAN_NB 256   // blocks per scan pass (2 passes: tgt, src)
#define NB_PASS 1024  // blocks per half of pass_both

typedef _Float16 hf;
typedef _Float16 hf2 __attribute__((ext_vector_type(2)));

__device__ inline float fdot2f(hf2 a, hf2 b, float c) {
#if __has_builtin(__builtin_amdgcn_fdot2)
    return __builtin_amdgcn_fdot2(a, b, c, false);
#else
    return (float)a[0] * (float)b[0] + (float)a[1] * (float)b[1] + c;
#endif
}

// ---------------- Kernel 1: per-node linear transforms (fp16 weights, fdot2) ----------------
__global__ __launch_bounds__(512) void node_pre_kernel(
    const float* __restrict__ h,
    const float* __restrict__ W_att,
    const float* __restrict__ W_p,
    const float* __restrict__ W_pp,
    const float* __restrict__ phi_w,
    const float* __restrict__ phi_b,
    const float* __restrict__ fdef_w,
    const float* __restrict__ fdef_b,
    hf* __restrict__ A16,
    hf* __restrict__ P16,
    hf* __restrict__ PP16,
    hf* __restrict__ PHI16,
    hf* __restrict__ s6,
    float* __restrict__ psi,
    int nNodes)
{
    __shared__ hf2 sW2[4][32][D];        // 32 KB
    __shared__ hf  hrowh[8][D];
    __shared__ float sPhib[D];
    __shared__ float sFdef[D];

    const int tid = threadIdx.x;
    const float* Wm[4] = { W_att, W_p, W_pp, phi_w };
    for (int idx = tid; idx < 4 * 32 * D; idx += 512) {
        const int m  = idx >> 11;
        const int k2 = (idx >> 6) & 31;
        const int j  = idx & 63;
        sW2[m][k2][j] = hf2{(hf)Wm[m][(2 * k2) * D + j], (hf)Wm[m][(2 * k2 + 1) * D + j]};
    }
    if (tid < D) { sPhib[tid] = phi_b[tid]; sFdef[tid] = fdef_w[tid]; }
    __syncthreads();
    const float fb = fdef_b[0];

    const int g = tid >> 6;
    const int j = tid & 63;

    for (int n0 = blockIdx.x * 8; n0 < nNodes; n0 += gridDim.x * 8) {
        const int n = n0 + g;
        float hj = 0.f;
        __syncthreads();
        if (n < nNodes) {
            hj = h[(size_t)n * D + j];
            hrowh[g][j] = (hf)hj;
        }
        __syncthreads();
        if (n < nNodes) {
            float a = 0.f, p = 0.f, pp = 0.f, ph = sPhib[j];
            const hf2* hr = (const hf2*)hrowh[g];
            #pragma unroll
            for (int k2 = 0; k2 < 32; ++k2) {
                const hf2 hb = hr[k2];
                a  = fdot2f(sW2[0][k2][j], hb, a);
                p  = fdot2f(sW2[1][k2][j], hb, p);
                pp = fdot2f(sW2[2][k2][j], hb, pp);
                ph = fdot2f(sW2[3][k2][j], hb, ph);
            }
            const size_t base = (size_t)n * D + j;
            A16[base]   = (hf)a;
            P16[base]   = (hf)p;
            PP16[base]  = (hf)pp;
            PHI16[base] = (hf)ph;
            if (j < 8) s6[(size_t)n * 8 + j] = (hf)(j < 6 ? hj : 0.f);
            float ps = hj * sFdef[j];
            #pragma unroll
            for (int off = 32; off >= 1; off >>= 1) ps += __shfl_xor(ps, off, 64);
            if (j == 0) psi[n] = ps + fb;
        }
    }
}

// ---------------- CSR build: dual histogram + rank ----------------
__global__ __launch_bounds__(256) void hist2_kernel(
    const int* __restrict__ srcI, const int* __restrict__ tgtI,
    int* __restrict__ cnt_t, int* __restrict__ cnt_s,
    int* __restrict__ rank_t, int* __restrict__ rank_s, int nEdges)
{
    const int e = blockIdx.x * 256 + threadIdx.x;
    if (e >= nEdges) return;
    rank_t[e] = atomicAdd(&cnt_t[tgtI[e]], 1);
    rank_s[e] = atomicAdd(&cnt_s[srcI[e]], 1);
}

// ---------------- Multi-block scan, step 1: per-block partial sums ----------------
__global__ __launch_bounds__(256) void scan_partial_kernel(
    const int* __restrict__ cnt_t, const int* __restrict__ cnt_s,
    int* __restrict__ bsum, int nNodes)
{
    const int pass = blockIdx.x >> 8;
    const int b = blockIdx.x & (SCAN_NB - 1);
    const int* cnt = pass ? cnt_s : cnt_t;
    const int C = (nNodes + SCAN_NB - 1) / SCAN_NB;
    const int K = (C + 255) / 256;
    const int base = b * C;
    const int lim = min(base + C, nNodes);
    const int tbeg = base + threadIdx.x * K;
    const int tend = min(tbeg + K, lim);
    int tsum = 0;
    for (int i = tbeg; i < tend; ++i) tsum += cnt[i];
    __shared__ int red[256];
    red[threadIdx.x] = tsum;
    __syncthreads();
    for (int off = 128; off >= 1; off >>= 1) {
        if (threadIdx.x < off) red[threadIdx.x] += red[threadIdx.x + off];
        __syncthreads();
    }
    if (threadIdx.x == 0) bsum[pass * SCAN_NB + b] = red[0];
}

// ---------------- Multi-block scan, step 2: scan the 2*SCAN_NB block sums ----------------
__global__ __launch_bounds__(512) void scan_bsum_kernel(int* __restrict__ bsum)
{
    __shared__ int s[2 * SCAN_NB];
    const int tid = threadIdx.x;
    const int orig = bsum[tid];
    s[tid] = orig;
    __syncthreads();
    const int seg = tid & (SCAN_NB - 1);
    for (int off = 1; off < SCAN_NB; off <<= 1) {
        const int add = (seg >= off) ? s[tid - off] : 0;
        __syncthreads();
        s[tid] += add;
        __syncthreads();
    }
    bsum[tid] = s[tid] - orig;
}

// ---------------- Multi-block scan, step 3: intra-chunk scan + offset -> rowstart ----------------
__global__ __launch_bounds__(256) void scan_final_kernel(
    const int* __restrict__ cnt_t, const int* __restrict__ cnt_s,
    const int* __restrict__ bsum,
    int* __restrict__ rowstart_t, int* __restrict__ rowstart_s,
    int nNodes, int nEdges)
{
    const int pass = blockIdx.x >> 8;
    const int b = blockIdx.x & (SCAN_NB - 1);
    const int* cnt = pass ? cnt_s : cnt_t;
    int* rs = pass ? rowstart_s : rowstart_t;
    const int C = (nNodes + SCAN_NB - 1) / SCAN_NB;
    const int K = (C + 255) / 256;
    const int base = b * C;
    const int lim = min(base + C, nNodes);
    const int tbeg = base + threadIdx.x * K;
    const int tend = min(tbeg + K, lim);
    int tsum = 0;
    for (int i = tbeg; i < tend; ++i) tsum += cnt[i];
    __shared__ int s[256];
    s[threadIdx.x] = tsum;
    __syncthreads();
    for (int off = 1; off < 256; off <<= 1) {
        const int add = (threadIdx.x >= off) ? s[threadIdx.x - off] : 0;
        __syncthreads();
        s[threadIdx.x] += add;
        __syncthreads();
    }
    int run = s[threadIdx.x] - tsum + bsum[pass * SCAN_NB + b];
    for (int i = tbeg; i < tend; ++i) { rs[i] = run; run += cnt[i]; }
    if (blockIdx.x == 0 && threadIdx.x == 0) {
        rowstart_t[nNodes] = nEdges;
        rowstart_s[nNodes] = nEdges;
    }
}

// ---------------- CSR build: dual scatter ----------------
__global__ __launch_bounds__(256) void scatter2_kernel(
    const int* __restrict__ srcI, const int* __restrict__ tgtI,
    const int* __restrict__ rank_t, const int* __restrict__ rank_s,
    const int* __restrict__ rowstart_t, const int* __restrict__ rowstart_s,
    int* __restrict__ src_sorted, int* __restrict__ tgt_sorted, int nEdges)
{
    const int e = blockIdx.x * 256 + threadIdx.x;
    if (e >= nEdges) return;
    const int s = srcI[e];
    const int t = tgtI[e];
    src_sorted[rowstart_t[t] + rank_t[e]] = s;
    tgt_sorted[rowstart_s[s] + rank_s[e]] = t;
}

// ---------------- Fused pass kernel: first NB_PASS blocks do tgt, rest do src ----------------
__global__ __launch_bounds__(256) void pass_both_kernel(
    const int* __restrict__ rowstart_t,
    const int* __restrict__ src_sorted,
    const float* __restrict__ h,
    const hf* __restrict__ A16,
    const hf* __restrict__ s6,
    float* __restrict__ alpha_sorted,
    float* __restrict__ inv_den,
    const int* __restrict__ rowstart_s,
    const int* __restrict__ tgt_sorted,
    const hf* __restrict__ P16,
    const hf* __restrict__ PP16,
    const float* __restrict__ psi,
    const hf* __restrict__ PHI16,
    hf* __restrict__ PHIw16,
    int nNodes)
{
    const int grp = threadIdx.x >> 4;
    const int l = threadIdx.x & 15;

    if (blockIdx.x < NB_PASS) {
        // ---------------- tgt pass: score -> alpha, inv_den ----------------
        for (int n = blockIdx.x * 16 + grp; n < nNodes; n += NB_PASS * 16) {
            const int beg = rowstart_t[n];
            const int end = rowstart_t[n + 1];
            const float4 htv = ((const float4*)(h + (size_t)n * D))[l];
            float aden = 0.f;

            int k = beg;
            for (; k + 3 < end; k += 4) {
                const int sA = src_sorted[k],     sB = src_sorted[k + 1];
                const int sC = src_sorted[k + 2], sD = src_sorted[k + 3];
                const float2 rA = ((const float2*)(A16 + (size_t)sA * D))[l];
                const float2 rB = ((const float2*)(A16 + (size_t)sB * D))[l];
                const float2 rC = ((const float2*)(A16 + (size_t)sC * D))[l];
                const float2 rD = ((const float2*)(A16 + (size_t)sD * D))[l];
                float a1 = 0.f, b1 = 0.f, c1 = 0.f, d1 = 0.f;
                if (l < 2) {
                    const float2 eA = ((const float2*)(s6 + (size_t)sA * 8))[l];
                    const float2 eB = ((const float2*)(s6 + (size_t)sB * 8))[l];
                    const float2 eC = ((const float2*)(s6 + (size_t)sC * 8))[l];
                    const float2 eD = ((const float2*)(s6 + (size_t)sD * 8))[l];
                    const hf* qa = (const hf*)&eA;
                    const hf* qb = (const hf*)&eB;
                    const hf* qc = (const hf*)&eC;
                    const hf* qd = (const hf*)&eD;
                    a1 = (float)qa[0] * htv.x + (float)qa[1] * htv.y + (float)qa[2] * htv.z + (float)qa[3] * htv.w;
                    b1 = (float)qb[0] * htv.x + (float)qb[1] * htv.y + (float)qb[2] * htv.z + (float)qb[3] * htv.w;
                    c1 = (float)qc[0] * htv.x + (float)qc[1] * htv.y + (float)qc[2] * htv.z + (float)qc[3] * htv.w;
                    d1 = (float)qd[0] * htv.x + (float)qd[1] * htv.y + (float)qd[2] * htv.z + (float)qd[3] * htv.w;
                }
                const hf* qA = (const hf*)&rA;
                const hf* qB = (const hf*)&rB;
                const hf* qC = (const hf*)&rC;
                const hf* qD = (const hf*)&rD;
                a1 += (float)qA[0] * htv.x + (float)qA[1] * htv.y + (float)qA[2] * htv.z + (float)qA[3] * htv.w;
                b1 += (float)qB[0] * htv.x + (float)qB[1] * htv.y + (float)qB[2] * htv.z + (float)qB[3] * htv.w;
                c1 += (float)qC[0] * htv.x + (float)qC[1] * htv.y + (float)qC[2] * htv.z + (float)qC[3] * htv.w;
                d1 += (float)qD[0] * htv.x + (float)qD[1] * htv.y + (float)qD[2] * htv.z + (float)qD[3] * htv.w;
                #pragma unroll
                for (int off = 8; off >= 1; off >>= 1) {
                    a1 += __shfl_xor(a1, off, 64);
                    b1 += __shfl_xor(b1, off, 64);
                    c1 += __shfl_xor(c1, off, 64);
                    d1 += __shfl_xor(d1, off, 64);
                }
                const float an0 = __expf(a1);
                const float an1 = __expf(b1);
                const float an2 = __expf(c1);
                const float an3 = __expf(d1);
                aden += an0 + an1 + an2 + an3;      // all lanes, divergence-free
                if (l < 4) {
                    const float v = (l == 0) ? an0 : (l == 1) ? an1 : (l == 2) ? an2 : an3;
                    alpha_sorted[k + l] = v;
                }
            }
            for (; k < end; ++k) {
                const int s = src_sorted[k];
                const float2 r = ((const float2*)(A16 + (size_t)s * D))[l];
                float a1 = 0.f;
                if (l < 2) {
                    const float2 e6 = ((const float2*)(s6 + (size_t)s * 8))[l];
                    const hf* q = (const hf*)&e6;
                    a1 = (float)q[0] * htv.x + (float)q[1] * htv.y + (float)q[2] * htv.z + (float)q[3] * htv.w;
                }
                const hf* q = (const hf*)&r;
                a1 += (float)q[0] * htv.x + (float)q[1] * htv.y + (float)q[2] * htv.z + (float)q[3] * htv.w;
                #pragma unroll
                for (int off = 8; off >= 1; off >>= 1) a1 += __shfl_xor(a1, off, 64);
                const float an = __expf(a1);
                aden += an;
                if (l == 0) alpha_sorted[k] = an;
            }
            if (l == 0) inv_den[n] = 1.0f / (aden + 1e-9f);
        }
    } else {
        // ---------------- src pass: pair/beta -> w1m, folded PHIw scale ----------------
        for (int n = (blockIdx.x - NB_PASS) * 16 + grp; n < nNodes; n += NB_PASS * 16) {
            const int beg = rowstart_s[n];
            const int end = rowstart_s[n + 1];
            const float2 pr = ((const float2*)(P16 + (size_t)n * D))[l];
            const hf* pq = (const hf*)&pr;
            const float p0 = pq[0], p1 = pq[1], p2 = pq[2], p3 = pq[3];
            float bden = 0.f, ssum = 0.f;

            int k = beg;
            for (; k + 3 < end; k += 4) {
                const int tA = tgt_sorted[k],     tB = tgt_sorted[k + 1];
                const int tC = tgt_sorted[k + 2], tD = tgt_sorted[k + 3];
                const float2 rA = ((const float2*)(PP16 + (size_t)tA * D))[l];
                const float2 rB = ((const float2*)(PP16 + (size_t)tB * D))[l];
                const float2 rC = ((const float2*)(PP16 + (size_t)tC * D))[l];
                const float2 rD = ((const float2*)(PP16 + (size_t)tD * D))[l];
                const float psA = psi[tA], psB = psi[tB], psC = psi[tC], psD = psi[tD];
                const hf* qA = (const hf*)&rA;
                const hf* qB = (const hf*)&rB;
                const hf* qC = (const hf*)&rC;
                const hf* qD = (const hf*)&rD;
                float a2 = (float)qA[0] * p0 + (float)qA[1] * p1 + (float)qA[2] * p2 + (float)qA[3] * p3;
                float b2 = (float)qB[0] * p0 + (float)qB[1] * p1 + (float)qB[2] * p2 + (float)qB[3] * p3;
                float c2 = (float)qC[0] * p0 + (float)qC[1] * p1 + (float)qC[2] * p2 + (float)qC[3] * p3;
                float d2 = (float)qD[0] * p0 + (float)qD[1] * p1 + (float)qD[2] * p2 + (float)qD[3] * p3;
                #pragma unroll
                for (int off = 8; off >= 1; off >>= 1) {
                    a2 += __shfl_xor(a2, off, 64);
                    b2 += __shfl_xor(b2, off, 64);
                    c2 += __shfl_xor(c2, off, 64);
                    d2 += __shfl_xor(d2, off, 64);
                }
                const float bn0 = __expf(a2);
                const float bn1 = __expf(b2);
                const float bn2 = __expf(c2);
                const float bn3 = __expf(d2);
                bden += bn0 + bn1 + bn2 + bn3;
                ssum += bn0 * __expf(-psA) + bn1 * __expf(-psB)
                      + bn2 * __expf(-psC) + bn3 * __expf(-psD);
            }
            for (; k < end; ++k) {
                const int t = tgt_sorted[k];
                const float2 r = ((const float2*)(PP16 + (size_t)t * D))[l];
                const float ps = psi[t];
                const hf* q = (const hf*)&r;
                float a2 = (float)q[0] * p0 + (float)q[1] * p1 + (float)q[2] * p2 + (float)q[3] * p3;
                #pragma unroll
                for (int off = 8; off >= 1; off >>= 1) a2 += __shfl_xor(a2, off, 64);
                const float bn = __expf(a2);
                bden += bn;
                ssum += bn * __expf(-ps);
            }
            // w1m on all lanes (redundant), then scale PHI row in place
            const float st = ssum / (bden + 1e-9f);
            const float d = -logf(st + 1e-8f);
            const float w = 1.0f - 1.0f / (1.0f + __expf(-(d - 0.5f)));
            const float2 phr = ((const float2*)(PHI16 + (size_t)n * D))[l];
            const hf* phq = (const hf*)&phr;
            hf out4[4];
            out4[0] = (hf)((float)phq[0] * w);
            out4[1] = (hf)((float)phq[1] * w);
            out4[2] = (hf)((float)phq[2] * w);
            out4[3] = (hf)((float)phq[3] * w);
            ((float2*)(PHIw16 + (size_t)n * D))[l] = *(const float2*)out4;
        }
    }
}

// ---------------- Fused: gather m_att + final matmuls + relu + residual + LN ----------------
__global__ __launch_bounds__(512) void final_fused_kernel(
    const int* __restrict__ rowstart_t,
    const int* __restrict__ src_sorted,
    const float* __restrict__ alpha_sorted,
    const float* __restrict__ inv_den,
    const hf* __restrict__ PHIw16,
    const float* __restrict__ h,
    const float* __restrict__ W_self_w, const float* __restrict__ W_self_b,
    const float* __restrict__ W_A_w,    const float* __restrict__ W_A_b,
    const float* __restrict__ W_str_w,  const float* __restrict__ W_str_b,
    const float* __restrict__ ln_g,     const float* __restrict__ ln_b,
    float* __restrict__ out,
    int nNodes)
{
    __shared__ hf2 sWs2[32][D];
    __shared__ hf2 sWa2[32][D];
    __shared__ float sWstr[6 * D];
    __shared__ float sBias[D];
    __shared__ float sG[D], sB[D];
    __shared__ hf hrowh[8][D];
    __shared__ hf mrowh[8][D];

    const int tid = threadIdx.x;
    for (int idx = tid; idx < 32 * D; idx += 512) {
        const int k2 = idx >> 6, j = idx & 63;
        sWs2[k2][j] = hf2{(hf)W_self_w[(2 * k2) * D + j], (hf)W_self_w[(2 * k2 + 1) * D + j]};
        sWa2[k2][j] = hf2{(hf)W_A_w[(2 * k2) * D + j],    (hf)W_A_w[(2 * k2 + 1) * D + j]};
    }
    for (int i = tid; i < 6 * D; i += 512) sWstr[i] = W_str_w[i];
    if (tid < D) {
        sBias[tid] = W_self_b[tid] + W_A_b[tid] + W_str_b[tid];
        sG[tid] = ln_g[tid];
        sB[tid] = ln_b[tid];
    }
    __syncthreads();

    const int g = tid >> 6, j = tid & 63;
    for (int n0 = blockIdx.x * 8; n0 < nNodes; n0 += gridDim.x * 8) {
        const int n = n0 + g;
        float hj = 0.f;
        __syncthreads();
        if (n < nNodes) {
            hj = h[(size_t)n * D + j];           // issued before the gather chain
            const float idn = inv_den[n];
            const int beg = rowstart_t[n];
            const int end = rowstart_t[n + 1];
            float acc = 0.f;
            int k = beg;
            for (; k + 7 < end; k += 8) {
                const int s0 = src_sorted[k],     s1 = src_sorted[k + 1];
                const int s2 = src_sorted[k + 2], s3 = src_sorted[k + 3];
                const int s4 = src_sorted[k + 4], s5 = src_sorted[k + 5];
                const int s6i = src_sorted[k + 6], s7 = src_sorted[k + 7];
                const float c0 = alpha_sorted[k],     c1 = alpha_sorted[k + 1];
                const float c2 = alpha_sorted[k + 2], c3 = alpha_sorted[k + 3];
                const float c4 = alpha_sorted[k + 4], c5 = alpha_sorted[k + 5];
                const float c6 = alpha_sorted[k + 6], c7 = alpha_sorted[k + 7];
                const float p0 = (float)PHIw16[(size_t)s0 * D + j];
                const float p1 = (float)PHIw16[(size_t)s1 * D + j];
                const float p2 = (float)PHIw16[(size_t)s2 * D + j];
                const float p3 = (float)PHIw16[(size_t)s3 * D + j];
                const float p4 = (float)PHIw16[(size_t)s4 * D + j];
                const float p5 = (float)PHIw16[(size_t)s5 * D + j];
                const float p6 = (float)PHIw16[(size_t)s6i * D + j];
                const float p7 = (float)PHIw16[(size_t)s7 * D + j];
                acc += c0 * p0 + c1 * p1 + c2 * p2 + c3 * p3
                     + c4 * p4 + c5 * p5 + c6 * p6 + c7 * p7;
            }
            for (; k < end; ++k)
                acc += alpha_sorted[k] * (float)PHIw16[(size_t)src_sorted[k] * D + j];

            hrowh[g][j] = (hf)hj;
            mrowh[g][j] = (hf)(acc * idn);
        }
        __syncthreads();
        if (n < nNodes) {
            float acc = sBias[j];
            const hf2* hr = (const hf2*)hrowh[g];
            const hf2* mr = (const hf2*)mrowh[g];
            #pragma unroll
            for (int k2 = 0; k2 < 32; ++k2) {
                acc = fdot2f(sWs2[k2][j], hr[k2], acc);
                acc = fdot2f(sWa2[k2][j], mr[k2], acc);
            }
            #pragma unroll
            for (int k = 0; k < 6; ++k)
                acc += (float)hrowh[g][k] * sWstr[k * D + j];

            float pre = fmaxf(acc, 0.f) + hj;

            float mu = pre;
            #pragma unroll
            for (int off = 32; off >= 1; off >>= 1) mu += __shfl_xor(mu, off, 64);
            mu *= (1.0f / 64.0f);
            const float diff = pre - mu;
            float v = diff * diff;
            #pragma unroll
            for (int off = 32; off >= 1; off >>= 1) v += __shfl_xor(v, off, 64);
            v *= (1.0f / 64.0f);
            out[(size_t)n * D + j] = diff * rsqrtf(v + 1e-5f) * sG[j] + sB[j];
        }
    }
}

extern "C" void kernel_launch(void* const* d_in, const int* in_sizes, int n_in,
                              void* d_out, int out_size, void* d_ws, size_t ws_size,
                              hipStream_t stream) {
    const int* edge       = (const int*)d_in[0];
    const float* h        = (const float*)d_in[1];
    const float* W_att    = (const float*)d_in[2];
    const float* phi_w    = (const float*)d_in[3];
    const float* phi_b    = (const float*)d_in[4];
    const float* W_p      = (const float*)d_in[5];
    const float* W_pp     = (const float*)d_in[6];
    const float* fdef_w   = (const float*)d_in[7];
    const float* fdef_b   = (const float*)d_in[8];
    const float* W_self_w = (const float*)d_in[9];
    const float* W_self_b = (const float*)d_in[10];
    const float* W_A_w    = (const float*)d_in[11];
    const float* W_A_b    = (const float*)d_in[12];
    const float* W_str_w  = (const float*)d_in[13];
    const float* W_str_b  = (const float*)d_in[14];
    const float* ln_g     = (const float*)d_in[15];
    const float* ln_b     = (const float*)d_in[16];

    const int E = in_sizes[0] / 2;
    const int nNodes = in_sizes[1] / D;
    const int* srcI = edge;
    const int* tgtI = edge + E;

    char* ws = (char*)d_ws;
    size_t off = 0;
    auto alloc = [&](size_t bytes) { char* p = ws + off; off = (off + bytes + 255) & ~(size_t)255; return p; };

    int*    cnt_t     = (int*)   alloc((size_t)nNodes * 4);
    int*    cnt_s     = (int*)   alloc((size_t)nNodes * 4);
    const size_t zero_bytes = off;
    hf*     A16       = (hf*)    alloc((size_t)nNodes * D * 2);
    hf*     P16       = (hf*)    alloc((size_t)nNodes * D * 2);
    hf*     PP16      = (hf*)    alloc((size_t)nNodes * D * 2);
    hf*     PHI16     = (hf*)    alloc((size_t)nNodes * D * 2);
    hf*     PHIw16    = (hf*)    alloc((size_t)nNodes * D * 2);
    hf*     s6        = (hf*)    alloc((size_t)nNodes * 8 * 2);
    float*  psi       = (float*) alloc((size_t)nNodes * 4);
    float*  inv_den   = (float*) alloc((size_t)nNodes * 4);
    int*    rank_t    = (int*)   alloc((size_t)E * 4);
    int*    rank_s    = (int*)   alloc((size_t)E * 4);
    int*    rowstart_t= (int*)   alloc(((size_t)nNodes + 1) * 4);
    int*    rowstart_s= (int*)   alloc(((size_t)nNodes + 1) * 4);
    int*    src_sorted= (int*)   alloc((size_t)E * 4);
    int*    tgt_sorted= (int*)   alloc((size_t)E * 4);
    float*  alpha_sorted = (float*)alloc((size_t)E * 4);
    int*    bsum      = (int*)   alloc((size_t)2 * SCAN_NB * 4);

    hipMemsetAsync(d_ws, 0, zero_bytes, stream);

    node_pre_kernel<<<2048, 512, 0, stream>>>(
        h, W_att, W_p, W_pp, phi_w, phi_b, fdef_w, fdef_b,
        A16, P16, PP16, PHI16, s6, psi, nNodes);

    hist2_kernel<<<(E + 255) / 256, 256, 0, stream>>>(
        srcI, tgtI, cnt_t, cnt_s, rank_t, rank_s, E);

    scan_partial_kernel<<<2 * SCAN_NB, 256, 0, stream>>>(cnt_t, cnt_s, bsum, nNodes);
    scan_bsum_kernel<<<1, 2 * SCAN_NB, 0, stream>>>(bsum);
    scan_final_kernel<<<2 * SCAN_NB, 256, 0, stream>>>(
        cnt_t, cnt_s, bsum, rowstart_t, rowstart_s, nNodes, E);

    scatter2_kernel<<<(E + 255) / 256, 256, 0, stream>>>(
        srcI, tgtI, rank_t, rank_s, rowstart_t, rowstart_s,
        src_sorted, tgt_sorted, E);

    pass_both_kernel<<<2 * NB_PASS, 256, 0, stream>>>(
        rowstart_t, src_sorted, h, A16, s6, alpha_sorted, inv_den,
        rowstart_s, tgt_sorted, P16, PP16, psi, PHI16, PHIw16, nNodes);

    final_fused_kernel<<<2048, 512, 0, stream>>>(
        rowstart_t, src_sorted, alpha_sorted, inv_den, PHIw16, h,
        W_self_w, W_self_b, W_A_w, W_A_b, W_str_w, W_str_b,
        ln_g, ln_b, (float*)d_out, nNodes);
}

// Round 10
// 251.152 us; speedup vs baseline: 1.8598x; 1.0561x over previous
//
#include <hip/hip_runtime.h>
#include <math.h>

#define D 64
#define SCAN_NB 256   // blocks per scan pass (2 passes: tgt, src)

typedef _Float16 hf;
typedef _Float16 hf2 __attribute__((ext_vector_type(2)));

__device__ inline float fdot2f(hf2 a, hf2 b, float c) {
#if __has_builtin(__builtin_amdgcn_fdot2)
    return __builtin_amdgcn_fdot2(a, b, c, false);
#else
    return (float)a[0] * (float)b[0] + (float)a[1] * (float)b[1] + c;
#endif
}

// ---------------- Kernel 1: per-node linear transforms (fp16 weights, fdot2) ----------------
__global__ __launch_bounds__(512) void node_pre_kernel(
    const float* __restrict__ h,
    const float* __restrict__ W_att,
    const float* __restrict__ W_p,
    const float* __restrict__ W_pp,
    const float* __restrict__ phi_w,
    const float* __restrict__ phi_b,
    const float* __restrict__ fdef_w,
    const float* __restrict__ fdef_b,
    hf* __restrict__ A16,
    hf* __restrict__ P16,
    hf* __restrict__ PP16,
    hf* __restrict__ PHI16,
    hf* __restrict__ s6,
    float* __restrict__ psi,
    int nNodes)
{
    __shared__ hf2 sW2[4][32][D];        // 32 KB
    __shared__ hf  hrowh[8][D];
    __shared__ float sPhib[D];
    __shared__ float sFdef[D];

    const int tid = threadIdx.x;
    const float* Wm[4] = { W_att, W_p, W_pp, phi_w };
    for (int idx = tid; idx < 4 * 32 * D; idx += 512) {
        const int m  = idx >> 11;
        const int k2 = (idx >> 6) & 31;
        const int j  = idx & 63;
        sW2[m][k2][j] = hf2{(hf)Wm[m][(2 * k2) * D + j], (hf)Wm[m][(2 * k2 + 1) * D + j]};
    }
    if (tid < D) { sPhib[tid] = phi_b[tid]; sFdef[tid] = fdef_w[tid]; }
    __syncthreads();
    const float fb = fdef_b[0];

    const int g = tid >> 6;
    const int j = tid & 63;

    for (int n0 = blockIdx.x * 8; n0 < nNodes; n0 += gridDim.x * 8) {
        const int n = n0 + g;
        float hj = 0.f;
        __syncthreads();
        if (n < nNodes) {
            hj = h[(size_t)n * D + j];
            hrowh[g][j] = (hf)hj;
        }
        __syncthreads();
        if (n < nNodes) {
            float a = 0.f, p = 0.f, pp = 0.f, ph = sPhib[j];
            const hf2* hr = (const hf2*)hrowh[g];
            #pragma unroll
            for (int k2 = 0; k2 < 32; ++k2) {
                const hf2 hb = hr[k2];
                a  = fdot2f(sW2[0][k2][j], hb, a);
                p  = fdot2f(sW2[1][k2][j], hb, p);
                pp = fdot2f(sW2[2][k2][j], hb, pp);
                ph = fdot2f(sW2[3][k2][j], hb, ph);
            }
            const size_t base = (size_t)n * D + j;
            A16[base]   = (hf)a;
            P16[base]   = (hf)p;
            PP16[base]  = (hf)pp;
            PHI16[base] = (hf)ph;
            if (j < 8) s6[(size_t)n * 8 + j] = (hf)(j < 6 ? hj : 0.f);
            float ps = hj * sFdef[j];
            #pragma unroll
            for (int off = 32; off >= 1; off >>= 1) ps += __shfl_xor(ps, off, 64);
            if (j == 0) psi[n] = ps + fb;
        }
    }
}

// ---------------- CSR build: dual histogram + rank ----------------
__global__ __launch_bounds__(256) void hist2_kernel(
    const int* __restrict__ srcI, const int* __restrict__ tgtI,
    int* __restrict__ cnt_t, int* __restrict__ cnt_s,
    int* __restrict__ rank_t, int* __restrict__ rank_s, int nEdges)
{
    const int e = blockIdx.x * 256 + threadIdx.x;
    if (e >= nEdges) return;
    rank_t[e] = atomicAdd(&cnt_t[tgtI[e]], 1);
    rank_s[e] = atomicAdd(&cnt_s[srcI[e]], 1);
}

// ---------------- Multi-block scan, step 1: per-block partial sums ----------------
__global__ __launch_bounds__(256) void scan_partial_kernel(
    const int* __restrict__ cnt_t, const int* __restrict__ cnt_s,
    int* __restrict__ bsum, int nNodes)
{
    const int pass = blockIdx.x >> 8;
    const int b = blockIdx.x & (SCAN_NB - 1);
    const int* cnt = pass ? cnt_s : cnt_t;
    const int C = (nNodes + SCAN_NB - 1) / SCAN_NB;
    const int K = (C + 255) / 256;
    const int base = b * C;
    const int lim = min(base + C, nNodes);
    const int tbeg = base + threadIdx.x * K;
    const int tend = min(tbeg + K, lim);
    int tsum = 0;
    for (int i = tbeg; i < tend; ++i) tsum += cnt[i];
    __shared__ int red[256];
    red[threadIdx.x] = tsum;
    __syncthreads();
    for (int off = 128; off >= 1; off >>= 1) {
        if (threadIdx.x < off) red[threadIdx.x] += red[threadIdx.x + off];
        __syncthreads();
    }
    if (threadIdx.x == 0) bsum[pass * SCAN_NB + b] = red[0];
}

// ---------------- Multi-block scan, step 2: scan the 2*SCAN_NB block sums ----------------
__global__ __launch_bounds__(512) void scan_bsum_kernel(int* __restrict__ bsum)
{
    __shared__ int s[2 * SCAN_NB];
    const int tid = threadIdx.x;
    const int orig = bsum[tid];
    s[tid] = orig;
    __syncthreads();
    const int seg = tid & (SCAN_NB - 1);
    for (int off = 1; off < SCAN_NB; off <<= 1) {
        const int add = (seg >= off) ? s[tid - off] : 0;
        __syncthreads();
        s[tid] += add;
        __syncthreads();
    }
    bsum[tid] = s[tid] - orig;
}

// ---------------- Multi-block scan, step 3: intra-chunk scan + offset -> rowstart ----------------
__global__ __launch_bounds__(256) void scan_final_kernel(
    const int* __restrict__ cnt_t, const int* __restrict__ cnt_s,
    const int* __restrict__ bsum,
    int* __restrict__ rowstart_t, int* __restrict__ rowstart_s,
    int nNodes, int nEdges)
{
    const int pass = blockIdx.x >> 8;
    const int b = blockIdx.x & (SCAN_NB - 1);
    const int* cnt = pass ? cnt_s : cnt_t;
    int* rs = pass ? rowstart_s : rowstart_t;
    const int C = (nNodes + SCAN_NB - 1) / SCAN_NB;
    const int K = (C + 255) / 256;
    const int base = b * C;
    const int lim = min(base + C, nNodes);
    const int tbeg = base + threadIdx.x * K;
    const int tend = min(tbeg + K, lim);
    int tsum = 0;
    for (int i = tbeg; i < tend; ++i) tsum += cnt[i];
    __shared__ int s[256];
    s[threadIdx.x] = tsum;
    __syncthreads();
    for (int off = 1; off < 256; off <<= 1) {
        const int add = (threadIdx.x >= off) ? s[threadIdx.x - off] : 0;
        __syncthreads();
        s[threadIdx.x] += add;
        __syncthreads();
    }
    int run = s[threadIdx.x] - tsum + bsum[pass * SCAN_NB + b];
    for (int i = tbeg; i < tend; ++i) { rs[i] = run; run += cnt[i]; }
    if (blockIdx.x == 0 && threadIdx.x == 0) {
        rowstart_t[nNodes] = nEdges;
        rowstart_s[nNodes] = nEdges;
    }
}

// ---------------- CSR build: dual scatter ----------------
__global__ __launch_bounds__(256) void scatter2_kernel(
    const int* __restrict__ srcI, const int* __restrict__ tgtI,
    const int* __restrict__ rank_t, const int* __restrict__ rank_s,
    const int* __restrict__ rowstart_t, const int* __restrict__ rowstart_s,
    int* __restrict__ src_sorted, int* __restrict__ tgt_sorted, int nEdges)
{
    const int e = blockIdx.x * 256 + threadIdx.x;
    if (e >= nEdges) return;
    const int s = srcI[e];
    const int t = tgtI[e];
    src_sorted[rowstart_t[t] + rank_t[e]] = s;
    tgt_sorted[rowstart_s[s] + rank_s[e]] = t;
}

// ---------------- Pass src: pair/beta -> w1m, PHIw16 = PHI16*w1m. 16-lane group per node. ----------------
__global__ __launch_bounds__(256) void pass_src_kernel(
    const int* __restrict__ rowstart_s,
    const int* __restrict__ tgt_sorted,
    const hf* __restrict__ P16,
    const hf* __restrict__ PP16,
    const float* __restrict__ psi,
    const hf* __restrict__ PHI16,
    hf* __restrict__ PHIw16,
    int nNodes)
{
    const int grp = threadIdx.x >> 4;
    const int l = threadIdx.x & 15;

    for (int n = blockIdx.x * 16 + grp; n < nNodes; n += gridDim.x * 16) {
        const int beg = rowstart_s[n];
        const int end = rowstart_s[n + 1];
        const float2 pr = ((const float2*)(P16 + (size_t)n * D))[l];
        const hf* pq = (const hf*)&pr;
        const float p0 = pq[0], p1 = pq[1], p2 = pq[2], p3 = pq[3];
        float bden = 0.f, ssum = 0.f;

        int k = beg;
        for (; k + 3 < end; k += 4) {
            const int tA = tgt_sorted[k],     tB = tgt_sorted[k + 1];
            const int tC = tgt_sorted[k + 2], tD = tgt_sorted[k + 3];
            const float2 rA = ((const float2*)(PP16 + (size_t)tA * D))[l];
            const float2 rB = ((const float2*)(PP16 + (size_t)tB * D))[l];
            const float2 rC = ((const float2*)(PP16 + (size_t)tC * D))[l];
            const float2 rD = ((const float2*)(PP16 + (size_t)tD * D))[l];
            const float psA = psi[tA], psB = psi[tB], psC = psi[tC], psD = psi[tD];
            const hf* qA = (const hf*)&rA;
            const hf* qB = (const hf*)&rB;
            const hf* qC = (const hf*)&rC;
            const hf* qD = (const hf*)&rD;
            float a2 = (float)qA[0] * p0 + (float)qA[1] * p1 + (float)qA[2] * p2 + (float)qA[3] * p3;
            float b2 = (float)qB[0] * p0 + (float)qB[1] * p1 + (float)qB[2] * p2 + (float)qB[3] * p3;
            float c2 = (float)qC[0] * p0 + (float)qC[1] * p1 + (float)qC[2] * p2 + (float)qC[3] * p3;
            float d2 = (float)qD[0] * p0 + (float)qD[1] * p1 + (float)qD[2] * p2 + (float)qD[3] * p3;
            #pragma unroll
            for (int off = 8; off >= 1; off >>= 1) {
                a2 += __shfl_xor(a2, off, 64);
                b2 += __shfl_xor(b2, off, 64);
                c2 += __shfl_xor(c2, off, 64);
                d2 += __shfl_xor(d2, off, 64);
            }
            const float bn0 = __expf(a2);
            const float bn1 = __expf(b2);
            const float bn2 = __expf(c2);
            const float bn3 = __expf(d2);
            bden += bn0 + bn1 + bn2 + bn3;
            ssum += bn0 * __expf(-psA) + bn1 * __expf(-psB)
                  + bn2 * __expf(-psC) + bn3 * __expf(-psD);
        }
        for (; k < end; ++k) {
            const int t = tgt_sorted[k];
            const float2 r = ((const float2*)(PP16 + (size_t)t * D))[l];
            const float ps = psi[t];
            const hf* q = (const hf*)&r;
            float a2 = (float)q[0] * p0 + (float)q[1] * p1 + (float)q[2] * p2 + (float)q[3] * p3;
            #pragma unroll
            for (int off = 8; off >= 1; off >>= 1) a2 += __shfl_xor(a2, off, 64);
            const float bn = __expf(a2);
            bden += bn;
            ssum += bn * __expf(-ps);
        }
        const float st = ssum / (bden + 1e-9f);
        const float d = -logf(st + 1e-8f);
        const float w = 1.0f - 1.0f / (1.0f + __expf(-(d - 0.5f)));
        const float2 phr = ((const float2*)(PHI16 + (size_t)n * D))[l];
        const hf* phq = (const hf*)&phr;
        hf out4[4];
        out4[0] = (hf)((float)phq[0] * w);
        out4[1] = (hf)((float)phq[1] * w);
        out4[2] = (hf)((float)phq[2] * w);
        out4[3] = (hf)((float)phq[3] * w);
        ((float2*)(PHIw16 + (size_t)n * D))[l] = *(const float2*)out4;
    }
}

// ---------------- Pass tgt FUSED: score -> alpha -> m accumulation, all in one edge loop ----------------
__global__ __launch_bounds__(256) void pass_tgt_fused_kernel(
    const int* __restrict__ rowstart_t,
    const int* __restrict__ src_sorted,
    const float* __restrict__ h,
    const hf* __restrict__ A16,
    const hf* __restrict__ s6,
    const hf* __restrict__ PHIw16,
    hf* __restrict__ m16,
    int nNodes)
{
    const int grp = threadIdx.x >> 4;
    const int l = threadIdx.x & 15;

    for (int n = blockIdx.x * 16 + grp; n < nNodes; n += gridDim.x * 16) {
        const int beg = rowstart_t[n];
        const int end = rowstart_t[n + 1];
        const float4 htv = ((const float4*)(h + (size_t)n * D))[l];
        float aden = 0.f;
        float m0 = 0.f, m1 = 0.f, m2 = 0.f, m3 = 0.f;

        int k = beg;
        for (; k + 3 < end; k += 4) {
            const int sA = src_sorted[k],     sB = src_sorted[k + 1];
            const int sC = src_sorted[k + 2], sD = src_sorted[k + 3];
            // 8 independent row-gathers in flight (A rows for scores, PHIw rows for messages)
            const float2 rA = ((const float2*)(A16 + (size_t)sA * D))[l];
            const float2 rB = ((const float2*)(A16 + (size_t)sB * D))[l];
            const float2 rC = ((const float2*)(A16 + (size_t)sC * D))[l];
            const float2 rD = ((const float2*)(A16 + (size_t)sD * D))[l];
            const float2 wA = ((const float2*)(PHIw16 + (size_t)sA * D))[l];
            const float2 wB = ((const float2*)(PHIw16 + (size_t)sB * D))[l];
            const float2 wC = ((const float2*)(PHIw16 + (size_t)sC * D))[l];
            const float2 wD = ((const float2*)(PHIw16 + (size_t)sD * D))[l];
            float a1 = 0.f, b1 = 0.f, c1 = 0.f, d1 = 0.f;
            if (l < 2) {
                const float2 eA = ((const float2*)(s6 + (size_t)sA * 8))[l];
                const float2 eB = ((const float2*)(s6 + (size_t)sB * 8))[l];
                const float2 eC = ((const float2*)(s6 + (size_t)sC * 8))[l];
                const float2 eD = ((const float2*)(s6 + (size_t)sD * 8))[l];
                const hf* qa = (const hf*)&eA;
                const hf* qb = (const hf*)&eB;
                const hf* qc = (const hf*)&eC;
                const hf* qd = (const hf*)&eD;
                a1 = (float)qa[0] * htv.x + (float)qa[1] * htv.y + (float)qa[2] * htv.z + (float)qa[3] * htv.w;
                b1 = (float)qb[0] * htv.x + (float)qb[1] * htv.y + (float)qb[2] * htv.z + (float)qb[3] * htv.w;
                c1 = (float)qc[0] * htv.x + (float)qc[1] * htv.y + (float)qc[2] * htv.z + (float)qc[3] * htv.w;
                d1 = (float)qd[0] * htv.x + (float)qd[1] * htv.y + (float)qd[2] * htv.z + (float)qd[3] * htv.w;
            }
            const hf* qA = (const hf*)&rA;
            const hf* qB = (const hf*)&rB;
            const hf* qC = (const hf*)&rC;
            const hf* qD = (const hf*)&rD;
            a1 += (float)qA[0] * htv.x + (float)qA[1] * htv.y + (float)qA[2] * htv.z + (float)qA[3] * htv.w;
            b1 += (float)qB[0] * htv.x + (float)qB[1] * htv.y + (float)qB[2] * htv.z + (float)qB[3] * htv.w;
            c1 += (float)qC[0] * htv.x + (float)qC[1] * htv.y + (float)qC[2] * htv.z + (float)qC[3] * htv.w;
            d1 += (float)qD[0] * htv.x + (float)qD[1] * htv.y + (float)qD[2] * htv.z + (float)qD[3] * htv.w;
            #pragma unroll
            for (int off = 8; off >= 1; off >>= 1) {
                a1 += __shfl_xor(a1, off, 64);
                b1 += __shfl_xor(b1, off, 64);
                c1 += __shfl_xor(c1, off, 64);
                d1 += __shfl_xor(d1, off, 64);
            }
            const float an0 = __expf(a1);
            const float an1 = __expf(b1);
            const float an2 = __expf(c1);
            const float an3 = __expf(d1);
            aden += an0 + an1 + an2 + an3;
            const hf* wa = (const hf*)&wA;
            const hf* wb = (const hf*)&wB;
            const hf* wc = (const hf*)&wC;
            const hf* wd = (const hf*)&wD;
            m0 += an0 * (float)wa[0] + an1 * (float)wb[0] + an2 * (float)wc[0] + an3 * (float)wd[0];
            m1 += an0 * (float)wa[1] + an1 * (float)wb[1] + an2 * (float)wc[1] + an3 * (float)wd[1];
            m2 += an0 * (float)wa[2] + an1 * (float)wb[2] + an2 * (float)wc[2] + an3 * (float)wd[2];
            m3 += an0 * (float)wa[3] + an1 * (float)wb[3] + an2 * (float)wc[3] + an3 * (float)wd[3];
        }
        for (; k < end; ++k) {
            const int s = src_sorted[k];
            const float2 r = ((const float2*)(A16 + (size_t)s * D))[l];
            const float2 w = ((const float2*)(PHIw16 + (size_t)s * D))[l];
            float a1 = 0.f;
            if (l < 2) {
                const float2 e6 = ((const float2*)(s6 + (size_t)s * 8))[l];
                const hf* q = (const hf*)&e6;
                a1 = (float)q[0] * htv.x + (float)q[1] * htv.y + (float)q[2] * htv.z + (float)q[3] * htv.w;
            }
            const hf* q = (const hf*)&r;
            a1 += (float)q[0] * htv.x + (float)q[1] * htv.y + (float)q[2] * htv.z + (float)q[3] * htv.w;
            #pragma unroll
            for (int off = 8; off >= 1; off >>= 1) a1 += __shfl_xor(a1, off, 64);
            const float an = __expf(a1);
            aden += an;
            const hf* wq = (const hf*)&w;
            m0 += an * (float)wq[0];
            m1 += an * (float)wq[1];
            m2 += an * (float)wq[2];
            m3 += an * (float)wq[3];
        }

        const float idn = 1.0f / (aden + 1e-9f);
        hf o4[4];
        o4[0] = (hf)(m0 * idn);
        o4[1] = (hf)(m1 * idn);
        o4[2] = (hf)(m2 * idn);
        o4[3] = (hf)(m3 * idn);
        ((float2*)(m16 + (size_t)n * D))[l] = *(const float2*)o4;
    }
}

// ---------------- Final: pure streaming matmuls (fp16 weights, fdot2) + relu + residual + LN ----------------
__global__ __launch_bounds__(512) void final_kernel(
    const float* __restrict__ h,
    const hf* __restrict__ m16,
    const float* __restrict__ W_self_w, const float* __restrict__ W_self_b,
    const float* __restrict__ W_A_w,    const float* __restrict__ W_A_b,
    const float* __restrict__ W_str_w,  const float* __restrict__ W_str_b,
    const float* __restrict__ ln_g,     const float* __restrict__ ln_b,
    float* __restrict__ out,
    int nNodes)
{
    __shared__ hf2 sWs2[32][D];
    __shared__ hf2 sWa2[32][D];
    __shared__ float sWstr[6 * D];
    __shared__ float sBias[D];
    __shared__ float sG[D], sB[D];
    __shared__ hf hrowh[8][D];
    __shared__ hf mrowh[8][D];

    const int tid = threadIdx.x;
    for (int idx = tid; idx < 32 * D; idx += 512) {
        const int k2 = idx >> 6, j = idx & 63;
        sWs2[k2][j] = hf2{(hf)W_self_w[(2 * k2) * D + j], (hf)W_self_w[(2 * k2 + 1) * D + j]};
        sWa2[k2][j] = hf2{(hf)W_A_w[(2 * k2) * D + j],    (hf)W_A_w[(2 * k2 + 1) * D + j]};
    }
    for (int i = tid; i < 6 * D; i += 512) sWstr[i] = W_str_w[i];
    if (tid < D) {
        sBias[tid] = W_self_b[tid] + W_A_b[tid] + W_str_b[tid];
        sG[tid] = ln_g[tid];
        sB[tid] = ln_b[tid];
    }
    __syncthreads();

    const int g = tid >> 6, j = tid & 63;
    for (int n0 = blockIdx.x * 8; n0 < nNodes; n0 += gridDim.x * 8) {
        const int n = n0 + g;
        float hj = 0.f;
        __syncthreads();
        if (n < nNodes) {
            hj = h[(size_t)n * D + j];
            hrowh[g][j] = (hf)hj;
            mrowh[g][j] = m16[(size_t)n * D + j];
        }
        __syncthreads();
        if (n < nNodes) {
            float acc = sBias[j];
            const hf2* hr = (const hf2*)hrowh[g];
            const hf2* mr = (const hf2*)mrowh[g];
            #pragma unroll
            for (int k2 = 0; k2 < 32; ++k2) {
                acc = fdot2f(sWs2[k2][j], hr[k2], acc);
                acc = fdot2f(sWa2[k2][j], mr[k2], acc);
            }
            #pragma unroll
            for (int k = 0; k < 6; ++k)
                acc += (float)hrowh[g][k] * sWstr[k * D + j];

            float pre = fmaxf(acc, 0.f) + hj;

            float mu = pre;
            #pragma unroll
            for (int off = 32; off >= 1; off >>= 1) mu += __shfl_xor(mu, off, 64);
            mu *= (1.0f / 64.0f);
            const float diff = pre - mu;
            float v = diff * diff;
            #pragma unroll
            for (int off = 32; off >= 1; off >>= 1) v += __shfl_xor(v, off, 64);
            v *= (1.0f / 64.0f);
            out[(size_t)n * D + j] = diff * rsqrtf(v + 1e-5f) * sG[j] + sB[j];
        }
    }
}

extern "C" void kernel_launch(void* const* d_in, const int* in_sizes, int n_in,
                              void* d_out, int out_size, void* d_ws, size_t ws_size,
                              hipStream_t stream) {
    const int* edge       = (const int*)d_in[0];
    const float* h        = (const float*)d_in[1];
    const float* W_att    = (const float*)d_in[2];
    const float* phi_w    = (const float*)d_in[3];
    const float* phi_b    = (const float*)d_in[4];
    const float* W_p      = (const float*)d_in[5];
    const float* W_pp     = (const float*)d_in[6];
    const float* fdef_w   = (const float*)d_in[7];
    const float* fdef_b   = (const float*)d_in[8];
    const float* W_self_w = (const float*)d_in[9];
    const float* W_self_b = (const float*)d_in[10];
    const float* W_A_w    = (const float*)d_in[11];
    const float* W_A_b    = (const float*)d_in[12];
    const float* W_str_w  = (const float*)d_in[13];
    const float* W_str_b  = (const float*)d_in[14];
    const float* ln_g     = (const float*)d_in[15];
    const float* ln_b     = (const float*)d_in[16];

    const int E = in_sizes[0] / 2;
    const int nNodes = in_sizes[1] / D;
    const int* srcI = edge;
    const int* tgtI = edge + E;

    char* ws = (char*)d_ws;
    size_t off = 0;
    auto alloc = [&](size_t bytes) { char* p = ws + off; off = (off + bytes + 255) & ~(size_t)255; return p; };

    int*    cnt_t     = (int*)   alloc((size_t)nNodes * 4);
    int*    cnt_s     = (int*)   alloc((size_t)nNodes * 4);
    const size_t zero_bytes = off;
    hf*     A16       = (hf*)    alloc((size_t)nNodes * D * 2);
    hf*     P16       = (hf*)    alloc((size_t)nNodes * D * 2);
    hf*     PP16      = (hf*)    alloc((size_t)nNodes * D * 2);
    hf*     PHI16     = (hf*)    alloc((size_t)nNodes * D * 2);
    hf*     PHIw16    = (hf*)    alloc((size_t)nNodes * D * 2);
    hf*     m16       = (hf*)    alloc((size_t)nNodes * D * 2);
    hf*     s6        = (hf*)    alloc((size_t)nNodes * 8 * 2);
    float*  psi       = (float*) alloc((size_t)nNodes * 4);
    int*    rank_t    = (int*)   alloc((size_t)E * 4);
    int*    rank_s    = (int*)   alloc((size_t)E * 4);
    int*    rowstart_t= (int*)   alloc(((size_t)nNodes + 1) * 4);
    int*    rowstart_s= (int*)   alloc(((size_t)nNodes + 1) * 4);
    int*    src_sorted= (int*)   alloc((size_t)E * 4);
    int*    tgt_sorted= (int*)   alloc((size_t)E * 4);
    int*    bsum      = (int*)   alloc((size_t)2 * SCAN_NB * 4);

    hipMemsetAsync(d_ws, 0, zero_bytes, stream);

    node_pre_kernel<<<2048, 512, 0, stream>>>(
        h, W_att, W_p, W_pp, phi_w, phi_b, fdef_w, fdef_b,
        A16, P16, PP16, PHI16, s6, psi, nNodes);

    hist2_kernel<<<(E + 255) / 256, 256, 0, stream>>>(
        srcI, tgtI, cnt_t, cnt_s, rank_t, rank_s, E);

    scan_partial_kernel<<<2 * SCAN_NB, 256, 0, stream>>>(cnt_t, cnt_s, bsum, nNodes);
    scan_bsum_kernel<<<1, 2 * SCAN_NB, 0, stream>>>(bsum);
    scan_final_kernel<<<2 * SCAN_NB, 256, 0, stream>>>(
        cnt_t, cnt_s, bsum, rowstart_t, rowstart_s, nNodes, E);

    scatter2_kernel<<<(E + 255) / 256, 256, 0, stream>>>(
        srcI, tgtI, rank_t, rank_s, rowstart_t, rowstart_s,
        src_sorted, tgt_sorted, E);

    pass_src_kernel<<<2048, 256, 0, stream>>>(
        rowstart_s, tgt_sorted, P16, PP16, psi, PHI16, PHIw16, nNodes);

    pass_tgt_fused_kernel<<<2048, 256, 0, stream>>>(
        rowstart_t, src_sorted, h, A16, s6, PHIw16, m16, nNodes);

    final_kernel<<<2048, 512, 0, stream>>>(
        h, m16, W_self_w, W_self_b, W_A_w, W_A_b,
        W_str_w, W_str_b, ln_g, ln_b, (float*)d_out, nNodes);
}

// Round 11
// 219.420 us; speedup vs baseline: 2.1288x; 1.1446x over previous
//
#include <hip/hip_runtime.h>
#include <math.h>

#define D 64
#define SCAN_NB 256   // blocks per scan pass (2 passes: tgt, src)

typedef _Float16 hf;
typedef _Float16 hf2 __attribute__((ext_vector_type(2)));

__device__ inline float fdot2f(hf2 a, hf2 b, float c) {
#if __has_builtin(__builtin_amdgcn_fdot2)
    return __builtin_amdgcn_fdot2(a, b, c, false);
#else
    return (float)a[0] * (float)b[0] + (float)a[1] * (float)b[1] + c;
#endif
}

// ---------------- Kernel 1: per-node linear transforms + FUSED edge histogram ----------------
// AW16[n][2j]=A'_j (A + structural fold), AW16[n][2j+1]=PHI_j (unscaled).
// P16, PP16 fp16 rows; enpsi[n]=exp(-psi[n]).
// Edge histogram: rank-returning atomics issued at entry, rank stores deferred to kernel end.
__global__ __launch_bounds__(512) void node_pre_hist_kernel(
    const float* __restrict__ h,
    const float* __restrict__ W_att,
    const float* __restrict__ W_p,
    const float* __restrict__ W_pp,
    const float* __restrict__ phi_w,
    const float* __restrict__ phi_b,
    const float* __restrict__ fdef_w,
    const float* __restrict__ fdef_b,
    const int* __restrict__ srcI,
    const int* __restrict__ tgtI,
    int* __restrict__ cnt_t,
    int* __restrict__ cnt_s,
    int* __restrict__ rank_t,
    int* __restrict__ rank_s,
    hf* __restrict__ AW16,
    hf* __restrict__ P16,
    hf* __restrict__ PP16,
    float* __restrict__ enpsi,
    int nNodes, int nEdges)
{
    __shared__ hf2 sW2[4][32][D];        // 32 KB
    __shared__ hf  hrowh[8][D];
    __shared__ float sPhib[D];
    __shared__ float sFdef[D];

    const int tid = threadIdx.x;

    // ---- phase 0: issue histogram atomics; results live in regs until kernel end ----
    const int span = gridDim.x * 512;
    const int e0 = blockIdx.x * 512 + tid;
    int my_rt = 0, my_rs = 0;
    const bool have_e = (e0 < nEdges);
    if (have_e) {
        my_rt = atomicAdd(&cnt_t[tgtI[e0]], 1);
        my_rs = atomicAdd(&cnt_s[srcI[e0]], 1);
    }
    // safety for E > span (zero iterations at current sizes)
    for (int e = e0 + span; e < nEdges; e += span) {
        rank_t[e] = atomicAdd(&cnt_t[tgtI[e]], 1);
        rank_s[e] = atomicAdd(&cnt_s[srcI[e]], 1);
    }

    // ---- weights to LDS ----
    const float* Wm[4] = { W_att, W_p, W_pp, phi_w };
    for (int idx = tid; idx < 4 * 32 * D; idx += 512) {
        const int m  = idx >> 11;
        const int k2 = (idx >> 6) & 31;
        const int j  = idx & 63;
        sW2[m][k2][j] = hf2{(hf)Wm[m][(2 * k2) * D + j], (hf)Wm[m][(2 * k2 + 1) * D + j]};
    }
    if (tid < D) { sPhib[tid] = phi_b[tid]; sFdef[tid] = fdef_w[tid]; }
    __syncthreads();
    const float fb = fdef_b[0];

    const int g = tid >> 6;
    const int j = tid & 63;

    for (int n0 = blockIdx.x * 8; n0 < nNodes; n0 += gridDim.x * 8) {
        const int n = n0 + g;
        float hj = 0.f;
        __syncthreads();
        if (n < nNodes) {
            hj = h[(size_t)n * D + j];
            hrowh[g][j] = (hf)hj;
        }
        __syncthreads();
        if (n < nNodes) {
            float a = 0.f, p = 0.f, pp = 0.f, ph = sPhib[j];
            const hf2* hr = (const hf2*)hrowh[g];
            #pragma unroll
            for (int k2 = 0; k2 < 32; ++k2) {
                const hf2 hb = hr[k2];
                a  = fdot2f(sW2[0][k2][j], hb, a);
                p  = fdot2f(sW2[1][k2][j], hb, p);
                pp = fdot2f(sW2[2][k2][j], hb, pp);
                ph = fdot2f(sW2[3][k2][j], hb, ph);
            }
            if (j < 6) a += hj;   // structural-dot fold: A' = A + s_feat
            const size_t base = (size_t)n * D + j;
            AW16[((size_t)n << 7) + 2 * j]     = (hf)a;
            AW16[((size_t)n << 7) + 2 * j + 1] = (hf)ph;
            P16[base]  = (hf)p;
            PP16[base] = (hf)pp;
            float ps = hj * sFdef[j];
            #pragma unroll
            for (int off = 32; off >= 1; off >>= 1) ps += __shfl_xor(ps, off, 64);
            if (j == 0) enpsi[n] = __expf(-(ps + fb));
        }
    }

    // ---- deferred rank stores (atomic results waited on here, after ~all compute) ----
    if (have_e) {
        rank_t[e0] = my_rt;
        rank_s[e0] = my_rs;
    }
}

// ---------------- Multi-block scan, step 1: per-block partial sums ----------------
__global__ __launch_bounds__(256) void scan_partial_kernel(
    const int* __restrict__ cnt_t, const int* __restrict__ cnt_s,
    int* __restrict__ bsum, int nNodes)
{
    const int pass = blockIdx.x >> 8;
    const int b = blockIdx.x & (SCAN_NB - 1);
    const int* cnt = pass ? cnt_s : cnt_t;
    const int C = (nNodes + SCAN_NB - 1) / SCAN_NB;
    const int K = (C + 255) / 256;
    const int base = b * C;
    const int lim = min(base + C, nNodes);
    const int tbeg = base + threadIdx.x * K;
    const int tend = min(tbeg + K, lim);
    int tsum = 0;
    for (int i = tbeg; i < tend; ++i) tsum += cnt[i];
    __shared__ int red[256];
    red[threadIdx.x] = tsum;
    __syncthreads();
    for (int off = 128; off >= 1; off >>= 1) {
        if (threadIdx.x < off) red[threadIdx.x] += red[threadIdx.x + off];
        __syncthreads();
    }
    if (threadIdx.x == 0) bsum[pass * SCAN_NB + b] = red[0];
}

// ---------------- Multi-block scan, step 2: scan the 2*SCAN_NB block sums ----------------
__global__ __launch_bounds__(512) void scan_bsum_kernel(int* __restrict__ bsum)
{
    __shared__ int s[2 * SCAN_NB];
    const int tid = threadIdx.x;
    const int orig = bsum[tid];
    s[tid] = orig;
    __syncthreads();
    const int seg = tid & (SCAN_NB - 1);
    for (int off = 1; off < SCAN_NB; off <<= 1) {
        const int add = (seg >= off) ? s[tid - off] : 0;
        __syncthreads();
        s[tid] += add;
        __syncthreads();
    }
    bsum[tid] = s[tid] - orig;
}

// ---------------- Multi-block scan, step 3: intra-chunk scan + offset -> rowstart ----------------
__global__ __launch_bounds__(256) void scan_final_kernel(
    const int* __restrict__ cnt_t, const int* __restrict__ cnt_s,
    const int* __restrict__ bsum,
    int* __restrict__ rowstart_t, int* __restrict__ rowstart_s,
    int nNodes, int nEdges)
{
    const int pass = blockIdx.x >> 8;
    const int b = blockIdx.x & (SCAN_NB - 1);
    const int* cnt = pass ? cnt_s : cnt_t;
    int* rs = pass ? rowstart_s : rowstart_t;
    const int C = (nNodes + SCAN_NB - 1) / SCAN_NB;
    const int K = (C + 255) / 256;
    const int base = b * C;
    const int lim = min(base + C, nNodes);
    const int tbeg = base + threadIdx.x * K;
    const int tend = min(tbeg + K, lim);
    int tsum = 0;
    for (int i = tbeg; i < tend; ++i) tsum += cnt[i];
    __shared__ int s[256];
    s[threadIdx.x] = tsum;
    __syncthreads();
    for (int off = 1; off < 256; off <<= 1) {
        const int add = (threadIdx.x >= off) ? s[threadIdx.x - off] : 0;
        __syncthreads();
        s[threadIdx.x] += add;
        __syncthreads();
    }
    int run = s[threadIdx.x] - tsum + bsum[pass * SCAN_NB + b];
    for (int i = tbeg; i < tend; ++i) { rs[i] = run; run += cnt[i]; }
    if (blockIdx.x == 0 && threadIdx.x == 0) {
        rowstart_t[nNodes] = nEdges;
        rowstart_s[nNodes] = nEdges;
    }
}

// ---------------- CSR build: dual scatter ----------------
__global__ __launch_bounds__(256) void scatter2_kernel(
    const int* __restrict__ srcI, const int* __restrict__ tgtI,
    const int* __restrict__ rank_t, const int* __restrict__ rank_s,
    const int* __restrict__ rowstart_t, const int* __restrict__ rowstart_s,
    int* __restrict__ src_sorted, int* __restrict__ tgt_sorted, int nEdges)
{
    const int e = blockIdx.x * 256 + threadIdx.x;
    if (e >= nEdges) return;
    const int s = srcI[e];
    const int t = tgtI[e];
    src_sorted[rowstart_t[t] + rank_t[e]] = s;
    tgt_sorted[rowstart_s[s] + rank_s[e]] = t;
}

// ---------------- Pass src: pair/beta -> w1m, scale odd (PHI) slots of AW in place ----------------
__global__ __launch_bounds__(256) void pass_src_kernel(
    const int* __restrict__ rowstart_s,
    const int* __restrict__ tgt_sorted,
    const hf* __restrict__ P16,
    const hf* __restrict__ PP16,
    const float* __restrict__ enpsi,
    hf* __restrict__ AW16,
    int nNodes)
{
    const int grp = threadIdx.x >> 4;
    const int l = threadIdx.x & 15;

    for (int n = blockIdx.x * 16 + grp; n < nNodes; n += gridDim.x * 16) {
        const int beg = rowstart_s[n];
        const int end = rowstart_s[n + 1];
        const float2 pr = ((const float2*)(P16 + (size_t)n * D))[l];
        const hf* pq = (const hf*)&pr;
        const float p0 = pq[0], p1 = pq[1], p2 = pq[2], p3 = pq[3];
        float bden = 0.f, ssum = 0.f;

        int k = beg;
        for (; k + 3 < end; k += 4) {
            const int tA = tgt_sorted[k],     tB = tgt_sorted[k + 1];
            const int tC = tgt_sorted[k + 2], tD = tgt_sorted[k + 3];
            const float2 rA = ((const float2*)(PP16 + (size_t)tA * D))[l];
            const float2 rB = ((const float2*)(PP16 + (size_t)tB * D))[l];
            const float2 rC = ((const float2*)(PP16 + (size_t)tC * D))[l];
            const float2 rD = ((const float2*)(PP16 + (size_t)tD * D))[l];
            const float eA = enpsi[tA], eB = enpsi[tB], eC = enpsi[tC], eD = enpsi[tD];
            const hf* qA = (const hf*)&rA;
            const hf* qB = (const hf*)&rB;
            const hf* qC = (const hf*)&rC;
            const hf* qD = (const hf*)&rD;
            float a2 = (float)qA[0] * p0 + (float)qA[1] * p1 + (float)qA[2] * p2 + (float)qA[3] * p3;
            float b2 = (float)qB[0] * p0 + (float)qB[1] * p1 + (float)qB[2] * p2 + (float)qB[3] * p3;
            float c2 = (float)qC[0] * p0 + (float)qC[1] * p1 + (float)qC[2] * p2 + (float)qC[3] * p3;
            float d2 = (float)qD[0] * p0 + (float)qD[1] * p1 + (float)qD[2] * p2 + (float)qD[3] * p3;
            #pragma unroll
            for (int off = 8; off >= 1; off >>= 1) {
                a2 += __shfl_xor(a2, off, 64);
                b2 += __shfl_xor(b2, off, 64);
                c2 += __shfl_xor(c2, off, 64);
                d2 += __shfl_xor(d2, off, 64);
            }
            const float bn0 = __expf(a2);
            const float bn1 = __expf(b2);
            const float bn2 = __expf(c2);
            const float bn3 = __expf(d2);
            bden += bn0 + bn1 + bn2 + bn3;
            ssum += bn0 * eA + bn1 * eB + bn2 * eC + bn3 * eD;
        }
        for (; k < end; ++k) {
            const int t = tgt_sorted[k];
            const float2 r = ((const float2*)(PP16 + (size_t)t * D))[l];
            const float et = enpsi[t];
            const hf* q = (const hf*)&r;
            float a2 = (float)q[0] * p0 + (float)q[1] * p1 + (float)q[2] * p2 + (float)q[3] * p3;
            #pragma unroll
            for (int off = 8; off >= 1; off >>= 1) a2 += __shfl_xor(a2, off, 64);
            const float bn = __expf(a2);
            bden += bn;
            ssum += bn * et;
        }
        const float st = ssum / (bden + 1e-9f);
        const float d = -logf(st + 1e-8f);
        const float w = 1.0f - 1.0f / (1.0f + __expf(-(d - 0.5f)));
        // scale odd (PHI) elements of own AW row, linear float4 RMW per lane
        float4* rowp = (float4*)(AW16 + ((size_t)n << 7));
        float4 rv = rowp[l];
        hf* q = (hf*)&rv;
        q[1] = (hf)((float)q[1] * w);
        q[3] = (hf)((float)q[3] * w);
        q[5] = (hf)((float)q[5] * w);
        q[7] = (hf)((float)q[7] * w);
        rowp[l] = rv;
    }
}

// ---------------- Pass tgt FUSED: one float4 gather per edge -> score + message ----------------
__global__ __launch_bounds__(256) void pass_tgt_fused_kernel(
    const int* __restrict__ rowstart_t,
    const int* __restrict__ src_sorted,
    const float* __restrict__ h,
    const hf* __restrict__ AW16,
    hf* __restrict__ m16,
    int nNodes)
{
    const int grp = threadIdx.x >> 4;
    const int l = threadIdx.x & 15;

    for (int n = blockIdx.x * 16 + grp; n < nNodes; n += gridDim.x * 16) {
        const int beg = rowstart_t[n];
        const int end = rowstart_t[n + 1];
        const float4 htv = ((const float4*)(h + (size_t)n * D))[l];
        float aden = 0.f;
        float m0 = 0.f, m1 = 0.f, m2 = 0.f, m3 = 0.f;

        int k = beg;
        for (; k + 3 < end; k += 4) {
            const int sA = src_sorted[k],     sB = src_sorted[k + 1];
            const int sC = src_sorted[k + 2], sD = src_sorted[k + 3];
            const float4 rA = ((const float4*)(AW16 + ((size_t)sA << 7)))[l];
            const float4 rB = ((const float4*)(AW16 + ((size_t)sB << 7)))[l];
            const float4 rC = ((const float4*)(AW16 + ((size_t)sC << 7)))[l];
            const float4 rD = ((const float4*)(AW16 + ((size_t)sD << 7)))[l];
            const hf* qA = (const hf*)&rA;
            const hf* qB = (const hf*)&rB;
            const hf* qC = (const hf*)&rC;
            const hf* qD = (const hf*)&rD;
            float a1 = (float)qA[0] * htv.x + (float)qA[2] * htv.y + (float)qA[4] * htv.z + (float)qA[6] * htv.w;
            float b1 = (float)qB[0] * htv.x + (float)qB[2] * htv.y + (float)qB[4] * htv.z + (float)qB[6] * htv.w;
            float c1 = (float)qC[0] * htv.x + (float)qC[2] * htv.y + (float)qC[4] * htv.z + (float)qC[6] * htv.w;
            float d1 = (float)qD[0] * htv.x + (float)qD[2] * htv.y + (float)qD[4] * htv.z + (float)qD[6] * htv.w;
            #pragma unroll
            for (int off = 8; off >= 1; off >>= 1) {
                a1 += __shfl_xor(a1, off, 64);
                b1 += __shfl_xor(b1, off, 64);
                c1 += __shfl_xor(c1, off, 64);
                d1 += __shfl_xor(d1, off, 64);
            }
            const float an0 = __expf(a1);
            const float an1 = __expf(b1);
            const float an2 = __expf(c1);
            const float an3 = __expf(d1);
            aden += an0 + an1 + an2 + an3;
            m0 += an0 * (float)qA[1] + an1 * (float)qB[1] + an2 * (float)qC[1] + an3 * (float)qD[1];
            m1 += an0 * (float)qA[3] + an1 * (float)qB[3] + an2 * (float)qC[3] + an3 * (float)qD[3];
            m2 += an0 * (float)qA[5] + an1 * (float)qB[5] + an2 * (float)qC[5] + an3 * (float)qD[5];
            m3 += an0 * (float)qA[7] + an1 * (float)qB[7] + an2 * (float)qC[7] + an3 * (float)qD[7];
        }
        for (; k < end; ++k) {
            const int s = src_sorted[k];
            const float4 r = ((const float4*)(AW16 + ((size_t)s << 7)))[l];
            const hf* q = (const hf*)&r;
            float a1 = (float)q[0] * htv.x + (float)q[2] * htv.y + (float)q[4] * htv.z + (float)q[6] * htv.w;
            #pragma unroll
            for (int off = 8; off >= 1; off >>= 1) a1 += __shfl_xor(a1, off, 64);
            const float an = __expf(a1);
            aden += an;
            m0 += an * (float)q[1];
            m1 += an * (float)q[3];
            m2 += an * (float)q[5];
            m3 += an * (float)q[7];
        }

        const float idn = 1.0f / (aden + 1e-9f);
        hf o4[4];
        o4[0] = (hf)(m0 * idn);
        o4[1] = (hf)(m1 * idn);
        o4[2] = (hf)(m2 * idn);
        o4[3] = (hf)(m3 * idn);
        ((float2*)(m16 + (size_t)n * D))[l] = *(const float2*)o4;
    }
}

// ---------------- Final: pure streaming matmuls (fp16 weights, fdot2) + relu + residual + LN ----------------
__global__ __launch_bounds__(512) void final_kernel(
    const float* __restrict__ h,
    const hf* __restrict__ m16,
    const float* __restrict__ W_self_w, const float* __restrict__ W_self_b,
    const float* __restrict__ W_A_w,    const float* __restrict__ W_A_b,
    const float* __restrict__ W_str_w,  const float* __restrict__ W_str_b,
    const float* __restrict__ ln_g,     const float* __restrict__ ln_b,
    float* __restrict__ out,
    int nNodes)
{
    __shared__ hf2 sWs2[32][D];
    __shared__ hf2 sWa2[32][D];
    __shared__ float sWstr[6 * D];
    __shared__ float sBias[D];
    __shared__ float sG[D], sB[D];
    __shared__ hf hrowh[8][D];
    __shared__ hf mrowh[8][D];

    const int tid = threadIdx.x;
    for (int idx = tid; idx < 32 * D; idx += 512) {
        const int k2 = idx >> 6, j = idx & 63;
        sWs2[k2][j] = hf2{(hf)W_self_w[(2 * k2) * D + j], (hf)W_self_w[(2 * k2 + 1) * D + j]};
        sWa2[k2][j] = hf2{(hf)W_A_w[(2 * k2) * D + j],    (hf)W_A_w[(2 * k2 + 1) * D + j]};
    }
    for (int i = tid; i < 6 * D; i += 512) sWstr[i] = W_str_w[i];
    if (tid < D) {
        sBias[tid] = W_self_b[tid] + W_A_b[tid] + W_str_b[tid];
        sG[tid] = ln_g[tid];
        sB[tid] = ln_b[tid];
    }
    __syncthreads();

    const int g = tid >> 6, j = tid & 63;
    for (int n0 = blockIdx.x * 8; n0 < nNodes; n0 += gridDim.x * 8) {
        const int n = n0 + g;
        float hj = 0.f;
        __syncthreads();
        if (n < nNodes) {
            hj = h[(size_t)n * D + j];
            hrowh[g][j] = (hf)hj;
            mrowh[g][j] = m16[(size_t)n * D + j];
        }
        __syncthreads();
        if (n < nNodes) {
            float acc = sBias[j];
            const hf2* hr = (const hf2*)hrowh[g];
            const hf2* mr = (const hf2*)mrowh[g];
            #pragma unroll
            for (int k2 = 0; k2 < 32; ++k2) {
                acc = fdot2f(sWs2[k2][j], hr[k2], acc);
                acc = fdot2f(sWa2[k2][j], mr[k2], acc);
            }
            #pragma unroll
            for (int k = 0; k < 6; ++k)
                acc += (float)hrowh[g][k] * sWstr[k * D + j];

            float pre = fmaxf(acc, 0.f) + hj;

            float mu = pre;
            #pragma unroll
            for (int off = 32; off >= 1; off >>= 1) mu += __shfl_xor(mu, off, 64);
            mu *= (1.0f / 64.0f);
            const float diff = pre - mu;
            float v = diff * diff;
            #pragma unroll
            for (int off = 32; off >= 1; off >>= 1) v += __shfl_xor(v, off, 64);
            v *= (1.0f / 64.0f);
            out[(size_t)n * D + j] = diff * rsqrtf(v + 1e-5f) * sG[j] + sB[j];
        }
    }
}

extern "C" void kernel_launch(void* const* d_in, const int* in_sizes, int n_in,
                              void* d_out, int out_size, void* d_ws, size_t ws_size,
                              hipStream_t stream) {
    const int* edge       = (const int*)d_in[0];
    const float* h        = (const float*)d_in[1];
    const float* W_att    = (const float*)d_in[2];
    const float* phi_w    = (const float*)d_in[3];
    const float* phi_b    = (const float*)d_in[4];
    const float* W_p      = (const float*)d_in[5];
    const float* W_pp     = (const float*)d_in[6];
    const float* fdef_w   = (const float*)d_in[7];
    const float* fdef_b   = (const float*)d_in[8];
    const float* W_self_w = (const float*)d_in[9];
    const float* W_self_b = (const float*)d_in[10];
    const float* W_A_w    = (const float*)d_in[11];
    const float* W_A_b    = (const float*)d_in[12];
    const float* W_str_w  = (const float*)d_in[13];
    const float* W_str_b  = (const float*)d_in[14];
    const float* ln_g     = (const float*)d_in[15];
    const float* ln_b     = (const float*)d_in[16];

    const int E = in_sizes[0] / 2;
    const int nNodes = in_sizes[1] / D;
    const int* srcI = edge;
    const int* tgtI = edge + E;

    char* ws = (char*)d_ws;
    size_t off = 0;
    auto alloc = [&](size_t bytes) { char* p = ws + off; off = (off + bytes + 255) & ~(size_t)255; return p; };

    int*    cnt_t     = (int*)   alloc((size_t)nNodes * 4);
    int*    cnt_s     = (int*)   alloc((size_t)nNodes * 4);
    const size_t zero_bytes = off;
    hf*     AW16      = (hf*)    alloc((size_t)nNodes * 2 * D * 2);  // interleaved A'|PHI
    hf*     P16       = (hf*)    alloc((size_t)nNodes * D * 2);
    hf*     PP16      = (hf*)    alloc((size_t)nNodes * D * 2);
    hf*     m16       = (hf*)    alloc((size_t)nNodes * D * 2);
    float*  enpsi     = (float*) alloc((size_t)nNodes * 4);
    int*    rank_t    = (int*)   alloc((size_t)E * 4);
    int*    rank_s    = (int*)   alloc((size_t)E * 4);
    int*    rowstart_t= (int*)   alloc(((size_t)nNodes + 1) * 4);
    int*    rowstart_s= (int*)   alloc(((size_t)nNodes + 1) * 4);
    int*    src_sorted= (int*)   alloc((size_t)E * 4);
    int*    tgt_sorted= (int*)   alloc((size_t)E * 4);
    int*    bsum      = (int*)   alloc((size_t)2 * SCAN_NB * 4);

    hipMemsetAsync(d_ws, 0, zero_bytes, stream);

    node_pre_hist_kernel<<<2048, 512, 0, stream>>>(
        h, W_att, W_p, W_pp, phi_w, phi_b, fdef_w, fdef_b,
        srcI, tgtI, cnt_t, cnt_s, rank_t, rank_s,
        AW16, P16, PP16, enpsi, nNodes, E);

    scan_partial_kernel<<<2 * SCAN_NB, 256, 0, stream>>>(cnt_t, cnt_s, bsum, nNodes);
    scan_bsum_kernel<<<1, 2 * SCAN_NB, 0, stream>>>(bsum);
    scan_final_kernel<<<2 * SCAN_NB, 256, 0, stream>>>(
        cnt_t, cnt_s, bsum, rowstart_t, rowstart_s, nNodes, E);

    scatter2_kernel<<<(E + 255) / 256, 256, 0, stream>>>(
        srcI, tgtI, rank_t, rank_s, rowstart_t, rowstart_s,
        src_sorted, tgt_sorted, E);

    pass_src_kernel<<<2048, 256, 0, stream>>>(
        rowstart_s, tgt_sorted, P16, PP16, enpsi, AW16, nNodes);

    pass_tgt_fused_kernel<<<2048, 256, 0, stream>>>(
        rowstart_t, src_sorted, h, AW16, m16, nNodes);

    final_kernel<<<2048, 512, 0, stream>>>(
        h, m16, W_self_w, W_self_b, W_A_w, W_A_b,
        W_str_w, W_str_b, ln_g, ln_b, (float*)d_out, nNodes);
}

// Round 12
// 192.764 us; speedup vs baseline: 2.4231x; 1.1383x over previous
//
#include <hip/hip_runtime.h>
#include <math.h>

#define D 64
#define NB 256        // blocks per direction for bucket hist/scatter
#define SCAN_NB 256   // blocks per scan pass

typedef _Float16 hf;
typedef _Float16 hf2 __attribute__((ext_vector_type(2)));

__device__ inline float fdot2f(hf2 a, hf2 b, float c) {
#if __has_builtin(__builtin_amdgcn_fdot2)
    return __builtin_amdgcn_fdot2(a, b, c, false);
#else
    return (float)a[0] * (float)b[0] + (float)a[1] * (float)b[1] + c;
#endif
}

// ---------------- Kernel 1: per-node linear transforms (fp16 weights, fdot2) ----------------
// AW16[n][2j]=A'_j (A + structural fold), AW16[n][2j+1]=PHI_j; P16/PP16 fp16; enpsi=exp(-psi).
__global__ __launch_bounds__(512) void node_pre_kernel(
    const float* __restrict__ h,
    const float* __restrict__ W_att,
    const float* __restrict__ W_p,
    const float* __restrict__ W_pp,
    const float* __restrict__ phi_w,
    const float* __restrict__ phi_b,
    const float* __restrict__ fdef_w,
    const float* __restrict__ fdef_b,
    hf* __restrict__ AW16,
    hf* __restrict__ P16,
    hf* __restrict__ PP16,
    float* __restrict__ enpsi,
    int nNodes)
{
    __shared__ hf2 sW2[4][32][D];        // 32 KB
    __shared__ hf  hrowh[8][D];
    __shared__ float sPhib[D];
    __shared__ float sFdef[D];

    const int tid = threadIdx.x;
    const float* Wm[4] = { W_att, W_p, W_pp, phi_w };
    for (int idx = tid; idx < 4 * 32 * D; idx += 512) {
        const int m  = idx >> 11;
        const int k2 = (idx >> 6) & 31;
        const int j  = idx & 63;
        sW2[m][k2][j] = hf2{(hf)Wm[m][(2 * k2) * D + j], (hf)Wm[m][(2 * k2 + 1) * D + j]};
    }
    if (tid < D) { sPhib[tid] = phi_b[tid]; sFdef[tid] = fdef_w[tid]; }
    __syncthreads();
    const float fb = fdef_b[0];

    const int g = tid >> 6;
    const int j = tid & 63;

    for (int n0 = blockIdx.x * 8; n0 < nNodes; n0 += gridDim.x * 8) {
        const int n = n0 + g;
        float hj = 0.f;
        __syncthreads();
        if (n < nNodes) {
            hj = h[(size_t)n * D + j];
            hrowh[g][j] = (hf)hj;
        }
        __syncthreads();
        if (n < nNodes) {
            float a = 0.f, p = 0.f, pp = 0.f, ph = sPhib[j];
            const hf2* hr = (const hf2*)hrowh[g];
            #pragma unroll
            for (int k2 = 0; k2 < 32; ++k2) {
                const hf2 hb = hr[k2];
                a  = fdot2f(sW2[0][k2][j], hb, a);
                p  = fdot2f(sW2[1][k2][j], hb, p);
                pp = fdot2f(sW2[2][k2][j], hb, pp);
                ph = fdot2f(sW2[3][k2][j], hb, ph);
            }
            if (j < 6) a += hj;   // structural-dot fold: A' = A + s_feat
            const size_t base = (size_t)n * D + j;
            AW16[((size_t)n << 7) + 2 * j]     = (hf)a;
            AW16[((size_t)n << 7) + 2 * j + 1] = (hf)ph;
            P16[base]  = (hf)p;
            PP16[base] = (hf)pp;
            float ps = hj * sFdef[j];
            #pragma unroll
            for (int off = 32; off >= 1; off >>= 1) ps += __shfl_xor(ps, off, 64);
            if (j == 0) enpsi[n] = __expf(-(ps + fb));
        }
    }
}

// ---------------- Bucket hist: LDS-only atomics. grid = 2*NB (dir 0: key=tgt, dir 1: key=src) ----------------
__global__ __launch_bounds__(256) void bucket_hist_kernel(
    const int* __restrict__ tgtI, const int* __restrict__ srcI,
    int* __restrict__ ghist_t, int* __restrict__ ghist_s,
    int nBkt, int nEdges)
{
    __shared__ int hist[2048];
    const int dir = blockIdx.x / NB;
    const int b = blockIdx.x % NB;
    const int* keys = dir ? srcI : tgtI;
    int* gh = dir ? ghist_s : ghist_t;
    const int tid = threadIdx.x;
    for (int d = tid; d < nBkt; d += 256) hist[d] = 0;
    __syncthreads();
    const int C = (nEdges + NB - 1) / NB;
    const int beg = b * C;
    const int end = min(beg + C, nEdges);
    for (int e = beg + tid; e < end; e += 256)
        atomicAdd(&hist[keys[e] >> 5], 1);
    __syncthreads();
    for (int d = tid; d < nBkt; d += 256)
        gh[(size_t)d * NB + b] = hist[d];
}

// ---------------- Scan step 1: per-block partial sums over L = nBkt*NB ----------------
__global__ __launch_bounds__(256) void scan_partial_kernel(
    const int* __restrict__ in_t, const int* __restrict__ in_s,
    int* __restrict__ bsum, int L)
{
    const int pass = blockIdx.x >> 8;
    const int b = blockIdx.x & (SCAN_NB - 1);
    const int* in = pass ? in_s : in_t;
    const int C = (L + SCAN_NB - 1) / SCAN_NB;
    const int K = (C + 255) / 256;
    const int base = b * C;
    const int lim = min(base + C, L);
    const int tbeg = base + threadIdx.x * K;
    const int tend = min(tbeg + K, lim);
    int tsum = 0;
    for (int i = tbeg; i < tend; ++i) tsum += in[i];
    __shared__ int red[256];
    red[threadIdx.x] = tsum;
    __syncthreads();
    for (int off = 128; off >= 1; off >>= 1) {
        if (threadIdx.x < off) red[threadIdx.x] += red[threadIdx.x + off];
        __syncthreads();
    }
    if (threadIdx.x == 0) bsum[pass * SCAN_NB + b] = red[0];
}

// ---------------- Scan step 2: scan the 2*SCAN_NB block sums ----------------
__global__ __launch_bounds__(512) void scan_bsum_kernel(int* __restrict__ bsum)
{
    __shared__ int s[2 * SCAN_NB];
    const int tid = threadIdx.x;
    const int orig = bsum[tid];
    s[tid] = orig;
    __syncthreads();
    const int seg = tid & (SCAN_NB - 1);
    for (int off = 1; off < SCAN_NB; off <<= 1) {
        const int add = (seg >= off) ? s[tid - off] : 0;
        __syncthreads();
        s[tid] += add;
        __syncthreads();
    }
    bsum[tid] = s[tid] - orig;
}

// ---------------- Scan step 3: intra-chunk exclusive scan + offset -> gsc ----------------
__global__ __launch_bounds__(256) void scan_final_kernel(
    const int* __restrict__ in_t, const int* __restrict__ in_s,
    const int* __restrict__ bsum,
    int* __restrict__ gsc_t, int* __restrict__ gsc_s, int L)
{
    const int pass = blockIdx.x >> 8;
    const int b = blockIdx.x & (SCAN_NB - 1);
    const int* in = pass ? in_s : in_t;
    int* out = pass ? gsc_s : gsc_t;
    const int C = (L + SCAN_NB - 1) / SCAN_NB;
    const int K = (C + 255) / 256;
    const int base = b * C;
    const int lim = min(base + C, L);
    const int tbeg = base + threadIdx.x * K;
    const int tend = min(tbeg + K, lim);
    int tsum = 0;
    for (int i = tbeg; i < tend; ++i) tsum += in[i];
    __shared__ int s[256];
    s[threadIdx.x] = tsum;
    __syncthreads();
    for (int off = 1; off < 256; off <<= 1) {
        const int add = (threadIdx.x >= off) ? s[threadIdx.x - off] : 0;
        __syncthreads();
        s[threadIdx.x] += add;
        __syncthreads();
    }
    int run = s[threadIdx.x] - tsum + bsum[pass * SCAN_NB + b];
    for (int i = tbeg; i < tend; ++i) { out[i] = run; run += in[i]; }
}

// ---------------- Bucket scatter: LDS cursors from gsc; packed (key<<16)|payload ----------------
__global__ __launch_bounds__(256) void bucket_scatter_kernel(
    const int* __restrict__ tgtI, const int* __restrict__ srcI,
    const int* __restrict__ gsc_t, const int* __restrict__ gsc_s,
    unsigned* __restrict__ ep_t, unsigned* __restrict__ ep_s,
    int nBkt, int nEdges)
{
    __shared__ int cursor[2048];
    const int dir = blockIdx.x / NB;
    const int b = blockIdx.x % NB;
    const int* keys = dir ? srcI : tgtI;
    const int* pays = dir ? tgtI : srcI;
    const int* gsc = dir ? gsc_s : gsc_t;
    unsigned* ep = dir ? ep_s : ep_t;
    const int tid = threadIdx.x;
    for (int d = tid; d < nBkt; d += 256) cursor[d] = gsc[(size_t)d * NB + b];
    __syncthreads();
    const int C = (nEdges + NB - 1) / NB;
    const int beg = b * C;
    const int end = min(beg + C, nEdges);
    for (int e = beg + tid; e < end; e += 256) {
        const unsigned k = (unsigned)keys[e];
        const unsigned p = (unsigned)pays[e];
        const int pos = atomicAdd(&cursor[k >> 5], 1);
        ep[pos] = (k << 16) | p;
    }
}

// ---------------- Per-bucket counting sort (32 bins) -> sorted payloads + rowstart ----------------
// grid = 2*nBkt (dir 0: tgt-CSR, dir 1: src-CSR)
__global__ __launch_bounds__(256) void bucket_sort_kernel(
    const unsigned* __restrict__ ep_t, const unsigned* __restrict__ ep_s,
    const int* __restrict__ gsc_t, const int* __restrict__ gsc_s,
    int* __restrict__ src_sorted, int* __restrict__ tgt_sorted,
    int* __restrict__ rowstart_t, int* __restrict__ rowstart_s,
    int nBkt, int nNodes, int nEdges)
{
    __shared__ int hist[32], pref[32], cur[32];
    const int dir = (int)(blockIdx.x >= (unsigned)nBkt);
    const int b = blockIdx.x - dir * nBkt;
    const unsigned* ep = dir ? ep_s : ep_t;
    const int* gsc = dir ? gsc_s : gsc_t;
    int* out = dir ? tgt_sorted : src_sorted;
    int* rowstart = dir ? rowstart_s : rowstart_t;
    const int tid = threadIdx.x;

    if (blockIdx.x == 0 && tid == 0) rowstart_t[nNodes] = nEdges;
    if (blockIdx.x == (unsigned)nBkt && tid == 0) rowstart_s[nNodes] = nEdges;

    const int s = gsc[(size_t)b * NB];
    const int e = (b + 1 < nBkt) ? gsc[(size_t)(b + 1) * NB] : nEdges;
    const int size = e - s;

    if (tid < 32) hist[tid] = 0;
    __syncthreads();
    for (int i = tid; i < size; i += 256)
        atomicAdd(&hist[(ep[s + i] >> 16) & 31], 1);
    __syncthreads();
    if (tid == 0) {
        int r = 0;
        for (int k = 0; k < 32; ++k) { pref[k] = r; cur[k] = r; r += hist[k]; }
    }
    __syncthreads();
    if (tid < 32) {
        const int key = (b << 5) + tid;
        if (key < nNodes) rowstart[key] = s + pref[tid];
    }
    __syncthreads();
    for (int i = tid; i < size; i += 256) {
        const unsigned v = ep[s + i];
        const int pos = atomicAdd(&cur[(v >> 16) & 31], 1);
        out[s + pos] = (int)(v & 0xFFFFu);
    }
}

// ---------------- Pass src: pair/beta -> w1m, scale odd (PHI) slots of AW in place ----------------
__global__ __launch_bounds__(256) void pass_src_kernel(
    const int* __restrict__ rowstart_s,
    const int* __restrict__ tgt_sorted,
    const hf* __restrict__ P16,
    const hf* __restrict__ PP16,
    const float* __restrict__ enpsi,
    hf* __restrict__ AW16,
    int nNodes)
{
    const int grp = threadIdx.x >> 4;
    const int l = threadIdx.x & 15;

    for (int n = blockIdx.x * 16 + grp; n < nNodes; n += gridDim.x * 16) {
        const int beg = rowstart_s[n];
        const int end = rowstart_s[n + 1];
        const float2 pr = ((const float2*)(P16 + (size_t)n * D))[l];
        const hf* pq = (const hf*)&pr;
        const float p0 = pq[0], p1 = pq[1], p2 = pq[2], p3 = pq[3];
        float bden = 0.f, ssum = 0.f;

        int k = beg;
        for (; k + 3 < end; k += 4) {
            const int tA = tgt_sorted[k],     tB = tgt_sorted[k + 1];
            const int tC = tgt_sorted[k + 2], tD = tgt_sorted[k + 3];
            const float2 rA = ((const float2*)(PP16 + (size_t)tA * D))[l];
            const float2 rB = ((const float2*)(PP16 + (size_t)tB * D))[l];
            const float2 rC = ((const float2*)(PP16 + (size_t)tC * D))[l];
            const float2 rD = ((const float2*)(PP16 + (size_t)tD * D))[l];
            const float eA = enpsi[tA], eB = enpsi[tB], eC = enpsi[tC], eD = enpsi[tD];
            const hf* qA = (const hf*)&rA;
            const hf* qB = (const hf*)&rB;
            const hf* qC = (const hf*)&rC;
            const hf* qD = (const hf*)&rD;
            float a2 = (float)qA[0] * p0 + (float)qA[1] * p1 + (float)qA[2] * p2 + (float)qA[3] * p3;
            float b2 = (float)qB[0] * p0 + (float)qB[1] * p1 + (float)qB[2] * p2 + (float)qB[3] * p3;
            float c2 = (float)qC[0] * p0 + (float)qC[1] * p1 + (float)qC[2] * p2 + (float)qC[3] * p3;
            float d2 = (float)qD[0] * p0 + (float)qD[1] * p1 + (float)qD[2] * p2 + (float)qD[3] * p3;
            #pragma unroll
            for (int off = 8; off >= 1; off >>= 1) {
                a2 += __shfl_xor(a2, off, 64);
                b2 += __shfl_xor(b2, off, 64);
                c2 += __shfl_xor(c2, off, 64);
                d2 += __shfl_xor(d2, off, 64);
            }
            const float bn0 = __expf(a2);
            const float bn1 = __expf(b2);
            const float bn2 = __expf(c2);
            const float bn3 = __expf(d2);
            bden += bn0 + bn1 + bn2 + bn3;
            ssum += bn0 * eA + bn1 * eB + bn2 * eC + bn3 * eD;
        }
        for (; k < end; ++k) {
            const int t = tgt_sorted[k];
            const float2 r = ((const float2*)(PP16 + (size_t)t * D))[l];
            const float et = enpsi[t];
            const hf* q = (const hf*)&r;
            float a2 = (float)q[0] * p0 + (float)q[1] * p1 + (float)q[2] * p2 + (float)q[3] * p3;
            #pragma unroll
            for (int off = 8; off >= 1; off >>= 1) a2 += __shfl_xor(a2, off, 64);
            const float bn = __expf(a2);
            bden += bn;
            ssum += bn * et;
        }
        const float st = ssum / (bden + 1e-9f);
        const float d = -logf(st + 1e-8f);
        const float w = 1.0f - 1.0f / (1.0f + __expf(-(d - 0.5f)));
        float4* rowp = (float4*)(AW16 + ((size_t)n << 7));
        float4 rv = rowp[l];
        hf* q = (hf*)&rv;
        q[1] = (hf)((float)q[1] * w);
        q[3] = (hf)((float)q[3] * w);
        q[5] = (hf)((float)q[5] * w);
        q[7] = (hf)((float)q[7] * w);
        rowp[l] = rv;
    }
}

// ---------------- Pass tgt FUSED: one float4 gather per edge -> score + message ----------------
__global__ __launch_bounds__(256) void pass_tgt_fused_kernel(
    const int* __restrict__ rowstart_t,
    const int* __restrict__ src_sorted,
    const float* __restrict__ h,
    const hf* __restrict__ AW16,
    hf* __restrict__ m16,
    int nNodes)
{
    const int grp = threadIdx.x >> 4;
    const int l = threadIdx.x & 15;

    for (int n = blockIdx.x * 16 + grp; n < nNodes; n += gridDim.x * 16) {
        const int beg = rowstart_t[n];
        const int end = rowstart_t[n + 1];
        const float4 htv = ((const float4*)(h + (size_t)n * D))[l];
        float aden = 0.f;
        float m0 = 0.f, m1 = 0.f, m2 = 0.f, m3 = 0.f;

        int k = beg;
        for (; k + 3 < end; k += 4) {
            const int sA = src_sorted[k],     sB = src_sorted[k + 1];
            const int sC = src_sorted[k + 2], sD = src_sorted[k + 3];
            const float4 rA = ((const float4*)(AW16 + ((size_t)sA << 7)))[l];
            const float4 rB = ((const float4*)(AW16 + ((size_t)sB << 7)))[l];
            const float4 rC = ((const float4*)(AW16 + ((size_t)sC << 7)))[l];
            const float4 rD = ((const float4*)(AW16 + ((size_t)sD << 7)))[l];
            const hf* qA = (const hf*)&rA;
            const hf* qB = (const hf*)&rB;
            const hf* qC = (const hf*)&rC;
            const hf* qD = (const hf*)&rD;
            float a1 = (float)qA[0] * htv.x + (float)qA[2] * htv.y + (float)qA[4] * htv.z + (float)qA[6] * htv.w;
            float b1 = (float)qB[0] * htv.x + (float)qB[2] * htv.y + (float)qB[4] * htv.z + (float)qB[6] * htv.w;
            float c1 = (float)qC[0] * htv.x + (float)qC[2] * htv.y + (float)qC[4] * htv.z + (float)qC[6] * htv.w;
            float d1 = (float)qD[0] * htv.x + (float)qD[2] * htv.y + (float)qD[4] * htv.z + (float)qD[6] * htv.w;
            #pragma unroll
            for (int off = 8; off >= 1; off >>= 1) {
                a1 += __shfl_xor(a1, off, 64);
                b1 += __shfl_xor(b1, off, 64);
                c1 += __shfl_xor(c1, off, 64);
                d1 += __shfl_xor(d1, off, 64);
            }
            const float an0 = __expf(a1);
            const float an1 = __expf(b1);
            const float an2 = __expf(c1);
            const float an3 = __expf(d1);
            aden += an0 + an1 + an2 + an3;
            m0 += an0 * (float)qA[1] + an1 * (float)qB[1] + an2 * (float)qC[1] + an3 * (float)qD[1];
            m1 += an0 * (float)qA[3] + an1 * (float)qB[3] + an2 * (float)qC[3] + an3 * (float)qD[3];
            m2 += an0 * (float)qA[5] + an1 * (float)qB[5] + an2 * (float)qC[5] + an3 * (float)qD[5];
            m3 += an0 * (float)qA[7] + an1 * (float)qB[7] + an2 * (float)qC[7] + an3 * (float)qD[7];
        }
        for (; k < end; ++k) {
            const int s = src_sorted[k];
            const float4 r = ((const float4*)(AW16 + ((size_t)s << 7)))[l];
            const hf* q = (const hf*)&r;
            float a1 = (float)q[0] * htv.x + (float)q[2] * htv.y + (float)q[4] * htv.z + (float)q[6] * htv.w;
            #pragma unroll
            for (int off = 8; off >= 1; off >>= 1) a1 += __shfl_xor(a1, off, 64);
            const float an = __expf(a1);
            aden += an;
            m0 += an * (float)q[1];
            m1 += an * (float)q[3];
            m2 += an * (float)q[5];
            m3 += an * (float)q[7];
        }

        const float idn = 1.0f / (aden + 1e-9f);
        hf o4[4];
        o4[0] = (hf)(m0 * idn);
        o4[1] = (hf)(m1 * idn);
        o4[2] = (hf)(m2 * idn);
        o4[3] = (hf)(m3 * idn);
        ((float2*)(m16 + (size_t)n * D))[l] = *(const float2*)o4;
    }
}

// ---------------- Final: pure streaming matmuls (fp16 weights, fdot2) + relu + residual + LN ----------------
__global__ __launch_bounds__(512) void final_kernel(
    const float* __restrict__ h,
    const hf* __restrict__ m16,
    const float* __restrict__ W_self_w, const float* __restrict__ W_self_b,
    const float* __restrict__ W_A_w,    const float* __restrict__ W_A_b,
    const float* __restrict__ W_str_w,  const float* __restrict__ W_str_b,
    const float* __restrict__ ln_g,     const float* __restrict__ ln_b,
    float* __restrict__ out,
    int nNodes)
{
    __shared__ hf2 sWs2[32][D];
    __shared__ hf2 sWa2[32][D];
    __shared__ float sWstr[6 * D];
    __shared__ float sBias[D];
    __shared__ float sG[D], sB[D];
    __shared__ hf hrowh[8][D];
    __shared__ hf mrowh[8][D];

    const int tid = threadIdx.x;
    for (int idx = tid; idx < 32 * D; idx += 512) {
        const int k2 = idx >> 6, j = idx & 63;
        sWs2[k2][j] = hf2{(hf)W_self_w[(2 * k2) * D + j], (hf)W_self_w[(2 * k2 + 1) * D + j]};
        sWa2[k2][j] = hf2{(hf)W_A_w[(2 * k2) * D + j],    (hf)W_A_w[(2 * k2 + 1) * D + j]};
    }
    for (int i = tid; i < 6 * D; i += 512) sWstr[i] = W_str_w[i];
    if (tid < D) {
        sBias[tid] = W_self_b[tid] + W_A_b[tid] + W_str_b[tid];
        sG[tid] = ln_g[tid];
        sB[tid] = ln_b[tid];
    }
    __syncthreads();

    const int g = tid >> 6, j = tid & 63;
    for (int n0 = blockIdx.x * 8; n0 < nNodes; n0 += gridDim.x * 8) {
        const int n = n0 + g;
        float hj = 0.f;
        __syncthreads();
        if (n < nNodes) {
            hj = h[(size_t)n * D + j];
            hrowh[g][j] = (hf)hj;
            mrowh[g][j] = m16[(size_t)n * D + j];
        }
        __syncthreads();
        if (n < nNodes) {
            float acc = sBias[j];
            const hf2* hr = (const hf2*)hrowh[g];
            const hf2* mr = (const hf2*)mrowh[g];
            #pragma unroll
            for (int k2 = 0; k2 < 32; ++k2) {
                acc = fdot2f(sWs2[k2][j], hr[k2], acc);
                acc = fdot2f(sWa2[k2][j], mr[k2], acc);
            }
            #pragma unroll
            for (int k = 0; k < 6; ++k)
                acc += (float)hrowh[g][k] * sWstr[k * D + j];

            float pre = fmaxf(acc, 0.f) + hj;

            float mu = pre;
            #pragma unroll
            for (int off = 32; off >= 1; off >>= 1) mu += __shfl_xor(mu, off, 64);
            mu *= (1.0f / 64.0f);
            const float diff = pre - mu;
            float v = diff * diff;
            #pragma unroll
            for (int off = 32; off >= 1; off >>= 1) v += __shfl_xor(v, off, 64);
            v *= (1.0f / 64.0f);
            out[(size_t)n * D + j] = diff * rsqrtf(v + 1e-5f) * sG[j] + sB[j];
        }
    }
}

extern "C" void kernel_launch(void* const* d_in, const int* in_sizes, int n_in,
                              void* d_out, int out_size, void* d_ws, size_t ws_size,
                              hipStream_t stream) {
    const int* edge       = (const int*)d_in[0];
    const float* h        = (const float*)d_in[1];
    const float* W_att    = (const float*)d_in[2];
    const float* phi_w    = (const float*)d_in[3];
    const float* phi_b    = (const float*)d_in[4];
    const float* W_p      = (const float*)d_in[5];
    const float* W_pp     = (const float*)d_in[6];
    const float* fdef_w   = (const float*)d_in[7];
    const float* fdef_b   = (const float*)d_in[8];
    const float* W_self_w = (const float*)d_in[9];
    const float* W_self_b = (const float*)d_in[10];
    const float* W_A_w    = (const float*)d_in[11];
    const float* W_A_b    = (const float*)d_in[12];
    const float* W_str_w  = (const float*)d_in[13];
    const float* W_str_b  = (const float*)d_in[14];
    const float* ln_g     = (const float*)d_in[15];
    const float* ln_b     = (const float*)d_in[16];

    const int E = in_sizes[0] / 2;
    const int nNodes = in_sizes[1] / D;
    const int* srcI = edge;
    const int* tgtI = edge + E;
    const int nBkt = (nNodes + 31) / 32;          // 1563 for N=50000 (fits 2048 LDS slots)
    const int L = nBkt * NB;                      // scan length per direction

    char* ws = (char*)d_ws;
    size_t off = 0;
    auto alloc = [&](size_t bytes) { char* p = ws + off; off = (off + bytes + 255) & ~(size_t)255; return p; };

    hf*       AW16      = (hf*)      alloc((size_t)nNodes * 2 * D * 2);  // interleaved A'|PHI
    hf*       P16       = (hf*)      alloc((size_t)nNodes * D * 2);
    hf*       PP16      = (hf*)      alloc((size_t)nNodes * D * 2);
    hf*       m16       = (hf*)      alloc((size_t)nNodes * D * 2);
    float*    enpsi     = (float*)   alloc((size_t)nNodes * 4);
    int*      ghist_t   = (int*)     alloc((size_t)L * 4);
    int*      ghist_s   = (int*)     alloc((size_t)L * 4);
    int*      gsc_t     = (int*)     alloc((size_t)L * 4);
    int*      gsc_s     = (int*)     alloc((size_t)L * 4);
    unsigned* ep_t      = (unsigned*)alloc((size_t)E * 4);
    unsigned* ep_s      = (unsigned*)alloc((size_t)E * 4);
    int*      src_sorted= (int*)     alloc((size_t)E * 4);
    int*      tgt_sorted= (int*)     alloc((size_t)E * 4);
    int*      rowstart_t= (int*)     alloc(((size_t)nNodes + 1) * 4);
    int*      rowstart_s= (int*)     alloc(((size_t)nNodes + 1) * 4);
    int*      bsum      = (int*)     alloc((size_t)2 * SCAN_NB * 4);

    node_pre_kernel<<<2048, 512, 0, stream>>>(
        h, W_att, W_p, W_pp, phi_w, phi_b, fdef_w, fdef_b,
        AW16, P16, PP16, enpsi, nNodes);

    bucket_hist_kernel<<<2 * NB, 256, 0, stream>>>(
        tgtI, srcI, ghist_t, ghist_s, nBkt, E);

    scan_partial_kernel<<<2 * SCAN_NB, 256, 0, stream>>>(ghist_t, ghist_s, bsum, L);
    scan_bsum_kernel<<<1, 2 * SCAN_NB, 0, stream>>>(bsum);
    scan_final_kernel<<<2 * SCAN_NB, 256, 0, stream>>>(
        ghist_t, ghist_s, bsum, gsc_t, gsc_s, L);

    bucket_scatter_kernel<<<2 * NB, 256, 0, stream>>>(
        tgtI, srcI, gsc_t, gsc_s, ep_t, ep_s, nBkt, E);

    bucket_sort_kernel<<<2 * nBkt, 256, 0, stream>>>(
        ep_t, ep_s, gsc_t, gsc_s, src_sorted, tgt_sorted,
        rowstart_t, rowstart_s, nBkt, nNodes, E);

    pass_src_kernel<<<2048, 256, 0, stream>>>(
        rowstart_s, tgt_sorted, P16, PP16, enpsi, AW16, nNodes);

    pass_tgt_fused_kernel<<<2048, 256, 0, stream>>>(
        rowstart_t, src_sorted, h, AW16, m16, nNodes);

    final_kernel<<<2048, 512, 0, stream>>>(
        h, m16, W_self_w, W_self_b, W_A_w, W_A_b,
        W_str_w, W_str_b, ln_g, ln_b, (float*)d_out, nNodes);
}

// Round 13
// 174.447 us; speedup vs baseline: 2.6776x; 1.1050x over previous
//
#include <hip/hip_runtime.h>
#include <math.h>

#define D 64
#define NB 256        // blocks per direction for bucket hist/scatter
#define SCAN_NB 256   // blocks per scan pass

typedef _Float16 hf;
typedef _Float16 hf2 __attribute__((ext_vector_type(2)));

__device__ inline float fdot2f(hf2 a, hf2 b, float c) {
#if __has_builtin(__builtin_amdgcn_fdot2)
    return __builtin_amdgcn_fdot2(a, b, c, false);
#else
    return (float)a[0] * (float)b[0] + (float)a[1] * (float)b[1] + c;
#endif
}

// ---------------- Kernel 1: per-node linear transforms, 4 nodes per thread ----------------
// AW16[n][2j]=A'_j (A + structural fold), AW16[n][2j+1]=PHI_j; P16/PP16 fp16; enpsi=exp(-psi).
// One block = 32 nodes, exactly one iteration (grid = ceil(n/32)).
__global__ __launch_bounds__(512) void node_pre_kernel(
    const float* __restrict__ h,
    const float* __restrict__ W_att,
    const float* __restrict__ W_p,
    const float* __restrict__ W_pp,
    const float* __restrict__ phi_w,
    const float* __restrict__ phi_b,
    const float* __restrict__ fdef_w,
    const float* __restrict__ fdef_b,
    hf* __restrict__ AW16,
    hf* __restrict__ P16,
    hf* __restrict__ PP16,
    float* __restrict__ enpsi,
    int nNodes)
{
    __shared__ hf2 sW2[4][32][D];        // 32 KB
    __shared__ hf  hall[32][D];          // 4 KB (32 node rows, fp16)
    __shared__ float sPhib[D];
    __shared__ float sFdef[D];

    const int tid = threadIdx.x;
    const float* Wm[4] = { W_att, W_p, W_pp, phi_w };
    for (int idx = tid; idx < 4 * 32 * D; idx += 512) {
        const int m  = idx >> 11;
        const int k2 = (idx >> 6) & 31;
        const int j  = idx & 63;
        sW2[m][k2][j] = hf2{(hf)Wm[m][(2 * k2) * D + j], (hf)Wm[m][(2 * k2 + 1) * D + j]};
    }
    if (tid < D) { sPhib[tid] = phi_b[tid]; sFdef[tid] = fdef_w[tid]; }
    __syncthreads();
    const float fb = fdef_b[0];

    // ---- stage 32 h-rows (f32 -> fp16) + fused psi partial-dot ----
    const int n0 = blockIdx.x * 32;
    {
        const int base = tid * 4;          // 0..2047
        const int ln = base >> 6;          // local node 0..31
        const int col = base & 63;
        const int n = n0 + ln;
        float ps = 0.f;
        if (n < nNodes) {
            const float4 v = *(const float4*)(h + (size_t)n * D + col);
            hall[ln][col]     = (hf)v.x;
            hall[ln][col + 1] = (hf)v.y;
            hall[ln][col + 2] = (hf)v.z;
            hall[ln][col + 3] = (hf)v.w;
            ps = v.x * sFdef[col] + v.y * sFdef[col + 1]
               + v.z * sFdef[col + 2] + v.w * sFdef[col + 3];
        }
        // reduce across the 16 threads that share a row (aligned 16-lane group)
        #pragma unroll
        for (int off = 8; off >= 1; off >>= 1) ps += __shfl_xor(ps, off, 64);
        if ((tid & 15) == 0 && n < nNodes) enpsi[n] = __expf(-(ps + fb));
    }
    __syncthreads();

    // ---- compute: wave g handles local nodes 4g..4g+3; weight read reused x4 ----
    const int g = tid >> 6;
    const int j = tid & 63;
    const int ln0 = 4 * g;

    float acc[4][4];   // [node][matrix: A, P, PP, PHI]
    #pragma unroll
    for (int m = 0; m < 4; ++m) {
        acc[m][0] = 0.f; acc[m][1] = 0.f; acc[m][2] = 0.f; acc[m][3] = sPhib[j];
    }
    const hf2* hr0 = (const hf2*)hall[ln0 + 0];
    const hf2* hr1 = (const hf2*)hall[ln0 + 1];
    const hf2* hr2 = (const hf2*)hall[ln0 + 2];
    const hf2* hr3 = (const hf2*)hall[ln0 + 3];

    #pragma unroll 8
    for (int k2 = 0; k2 < 32; ++k2) {
        const hf2 w0 = sW2[0][k2][j];
        const hf2 w1 = sW2[1][k2][j];
        const hf2 w2 = sW2[2][k2][j];
        const hf2 w3 = sW2[3][k2][j];
        const hf2 h0 = hr0[k2];
        const hf2 h1 = hr1[k2];
        const hf2 h2 = hr2[k2];
        const hf2 h3 = hr3[k2];
        acc[0][0] = fdot2f(w0, h0, acc[0][0]);
        acc[0][1] = fdot2f(w1, h0, acc[0][1]);
        acc[0][2] = fdot2f(w2, h0, acc[0][2]);
        acc[0][3] = fdot2f(w3, h0, acc[0][3]);
        acc[1][0] = fdot2f(w0, h1, acc[1][0]);
        acc[1][1] = fdot2f(w1, h1, acc[1][1]);
        acc[1][2] = fdot2f(w2, h1, acc[1][2]);
        acc[1][3] = fdot2f(w3, h1, acc[1][3]);
        acc[2][0] = fdot2f(w0, h2, acc[2][0]);
        acc[2][1] = fdot2f(w1, h2, acc[2][1]);
        acc[2][2] = fdot2f(w2, h2, acc[2][2]);
        acc[2][3] = fdot2f(w3, h2, acc[2][3]);
        acc[3][0] = fdot2f(w0, h3, acc[3][0]);
        acc[3][1] = fdot2f(w1, h3, acc[3][1]);
        acc[3][2] = fdot2f(w2, h3, acc[3][2]);
        acc[3][3] = fdot2f(w3, h3, acc[3][3]);
    }

    #pragma unroll
    for (int m = 0; m < 4; ++m) {
        const int n = n0 + ln0 + m;
        if (n < nNodes) {
            float a = acc[m][0];
            if (j < 6) a += (float)hall[ln0 + m][j];   // structural fold: A' = A + s_feat
            const size_t base = (size_t)n * D + j;
            *(hf2*)(AW16 + ((size_t)n << 7) + 2 * j) = hf2{(hf)a, (hf)acc[m][3]};
            P16[base]  = (hf)acc[m][1];
            PP16[base] = (hf)acc[m][2];
        }
    }
}

// ---------------- Bucket hist: LDS-only atomics. grid = 2*NB ----------------
__global__ __launch_bounds__(256) void bucket_hist_kernel(
    const int* __restrict__ tgtI, const int* __restrict__ srcI,
    int* __restrict__ ghist_t, int* __restrict__ ghist_s,
    int nBkt, int nEdges)
{
    __shared__ int hist[2048];
    const int dir = blockIdx.x / NB;
    const int b = blockIdx.x % NB;
    const int* keys = dir ? srcI : tgtI;
    int* gh = dir ? ghist_s : ghist_t;
    const int tid = threadIdx.x;
    for (int d = tid; d < nBkt; d += 256) hist[d] = 0;
    __syncthreads();
    const int C = (nEdges + NB - 1) / NB;
    const int beg = b * C;
    const int end = min(beg + C, nEdges);
    for (int e = beg + tid; e < end; e += 256)
        atomicAdd(&hist[keys[e] >> 5], 1);
    __syncthreads();
    for (int d = tid; d < nBkt; d += 256)
        gh[(size_t)d * NB + b] = hist[d];
}

// ---------------- Scan step 1 ----------------
__global__ __launch_bounds__(256) void scan_partial_kernel(
    const int* __restrict__ in_t, const int* __restrict__ in_s,
    int* __restrict__ bsum, int L)
{
    const int pass = blockIdx.x >> 8;
    const int b = blockIdx.x & (SCAN_NB - 1);
    const int* in = pass ? in_s : in_t;
    const int C = (L + SCAN_NB - 1) / SCAN_NB;
    const int K = (C + 255) / 256;
    const int base = b * C;
    const int lim = min(base + C, L);
    const int tbeg = base + threadIdx.x * K;
    const int tend = min(tbeg + K, lim);
    int tsum = 0;
    for (int i = tbeg; i < tend; ++i) tsum += in[i];
    __shared__ int red[256];
    red[threadIdx.x] = tsum;
    __syncthreads();
    for (int off = 128; off >= 1; off >>= 1) {
        if (threadIdx.x < off) red[threadIdx.x] += red[threadIdx.x + off];
        __syncthreads();
    }
    if (threadIdx.x == 0) bsum[pass * SCAN_NB + b] = red[0];
}

// ---------------- Scan step 2 ----------------
__global__ __launch_bounds__(512) void scan_bsum_kernel(int* __restrict__ bsum)
{
    __shared__ int s[2 * SCAN_NB];
    const int tid = threadIdx.x;
    const int orig = bsum[tid];
    s[tid] = orig;
    __syncthreads();
    const int seg = tid & (SCAN_NB - 1);
    for (int off = 1; off < SCAN_NB; off <<= 1) {
        const int add = (seg >= off) ? s[tid - off] : 0;
        __syncthreads();
        s[tid] += add;
        __syncthreads();
    }
    bsum[tid] = s[tid] - orig;
}

// ---------------- Scan step 3 ----------------
__global__ __launch_bounds__(256) void scan_final_kernel(
    const int* __restrict__ in_t, const int* __restrict__ in_s,
    const int* __restrict__ bsum,
    int* __restrict__ gsc_t, int* __restrict__ gsc_s, int L)
{
    const int pass = blockIdx.x >> 8;
    const int b = blockIdx.x & (SCAN_NB - 1);
    const int* in = pass ? in_s : in_t;
    int* out = pass ? gsc_s : gsc_t;
    const int C = (L + SCAN_NB - 1) / SCAN_NB;
    const int K = (C + 255) / 256;
    const int base = b * C;
    const int lim = min(base + C, L);
    const int tbeg = base + threadIdx.x * K;
    const int tend = min(tbeg + K, lim);
    int tsum = 0;
    for (int i = tbeg; i < tend; ++i) tsum += in[i];
    __shared__ int s[256];
    s[threadIdx.x] = tsum;
    __syncthreads();
    for (int off = 1; off < 256; off <<= 1) {
        const int add = (threadIdx.x >= off) ? s[threadIdx.x - off] : 0;
        __syncthreads();
        s[threadIdx.x] += add;
        __syncthreads();
    }
    int run = s[threadIdx.x] - tsum + bsum[pass * SCAN_NB + b];
    for (int i = tbeg; i < tend; ++i) { out[i] = run; run += in[i]; }
}

// ---------------- Bucket scatter ----------------
__global__ __launch_bounds__(256) void bucket_scatter_kernel(
    const int* __restrict__ tgtI, const int* __restrict__ srcI,
    const int* __restrict__ gsc_t, const int* __restrict__ gsc_s,
    unsigned* __restrict__ ep_t, unsigned* __restrict__ ep_s,
    int nBkt, int nEdges)
{
    __shared__ int cursor[2048];
    const int dir = blockIdx.x / NB;
    const int b = blockIdx.x % NB;
    const int* keys = dir ? srcI : tgtI;
    const int* pays = dir ? tgtI : srcI;
    const int* gsc = dir ? gsc_s : gsc_t;
    unsigned* ep = dir ? ep_s : ep_t;
    const int tid = threadIdx.x;
    for (int d = tid; d < nBkt; d += 256) cursor[d] = gsc[(size_t)d * NB + b];
    __syncthreads();
    const int C = (nEdges + NB - 1) / NB;
    const int beg = b * C;
    const int end = min(beg + C, nEdges);
    for (int e = beg + tid; e < end; e += 256) {
        const unsigned k = (unsigned)keys[e];
        const unsigned p = (unsigned)pays[e];
        const int pos = atomicAdd(&cursor[k >> 5], 1);
        ep[pos] = (k << 16) | p;
    }
}

// ---------------- Per-bucket counting sort -> sorted payloads + rowstart ----------------
__global__ __launch_bounds__(256) void bucket_sort_kernel(
    const unsigned* __restrict__ ep_t, const unsigned* __restrict__ ep_s,
    const int* __restrict__ gsc_t, const int* __restrict__ gsc_s,
    int* __restrict__ src_sorted, int* __restrict__ tgt_sorted,
    int* __restrict__ rowstart_t, int* __restrict__ rowstart_s,
    int nBkt, int nNodes, int nEdges)
{
    __shared__ int hist[32], pref[32], cur[32];
    const int dir = (int)(blockIdx.x >= (unsigned)nBkt);
    const int b = blockIdx.x - dir * nBkt;
    const unsigned* ep = dir ? ep_s : ep_t;
    const int* gsc = dir ? gsc_s : gsc_t;
    int* out = dir ? tgt_sorted : src_sorted;
    int* rowstart = dir ? rowstart_s : rowstart_t;
    const int tid = threadIdx.x;

    if (blockIdx.x == 0 && tid == 0) rowstart_t[nNodes] = nEdges;
    if (blockIdx.x == (unsigned)nBkt && tid == 0) rowstart_s[nNodes] = nEdges;

    const int s = gsc[(size_t)b * NB];
    const int e = (b + 1 < nBkt) ? gsc[(size_t)(b + 1) * NB] : nEdges;
    const int size = e - s;

    if (tid < 32) hist[tid] = 0;
    __syncthreads();
    for (int i = tid; i < size; i += 256)
        atomicAdd(&hist[(ep[s + i] >> 16) & 31], 1);
    __syncthreads();
    if (tid == 0) {
        int r = 0;
        for (int k = 0; k < 32; ++k) { pref[k] = r; cur[k] = r; r += hist[k]; }
    }
    __syncthreads();
    if (tid < 32) {
        const int key = (b << 5) + tid;
        if (key < nNodes) rowstart[key] = s + pref[tid];
    }
    __syncthreads();
    for (int i = tid; i < size; i += 256) {
        const unsigned v = ep[s + i];
        const int pos = atomicAdd(&cur[(v >> 16) & 31], 1);
        out[s + pos] = (int)(v & 0xFFFFu);
    }
}

// ---------------- Pass src: pair/beta -> w1m, scale odd (PHI) slots of AW in place ----------------
__global__ __launch_bounds__(256) void pass_src_kernel(
    const int* __restrict__ rowstart_s,
    const int* __restrict__ tgt_sorted,
    const hf* __restrict__ P16,
    const hf* __restrict__ PP16,
    const float* __restrict__ enpsi,
    hf* __restrict__ AW16,
    int nNodes)
{
    const int grp = threadIdx.x >> 4;
    const int l = threadIdx.x & 15;

    for (int n = blockIdx.x * 16 + grp; n < nNodes; n += gridDim.x * 16) {
        const int beg = rowstart_s[n];
        const int end = rowstart_s[n + 1];
        const float2 pr = ((const float2*)(P16 + (size_t)n * D))[l];
        const hf* pq = (const hf*)&pr;
        const float p0 = pq[0], p1 = pq[1], p2 = pq[2], p3 = pq[3];
        float bden = 0.f, ssum = 0.f;

        int k = beg;
        for (; k + 3 < end; k += 4) {
            const int tA = tgt_sorted[k],     tB = tgt_sorted[k + 1];
            const int tC = tgt_sorted[k + 2], tD = tgt_sorted[k + 3];
            const float2 rA = ((const float2*)(PP16 + (size_t)tA * D))[l];
            const float2 rB = ((const float2*)(PP16 + (size_t)tB * D))[l];
            const float2 rC = ((const float2*)(PP16 + (size_t)tC * D))[l];
            const float2 rD = ((const float2*)(PP16 + (size_t)tD * D))[l];
            const float eA = enpsi[tA], eB = enpsi[tB], eC = enpsi[tC], eD = enpsi[tD];
            const hf* qA = (const hf*)&rA;
            const hf* qB = (const hf*)&rB;
            const hf* qC = (const hf*)&rC;
            const hf* qD = (const hf*)&rD;
            float a2 = (float)qA[0] * p0 + (float)qA[1] * p1 + (float)qA[2] * p2 + (float)qA[3] * p3;
            float b2 = (float)qB[0] * p0 + (float)qB[1] * p1 + (float)qB[2] * p2 + (float)qB[3] * p3;
            float c2 = (float)qC[0] * p0 + (float)qC[1] * p1 + (float)qC[2] * p2 + (float)qC[3] * p3;
            float d2 = (float)qD[0] * p0 + (float)qD[1] * p1 + (float)qD[2] * p2 + (float)qD[3] * p3;
            #pragma unroll
            for (int off = 8; off >= 1; off >>= 1) {
                a2 += __shfl_xor(a2, off, 64);
                b2 += __shfl_xor(b2, off, 64);
                c2 += __shfl_xor(c2, off, 64);
                d2 += __shfl_xor(d2, off, 64);
            }
            const float bn0 = __expf(a2);
            const float bn1 = __expf(b2);
            const float bn2 = __expf(c2);
            const float bn3 = __expf(d2);
            bden += bn0 + bn1 + bn2 + bn3;
            ssum += bn0 * eA + bn1 * eB + bn2 * eC + bn3 * eD;
        }
        for (; k < end; ++k) {
            const int t = tgt_sorted[k];
            const float2 r = ((const float2*)(PP16 + (size_t)t * D))[l];
            const float et = enpsi[t];
            const hf* q = (const hf*)&r;
            float a2 = (float)q[0] * p0 + (float)q[1] * p1 + (float)q[2] * p2 + (float)q[3] * p3;
            #pragma unroll
            for (int off = 8; off >= 1; off >>= 1) a2 += __shfl_xor(a2, off, 64);
            const float bn = __expf(a2);
            bden += bn;
            ssum += bn * et;
        }
        const float st = ssum / (bden + 1e-9f);
        const float d = -logf(st + 1e-8f);
        const float w = 1.0f - 1.0f / (1.0f + __expf(-(d - 0.5f)));
        float4* rowp = (float4*)(AW16 + ((size_t)n << 7));
        float4 rv = rowp[l];
        hf* q = (hf*)&rv;
        q[1] = (hf)((float)q[1] * w);
        q[3] = (hf)((float)q[3] * w);
        q[5] = (hf)((float)q[5] * w);
        q[7] = (hf)((float)q[7] * w);
        rowp[l] = rv;
    }
}

// ---------------- Pass tgt FUSED: one float4 gather per edge -> score + message ----------------
__global__ __launch_bounds__(256) void pass_tgt_fused_kernel(
    const int* __restrict__ rowstart_t,
    const int* __restrict__ src_sorted,
    const float* __restrict__ h,
    const hf* __restrict__ AW16,
    hf* __restrict__ m16,
    int nNodes)
{
    const int grp = threadIdx.x >> 4;
    const int l = threadIdx.x & 15;

    for (int n = blockIdx.x * 16 + grp; n < nNodes; n += gridDim.x * 16) {
        const int beg = rowstart_t[n];
        const int end = rowstart_t[n + 1];
        const float4 htv = ((const float4*)(h + (size_t)n * D))[l];
        float aden = 0.f;
        float m0 = 0.f, m1 = 0.f, m2 = 0.f, m3 = 0.f;

        int k = beg;
        for (; k + 3 < end; k += 4) {
            const int sA = src_sorted[k],     sB = src_sorted[k + 1];
            const int sC = src_sorted[k + 2], sD = src_sorted[k + 3];
            const float4 rA = ((const float4*)(AW16 + ((size_t)sA << 7)))[l];
            const float4 rB = ((const float4*)(AW16 + ((size_t)sB << 7)))[l];
            const float4 rC = ((const float4*)(AW16 + ((size_t)sC << 7)))[l];
            const float4 rD = ((const float4*)(AW16 + ((size_t)sD << 7)))[l];
            const hf* qA = (const hf*)&rA;
            const hf* qB = (const hf*)&rB;
            const hf* qC = (const hf*)&rC;
            const hf* qD = (const hf*)&rD;
            float a1 = (float)qA[0] * htv.x + (float)qA[2] * htv.y + (float)qA[4] * htv.z + (float)qA[6] * htv.w;
            float b1 = (float)qB[0] * htv.x + (float)qB[2] * htv.y + (float)qB[4] * htv.z + (float)qB[6] * htv.w;
            float c1 = (float)qC[0] * htv.x + (float)qC[2] * htv.y + (float)qC[4] * htv.z + (float)qC[6] * htv.w;
            float d1 = (float)qD[0] * htv.x + (float)qD[2] * htv.y + (float)qD[4] * htv.z + (float)qD[6] * htv.w;
            #pragma unroll
            for (int off = 8; off >= 1; off >>= 1) {
                a1 += __shfl_xor(a1, off, 64);
                b1 += __shfl_xor(b1, off, 64);
                c1 += __shfl_xor(c1, off, 64);
                d1 += __shfl_xor(d1, off, 64);
            }
            const float an0 = __expf(a1);
            const float an1 = __expf(b1);
            const float an2 = __expf(c1);
            const float an3 = __expf(d1);
            aden += an0 + an1 + an2 + an3;
            m0 += an0 * (float)qA[1] + an1 * (float)qB[1] + an2 * (float)qC[1] + an3 * (float)qD[1];
            m1 += an0 * (float)qA[3] + an1 * (float)qB[3] + an2 * (float)qC[3] + an3 * (float)qD[3];
            m2 += an0 * (float)qA[5] + an1 * (float)qB[5] + an2 * (float)qC[5] + an3 * (float)qD[5];
            m3 += an0 * (float)qA[7] + an1 * (float)qB[7] + an2 * (float)qC[7] + an3 * (float)qD[7];
        }
        for (; k < end; ++k) {
            const int s = src_sorted[k];
            const float4 r = ((const float4*)(AW16 + ((size_t)s << 7)))[l];
            const hf* q = (const hf*)&r;
            float a1 = (float)q[0] * htv.x + (float)q[2] * htv.y + (float)q[4] * htv.z + (float)q[6] * htv.w;
            #pragma unroll
            for (int off = 8; off >= 1; off >>= 1) a1 += __shfl_xor(a1, off, 64);
            const float an = __expf(a1);
            aden += an;
            m0 += an * (float)q[1];
            m1 += an * (float)q[3];
            m2 += an * (float)q[5];
            m3 += an * (float)q[7];
        }

        const float idn = 1.0f / (aden + 1e-9f);
        hf o4[4];
        o4[0] = (hf)(m0 * idn);
        o4[1] = (hf)(m1 * idn);
        o4[2] = (hf)(m2 * idn);
        o4[3] = (hf)(m3 * idn);
        ((float2*)(m16 + (size_t)n * D))[l] = *(const float2*)o4;
    }
}

// ---------------- Final: streaming matmuls, 4 nodes per thread + LN ----------------
__global__ __launch_bounds__(512) void final_kernel(
    const float* __restrict__ h,
    const hf* __restrict__ m16,
    const float* __restrict__ W_self_w, const float* __restrict__ W_self_b,
    const float* __restrict__ W_A_w,    const float* __restrict__ W_A_b,
    const float* __restrict__ W_str_w,  const float* __restrict__ W_str_b,
    const float* __restrict__ ln_g,     const float* __restrict__ ln_b,
    float* __restrict__ out,
    int nNodes)
{
    __shared__ hf2 sWs2[32][D];     // 8 KB
    __shared__ hf2 sWa2[32][D];     // 8 KB
    __shared__ float sWstr[6 * D];
    __shared__ float sBias[D];
    __shared__ float sG[D], sB[D];
    __shared__ hf hall[32][D];      // 4 KB
    __shared__ hf mall[32][D];      // 4 KB

    const int tid = threadIdx.x;
    for (int idx = tid; idx < 32 * D; idx += 512) {
        const int k2 = idx >> 6, j = idx & 63;
        sWs2[k2][j] = hf2{(hf)W_self_w[(2 * k2) * D + j], (hf)W_self_w[(2 * k2 + 1) * D + j]};
        sWa2[k2][j] = hf2{(hf)W_A_w[(2 * k2) * D + j],    (hf)W_A_w[(2 * k2 + 1) * D + j]};
    }
    for (int i = tid; i < 6 * D; i += 512) sWstr[i] = W_str_w[i];
    if (tid < D) {
        sBias[tid] = W_self_b[tid] + W_A_b[tid] + W_str_b[tid];
        sG[tid] = ln_g[tid];
        sB[tid] = ln_b[tid];
    }

    const int n0 = blockIdx.x * 32;
    {
        const int base = tid * 4;
        const int ln = base >> 6;
        const int col = base & 63;
        const int n = n0 + ln;
        if (n < nNodes) {
            const float4 v = *(const float4*)(h + (size_t)n * D + col);
            hall[ln][col]     = (hf)v.x;
            hall[ln][col + 1] = (hf)v.y;
            hall[ln][col + 2] = (hf)v.z;
            hall[ln][col + 3] = (hf)v.w;
            *(uint2*)&mall[ln][col] = *(const uint2*)(m16 + (size_t)n * D + col);
        }
    }
    __syncthreads();

    const int g = tid >> 6, j = tid & 63;
    const int ln0 = 4 * g;

    float acc[4];
    #pragma unroll
    for (int m = 0; m < 4; ++m) acc[m] = sBias[j];

    const hf2* hr0 = (const hf2*)hall[ln0 + 0];
    const hf2* hr1 = (const hf2*)hall[ln0 + 1];
    const hf2* hr2 = (const hf2*)hall[ln0 + 2];
    const hf2* hr3 = (const hf2*)hall[ln0 + 3];
    const hf2* mr0 = (const hf2*)mall[ln0 + 0];
    const hf2* mr1 = (const hf2*)mall[ln0 + 1];
    const hf2* mr2 = (const hf2*)mall[ln0 + 2];
    const hf2* mr3 = (const hf2*)mall[ln0 + 3];

    #pragma unroll 8
    for (int k2 = 0; k2 < 32; ++k2) {
        const hf2 ws = sWs2[k2][j];
        const hf2 wa = sWa2[k2][j];
        acc[0] = fdot2f(ws, hr0[k2], acc[0]);
        acc[0] = fdot2f(wa, mr0[k2], acc[0]);
        acc[1] = fdot2f(ws, hr1[k2], acc[1]);
        acc[1] = fdot2f(wa, mr1[k2], acc[1]);
        acc[2] = fdot2f(ws, hr2[k2], acc[2]);
        acc[2] = fdot2f(wa, mr2[k2], acc[2]);
        acc[3] = fdot2f(ws, hr3[k2], acc[3]);
        acc[3] = fdot2f(wa, mr3[k2], acc[3]);
    }
    #pragma unroll
    for (int k = 0; k < 6; ++k) {
        const float w = sWstr[k * D + j];
        acc[0] += (float)hall[ln0 + 0][k] * w;
        acc[1] += (float)hall[ln0 + 1][k] * w;
        acc[2] += (float)hall[ln0 + 2][k] * w;
        acc[3] += (float)hall[ln0 + 3][k] * w;
    }

    float pre[4], mu[4], vv[4];
    #pragma unroll
    for (int m = 0; m < 4; ++m)
        pre[m] = fmaxf(acc[m], 0.f) + (float)hall[ln0 + m][j];

    #pragma unroll
    for (int m = 0; m < 4; ++m) mu[m] = pre[m];
    #pragma unroll
    for (int off = 32; off >= 1; off >>= 1) {
        #pragma unroll
        for (int m = 0; m < 4; ++m) mu[m] += __shfl_xor(mu[m], off, 64);
    }
    #pragma unroll
    for (int m = 0; m < 4; ++m) {
        mu[m] *= (1.0f / 64.0f);
        const float diff = pre[m] - mu[m];
        vv[m] = diff * diff;
    }
    #pragma unroll
    for (int off = 32; off >= 1; off >>= 1) {
        #pragma unroll
        for (int m = 0; m < 4; ++m) vv[m] += __shfl_xor(vv[m], off, 64);
    }
    #pragma unroll
    for (int m = 0; m < 4; ++m) {
        const int n = n0 + ln0 + m;
        if (n < nNodes) {
            const float diff = pre[m] - mu[m];
            out[(size_t)n * D + j] = diff * rsqrtf(vv[m] * (1.0f / 64.0f) + 1e-5f) * sG[j] + sB[j];
        }
    }
}

extern "C" void kernel_launch(void* const* d_in, const int* in_sizes, int n_in,
                              void* d_out, int out_size, void* d_ws, size_t ws_size,
                              hipStream_t stream) {
    const int* edge       = (const int*)d_in[0];
    const float* h        = (const float*)d_in[1];
    const float* W_att    = (const float*)d_in[2];
    const float* phi_w    = (const float*)d_in[3];
    const float* phi_b    = (const float*)d_in[4];
    const float* W_p      = (const float*)d_in[5];
    const float* W_pp     = (const float*)d_in[6];
    const float* fdef_w   = (const float*)d_in[7];
    const float* fdef_b   = (const float*)d_in[8];
    const float* W_self_w = (const float*)d_in[9];
    const float* W_self_b = (const float*)d_in[10];
    const float* W_A_w    = (const float*)d_in[11];
    const float* W_A_b    = (const float*)d_in[12];
    const float* W_str_w  = (const float*)d_in[13];
    const float* W_str_b  = (const float*)d_in[14];
    const float* ln_g     = (const float*)d_in[15];
    const float* ln_b     = (const float*)d_in[16];

    const int E = in_sizes[0] / 2;
    const int nNodes = in_sizes[1] / D;
    const int* srcI = edge;
    const int* tgtI = edge + E;
    const int nBkt = (nNodes + 31) / 32;
    const int L = nBkt * NB;
    const int nbNode = (nNodes + 31) / 32;

    char* ws = (char*)d_ws;
    size_t off = 0;
    auto alloc = [&](size_t bytes) { char* p = ws + off; off = (off + bytes + 255) & ~(size_t)255; return p; };

    hf*       AW16      = (hf*)      alloc((size_t)nNodes * 2 * D * 2);
    hf*       P16       = (hf*)      alloc((size_t)nNodes * D * 2);
    hf*       PP16      = (hf*)      alloc((size_t)nNodes * D * 2);
    hf*       m16       = (hf*)      alloc((size_t)nNodes * D * 2);
    float*    enpsi     = (float*)   alloc((size_t)nNodes * 4);
    int*      ghist_t   = (int*)     alloc((size_t)L * 4);
    int*      ghist_s   = (int*)     alloc((size_t)L * 4);
    int*      gsc_t     = (int*)     alloc((size_t)L * 4);
    int*      gsc_s     = (int*)     alloc((size_t)L * 4);
    unsigned* ep_t      = (unsigned*)alloc((size_t)E * 4);
    unsigned* ep_s      = (unsigned*)alloc((size_t)E * 4);
    int*      src_sorted= (int*)     alloc((size_t)E * 4);
    int*      tgt_sorted= (int*)     alloc((size_t)E * 4);
    int*      rowstart_t= (int*)     alloc(((size_t)nNodes + 1) * 4);
    int*      rowstart_s= (int*)     alloc(((size_t)nNodes + 1) * 4);
    int*      bsum      = (int*)     alloc((size_t)2 * SCAN_NB * 4);

    node_pre_kernel<<<nbNode, 512, 0, stream>>>(
        h, W_att, W_p, W_pp, phi_w, phi_b, fdef_w, fdef_b,
        AW16, P16, PP16, enpsi, nNodes);

    bucket_hist_kernel<<<2 * NB, 256, 0, stream>>>(
        tgtI, srcI, ghist_t, ghist_s, nBkt, E);

    scan_partial_kernel<<<2 * SCAN_NB, 256, 0, stream>>>(ghist_t, ghist_s, bsum, L);
    scan_bsum_kernel<<<1, 2 * SCAN_NB, 0, stream>>>(bsum);
    scan_final_kernel<<<2 * SCAN_NB, 256, 0, stream>>>(
        ghist_t, ghist_s, bsum, gsc_t, gsc_s, L);

    bucket_scatter_kernel<<<2 * NB, 256, 0, stream>>>(
        tgtI, srcI, gsc_t, gsc_s, ep_t, ep_s, nBkt, E);

    bucket_sort_kernel<<<2 * nBkt, 256, 0, stream>>>(
        ep_t, ep_s, gsc_t, gsc_s, src_sorted, tgt_sorted,
        rowstart_t, rowstart_s, nBkt, nNodes, E);

    pass_src_kernel<<<2048, 256, 0, stream>>>(
        rowstart_s, tgt_sorted, P16, PP16, enpsi, AW16, nNodes);

    pass_tgt_fused_kernel<<<2048, 256, 0, stream>>>(
        rowstart_t, src_sorted, h, AW16, m16, nNodes);

    final_kernel<<<nbNode, 512, 0, stream>>>(
        h, m16, W_self_w, W_self_b, W_A_w, W_A_b,
        W_str_w, W_str_b, ln_g, ln_b, (float*)d_out, nNodes);
}

// Round 14
// 167.436 us; speedup vs baseline: 2.7897x; 1.0419x over previous
//
#include <hip/hip_runtime.h>
#include <math.h>

#define D 64
#define NB 256        // blocks per direction for bucket hist/scatter
#define SCAN_NB 256   // blocks per scan pass
#define PS_NB 2048    // pass_src blocks in fused launch

typedef _Float16 hf;
typedef _Float16 hf2 __attribute__((ext_vector_type(2)));

__device__ inline float fdot2f(hf2 a, hf2 b, float c) {
#if __has_builtin(__builtin_amdgcn_fdot2)
    return __builtin_amdgcn_fdot2(a, b, c, false);
#else
    return (float)a[0] * (float)b[0] + (float)a[1] * (float)b[1] + c;
#endif
}

// ---------------- K1: node_pre (4 nodes/thread) FUSED with bucket_hist ----------------
__global__ __launch_bounds__(512) void node_pre_hist_kernel(
    const float* __restrict__ h,
    const float* __restrict__ W_att,
    const float* __restrict__ W_p,
    const float* __restrict__ W_pp,
    const float* __restrict__ phi_w,
    const float* __restrict__ phi_b,
    const float* __restrict__ fdef_w,
    const float* __restrict__ fdef_b,
    const int* __restrict__ tgtI, const int* __restrict__ srcI,
    int* __restrict__ ghist_t, int* __restrict__ ghist_s,
    hf* __restrict__ AW16,
    hf* __restrict__ P16,
    hf* __restrict__ PP16,
    float* __restrict__ enpsi,
    int nNodes, int nbNode, int nBkt, int nEdges)
{
    __shared__ hf2 sW2[4][32][D];        // 32 KB
    __shared__ hf  hall[32][D];          // 4 KB
    __shared__ float sPhib[D];
    __shared__ float sFdef[D];
    __shared__ int hist[2048];           // 8 KB (hist branch)

    const int tid = threadIdx.x;

    if (blockIdx.x >= nbNode) {
        // ---------------- bucket_hist branch ----------------
        const int hb = blockIdx.x - nbNode;
        const int dir = hb / NB;
        const int b = hb % NB;
        const int* keys = dir ? srcI : tgtI;
        int* gh = dir ? ghist_s : ghist_t;
        for (int d = tid; d < nBkt; d += 512) hist[d] = 0;
        __syncthreads();
        const int C = (nEdges + NB - 1) / NB;
        const int beg = b * C;
        const int end = min(beg + C, nEdges);
        for (int e = beg + tid; e < end; e += 512)
            atomicAdd(&hist[keys[e] >> 5], 1);
        __syncthreads();
        for (int d = tid; d < nBkt; d += 512)
            gh[(size_t)d * NB + b] = hist[d];
        return;
    }

    // ---------------- node_pre branch ----------------
    const float* Wm[4] = { W_att, W_p, W_pp, phi_w };
    for (int idx = tid; idx < 4 * 32 * D; idx += 512) {
        const int m  = idx >> 11;
        const int k2 = (idx >> 6) & 31;
        const int j  = idx & 63;
        sW2[m][k2][j] = hf2{(hf)Wm[m][(2 * k2) * D + j], (hf)Wm[m][(2 * k2 + 1) * D + j]};
    }
    if (tid < D) { sPhib[tid] = phi_b[tid]; sFdef[tid] = fdef_w[tid]; }
    __syncthreads();
    const float fb = fdef_b[0];

    const int n0 = blockIdx.x * 32;
    {
        const int base = tid * 4;
        const int ln = base >> 6;
        const int col = base & 63;
        const int n = n0 + ln;
        float ps = 0.f;
        if (n < nNodes) {
            const float4 v = *(const float4*)(h + (size_t)n * D + col);
            hall[ln][col]     = (hf)v.x;
            hall[ln][col + 1] = (hf)v.y;
            hall[ln][col + 2] = (hf)v.z;
            hall[ln][col + 3] = (hf)v.w;
            ps = v.x * sFdef[col] + v.y * sFdef[col + 1]
               + v.z * sFdef[col + 2] + v.w * sFdef[col + 3];
        }
        #pragma unroll
        for (int off = 8; off >= 1; off >>= 1) ps += __shfl_xor(ps, off, 64);
        if ((tid & 15) == 0 && n < nNodes) enpsi[n] = __expf(-(ps + fb));
    }
    __syncthreads();

    const int g = tid >> 6;
    const int j = tid & 63;
    const int ln0 = 4 * g;

    float acc[4][4];
    #pragma unroll
    for (int m = 0; m < 4; ++m) {
        acc[m][0] = 0.f; acc[m][1] = 0.f; acc[m][2] = 0.f; acc[m][3] = sPhib[j];
    }
    const hf2* hr0 = (const hf2*)hall[ln0 + 0];
    const hf2* hr1 = (const hf2*)hall[ln0 + 1];
    const hf2* hr2 = (const hf2*)hall[ln0 + 2];
    const hf2* hr3 = (const hf2*)hall[ln0 + 3];

    #pragma unroll 8
    for (int k2 = 0; k2 < 32; ++k2) {
        const hf2 w0 = sW2[0][k2][j];
        const hf2 w1 = sW2[1][k2][j];
        const hf2 w2 = sW2[2][k2][j];
        const hf2 w3 = sW2[3][k2][j];
        const hf2 h0 = hr0[k2];
        const hf2 h1 = hr1[k2];
        const hf2 h2 = hr2[k2];
        const hf2 h3 = hr3[k2];
        acc[0][0] = fdot2f(w0, h0, acc[0][0]);
        acc[0][1] = fdot2f(w1, h0, acc[0][1]);
        acc[0][2] = fdot2f(w2, h0, acc[0][2]);
        acc[0][3] = fdot2f(w3, h0, acc[0][3]);
        acc[1][0] = fdot2f(w0, h1, acc[1][0]);
        acc[1][1] = fdot2f(w1, h1, acc[1][1]);
        acc[1][2] = fdot2f(w2, h1, acc[1][2]);
        acc[1][3] = fdot2f(w3, h1, acc[1][3]);
        acc[2][0] = fdot2f(w0, h2, acc[2][0]);
        acc[2][1] = fdot2f(w1, h2, acc[2][1]);
        acc[2][2] = fdot2f(w2, h2, acc[2][2]);
        acc[2][3] = fdot2f(w3, h2, acc[2][3]);
        acc[3][0] = fdot2f(w0, h3, acc[3][0]);
        acc[3][1] = fdot2f(w1, h3, acc[3][1]);
        acc[3][2] = fdot2f(w2, h3, acc[3][2]);
        acc[3][3] = fdot2f(w3, h3, acc[3][3]);
    }

    #pragma unroll
    for (int m = 0; m < 4; ++m) {
        const int n = n0 + ln0 + m;
        if (n < nNodes) {
            float a = acc[m][0];
            if (j < 6) a += (float)hall[ln0 + m][j];
            const size_t base = (size_t)n * D + j;
            *(hf2*)(AW16 + ((size_t)n << 7) + 2 * j) = hf2{(hf)a, (hf)acc[m][3]};
            P16[base]  = (hf)acc[m][1];
            PP16[base] = (hf)acc[m][2];
        }
    }
}

// ---------------- Scan step 1 ----------------
__global__ __launch_bounds__(256) void scan_partial_kernel(
    const int* __restrict__ in_t, const int* __restrict__ in_s,
    int* __restrict__ bsum, int L)
{
    const int pass = blockIdx.x >> 8;
    const int b = blockIdx.x & (SCAN_NB - 1);
    const int* in = pass ? in_s : in_t;
    const int C = (L + SCAN_NB - 1) / SCAN_NB;
    const int K = (C + 255) / 256;
    const int base = b * C;
    const int lim = min(base + C, L);
    const int tbeg = base + threadIdx.x * K;
    const int tend = min(tbeg + K, lim);
    int tsum = 0;
    for (int i = tbeg; i < tend; ++i) tsum += in[i];
    __shared__ int red[256];
    red[threadIdx.x] = tsum;
    __syncthreads();
    for (int off = 128; off >= 1; off >>= 1) {
        if (threadIdx.x < off) red[threadIdx.x] += red[threadIdx.x + off];
        __syncthreads();
    }
    if (threadIdx.x == 0) bsum[pass * SCAN_NB + b] = red[0];
}

// ---------------- Scan step 2 ----------------
__global__ __launch_bounds__(512) void scan_bsum_kernel(int* __restrict__ bsum)
{
    __shared__ int s[2 * SCAN_NB];
    const int tid = threadIdx.x;
    const int orig = bsum[tid];
    s[tid] = orig;
    __syncthreads();
    const int seg = tid & (SCAN_NB - 1);
    for (int off = 1; off < SCAN_NB; off <<= 1) {
        const int add = (seg >= off) ? s[tid - off] : 0;
        __syncthreads();
        s[tid] += add;
        __syncthreads();
    }
    bsum[tid] = s[tid] - orig;
}

// ---------------- Scan step 3 ----------------
__global__ __launch_bounds__(256) void scan_final_kernel(
    const int* __restrict__ in_t, const int* __restrict__ in_s,
    const int* __restrict__ bsum,
    int* __restrict__ gsc_t, int* __restrict__ gsc_s, int L)
{
    const int pass = blockIdx.x >> 8;
    const int b = blockIdx.x & (SCAN_NB - 1);
    const int* in = pass ? in_s : in_t;
    int* out = pass ? gsc_s : gsc_t;
    const int C = (L + SCAN_NB - 1) / SCAN_NB;
    const int K = (C + 255) / 256;
    const int base = b * C;
    const int lim = min(base + C, L);
    const int tbeg = base + threadIdx.x * K;
    const int tend = min(tbeg + K, lim);
    int tsum = 0;
    for (int i = tbeg; i < tend; ++i) tsum += in[i];
    __shared__ int s[256];
    s[threadIdx.x] = tsum;
    __syncthreads();
    for (int off = 1; off < 256; off <<= 1) {
        const int add = (threadIdx.x >= off) ? s[threadIdx.x - off] : 0;
        __syncthreads();
        s[threadIdx.x] += add;
        __syncthreads();
    }
    int run = s[threadIdx.x] - tsum + bsum[pass * SCAN_NB + b];
    for (int i = tbeg; i < tend; ++i) { out[i] = run; run += in[i]; }
}

// ---------------- Bucket scatter ----------------
__global__ __launch_bounds__(256) void bucket_scatter_kernel(
    const int* __restrict__ tgtI, const int* __restrict__ srcI,
    const int* __restrict__ gsc_t, const int* __restrict__ gsc_s,
    unsigned* __restrict__ ep_t, unsigned* __restrict__ ep_s,
    int nBkt, int nEdges)
{
    __shared__ int cursor[2048];
    const int dir = blockIdx.x / NB;
    const int b = blockIdx.x % NB;
    const int* keys = dir ? srcI : tgtI;
    const int* pays = dir ? tgtI : srcI;
    const int* gsc = dir ? gsc_s : gsc_t;
    unsigned* ep = dir ? ep_s : ep_t;
    const int tid = threadIdx.x;
    for (int d = tid; d < nBkt; d += 256) cursor[d] = gsc[(size_t)d * NB + b];
    __syncthreads();
    const int C = (nEdges + NB - 1) / NB;
    const int beg = b * C;
    const int end = min(beg + C, nEdges);
    for (int e = beg + tid; e < end; e += 256) {
        const unsigned k = (unsigned)keys[e];
        const unsigned p = (unsigned)pays[e];
        const int pos = atomicAdd(&cursor[k >> 5], 1);
        ep[pos] = (k << 16) | p;
    }
}

// ---------------- Per-bucket counting sort body ----------------
__device__ inline void bucket_sort_body(
    const unsigned* __restrict__ ep, const int* __restrict__ gsc,
    int* __restrict__ out, int* __restrict__ rowstart,
    int b, int nBkt, int nNodes, int nEdges,
    int* hist, int* pref, int* cur, int tid)
{
    if (b == 0 && tid == 0) rowstart[nNodes] = nEdges;

    const int s = gsc[(size_t)b * NB];
    const int e = (b + 1 < nBkt) ? gsc[(size_t)(b + 1) * NB] : nEdges;
    const int size = e - s;

    if (tid < 32) hist[tid] = 0;
    __syncthreads();
    for (int i = tid; i < size; i += 256)
        atomicAdd(&hist[(ep[s + i] >> 16) & 31], 1);
    __syncthreads();
    if (tid == 0) {
        int r = 0;
        for (int k = 0; k < 32; ++k) { pref[k] = r; cur[k] = r; r += hist[k]; }
    }
    __syncthreads();
    if (tid < 32) {
        const int key = (b << 5) + tid;
        if (key < nNodes) rowstart[key] = s + pref[tid];
    }
    __syncthreads();
    for (int i = tid; i < size; i += 256) {
        const unsigned v = ep[s + i];
        const int pos = atomicAdd(&cur[(v >> 16) & 31], 1);
        out[s + pos] = (int)(v & 0xFFFFu);
    }
}

// ---------------- Solo s-direction sort (needed before pass_src) ----------------
__global__ __launch_bounds__(256) void bucket_sort_s_kernel(
    const unsigned* __restrict__ ep_s, const int* __restrict__ gsc_s,
    int* __restrict__ tgt_sorted, int* __restrict__ rowstart_s,
    int nBkt, int nNodes, int nEdges)
{
    __shared__ int hist[32], pref[32], cur[32];
    bucket_sort_body(ep_s, gsc_s, tgt_sorted, rowstart_s,
                     blockIdx.x, nBkt, nNodes, nEdges, hist, pref, cur, threadIdx.x);
}

// ---------------- K3: pass_src (8-deep) FUSED with t-direction sort ----------------
__global__ __launch_bounds__(256) void pass_src_sortT_kernel(
    const int* __restrict__ rowstart_s,
    const int* __restrict__ tgt_sorted,
    const hf* __restrict__ P16,
    const hf* __restrict__ PP16,
    const float* __restrict__ enpsi,
    hf* __restrict__ AW16,
    const unsigned* __restrict__ ep_t, const int* __restrict__ gsc_t,
    int* __restrict__ src_sorted, int* __restrict__ rowstart_t,
    int nBkt, int nNodes, int nEdges)
{
    __shared__ int hist[32], pref[32], cur[32];
    const int tid = threadIdx.x;

    if (blockIdx.x >= PS_NB) {
        bucket_sort_body(ep_t, gsc_t, src_sorted, rowstart_t,
                         blockIdx.x - PS_NB, nBkt, nNodes, nEdges, hist, pref, cur, tid);
        return;
    }

    const int grp = tid >> 4;
    const int l = tid & 15;

    for (int n = blockIdx.x * 16 + grp; n < nNodes; n += PS_NB * 16) {
        const int beg = rowstart_s[n];
        const int end = rowstart_s[n + 1];
        const float2 pr = ((const float2*)(P16 + (size_t)n * D))[l];
        const hf* pq = (const hf*)&pr;
        const float p0 = pq[0], p1 = pq[1], p2 = pq[2], p3 = pq[3];
        float bden = 0.f, ssum = 0.f;

        int k = beg;
        for (; k + 7 < end; k += 8) {
            int tv[8]; float2 rv[8]; float ev[8];
            #pragma unroll
            for (int u = 0; u < 8; ++u) tv[u] = tgt_sorted[k + u];
            #pragma unroll
            for (int u = 0; u < 8; ++u) rv[u] = ((const float2*)(PP16 + (size_t)tv[u] * D))[l];
            #pragma unroll
            for (int u = 0; u < 8; ++u) ev[u] = enpsi[tv[u]];
            float sc[8];
            #pragma unroll
            for (int u = 0; u < 8; ++u) {
                const hf* q = (const hf*)&rv[u];
                sc[u] = (float)q[0] * p0 + (float)q[1] * p1 + (float)q[2] * p2 + (float)q[3] * p3;
            }
            #pragma unroll
            for (int off = 8; off >= 1; off >>= 1) {
                #pragma unroll
                for (int u = 0; u < 8; ++u) sc[u] += __shfl_xor(sc[u], off, 64);
            }
            #pragma unroll
            for (int u = 0; u < 8; ++u) {
                const float bn = __expf(sc[u]);
                bden += bn;
                ssum += bn * ev[u];
            }
        }
        for (; k + 3 < end; k += 4) {
            int tv[4]; float2 rv[4]; float ev[4];
            #pragma unroll
            for (int u = 0; u < 4; ++u) tv[u] = tgt_sorted[k + u];
            #pragma unroll
            for (int u = 0; u < 4; ++u) rv[u] = ((const float2*)(PP16 + (size_t)tv[u] * D))[l];
            #pragma unroll
            for (int u = 0; u < 4; ++u) ev[u] = enpsi[tv[u]];
            float sc[4];
            #pragma unroll
            for (int u = 0; u < 4; ++u) {
                const hf* q = (const hf*)&rv[u];
                sc[u] = (float)q[0] * p0 + (float)q[1] * p1 + (float)q[2] * p2 + (float)q[3] * p3;
            }
            #pragma unroll
            for (int off = 8; off >= 1; off >>= 1) {
                #pragma unroll
                for (int u = 0; u < 4; ++u) sc[u] += __shfl_xor(sc[u], off, 64);
            }
            #pragma unroll
            for (int u = 0; u < 4; ++u) {
                const float bn = __expf(sc[u]);
                bden += bn;
                ssum += bn * ev[u];
            }
        }
        for (; k < end; ++k) {
            const int t = tgt_sorted[k];
            const float2 r = ((const float2*)(PP16 + (size_t)t * D))[l];
            const float et = enpsi[t];
            const hf* q = (const hf*)&r;
            float a2 = (float)q[0] * p0 + (float)q[1] * p1 + (float)q[2] * p2 + (float)q[3] * p3;
            #pragma unroll
            for (int off = 8; off >= 1; off >>= 1) a2 += __shfl_xor(a2, off, 64);
            const float bn = __expf(a2);
            bden += bn;
            ssum += bn * et;
        }
        const float st = ssum / (bden + 1e-9f);
        const float d = -logf(st + 1e-8f);
        const float w = 1.0f - 1.0f / (1.0f + __expf(-(d - 0.5f)));
        float4* rowp = (float4*)(AW16 + ((size_t)n << 7));
        float4 rv = rowp[l];
        hf* q = (hf*)&rv;
        q[1] = (hf)((float)q[1] * w);
        q[3] = (hf)((float)q[3] * w);
        q[5] = (hf)((float)q[5] * w);
        q[7] = (hf)((float)q[7] * w);
        rowp[l] = rv;
    }
}

// ---------------- Pass tgt FUSED (8-deep): one float4 gather per edge ----------------
__global__ __launch_bounds__(256) void pass_tgt_fused_kernel(
    const int* __restrict__ rowstart_t,
    const int* __restrict__ src_sorted,
    const float* __restrict__ h,
    const hf* __restrict__ AW16,
    hf* __restrict__ m16,
    int nNodes)
{
    const int grp = threadIdx.x >> 4;
    const int l = threadIdx.x & 15;

    for (int n = blockIdx.x * 16 + grp; n < nNodes; n += gridDim.x * 16) {
        const int beg = rowstart_t[n];
        const int end = rowstart_t[n + 1];
        const float4 htv = ((const float4*)(h + (size_t)n * D))[l];
        float aden = 0.f;
        float m0 = 0.f, m1 = 0.f, m2 = 0.f, m3 = 0.f;

        int k = beg;
        for (; k + 7 < end; k += 8) {
            int sv[8]; float4 rv[8];
            #pragma unroll
            for (int u = 0; u < 8; ++u) sv[u] = src_sorted[k + u];
            #pragma unroll
            for (int u = 0; u < 8; ++u) rv[u] = ((const float4*)(AW16 + ((size_t)sv[u] << 7)))[l];
            float sc[8];
            #pragma unroll
            for (int u = 0; u < 8; ++u) {
                const hf* q = (const hf*)&rv[u];
                sc[u] = (float)q[0] * htv.x + (float)q[2] * htv.y
                      + (float)q[4] * htv.z + (float)q[6] * htv.w;
            }
            #pragma unroll
            for (int off = 8; off >= 1; off >>= 1) {
                #pragma unroll
                for (int u = 0; u < 8; ++u) sc[u] += __shfl_xor(sc[u], off, 64);
            }
            #pragma unroll
            for (int u = 0; u < 8; ++u) {
                const float an = __expf(sc[u]);
                aden += an;
                const hf* q = (const hf*)&rv[u];
                m0 += an * (float)q[1];
                m1 += an * (float)q[3];
                m2 += an * (float)q[5];
                m3 += an * (float)q[7];
            }
        }
        for (; k + 3 < end; k += 4) {
            int sv[4]; float4 rv[4];
            #pragma unroll
            for (int u = 0; u < 4; ++u) sv[u] = src_sorted[k + u];
            #pragma unroll
            for (int u = 0; u < 4; ++u) rv[u] = ((const float4*)(AW16 + ((size_t)sv[u] << 7)))[l];
            float sc[4];
            #pragma unroll
            for (int u = 0; u < 4; ++u) {
                const hf* q = (const hf*)&rv[u];
                sc[u] = (float)q[0] * htv.x + (float)q[2] * htv.y
                      + (float)q[4] * htv.z + (float)q[6] * htv.w;
            }
            #pragma unroll
            for (int off = 8; off >= 1; off >>= 1) {
                #pragma unroll
                for (int u = 0; u < 4; ++u) sc[u] += __shfl_xor(sc[u], off, 64);
            }
            #pragma unroll
            for (int u = 0; u < 4; ++u) {
                const float an = __expf(sc[u]);
                aden += an;
                const hf* q = (const hf*)&rv[u];
                m0 += an * (float)q[1];
                m1 += an * (float)q[3];
                m2 += an * (float)q[5];
                m3 += an * (float)q[7];
            }
        }
        for (; k < end; ++k) {
            const int s = src_sorted[k];
            const float4 r = ((const float4*)(AW16 + ((size_t)s << 7)))[l];
            const hf* q = (const hf*)&r;
            float a1 = (float)q[0] * htv.x + (float)q[2] * htv.y
                     + (float)q[4] * htv.z + (float)q[6] * htv.w;
            #pragma unroll
            for (int off = 8; off >= 1; off >>= 1) a1 += __shfl_xor(a1, off, 64);
            const float an = __expf(a1);
            aden += an;
            m0 += an * (float)q[1];
            m1 += an * (float)q[3];
            m2 += an * (float)q[5];
            m3 += an * (float)q[7];
        }

        const float idn = 1.0f / (aden + 1e-9f);
        hf o4[4];
        o4[0] = (hf)(m0 * idn);
        o4[1] = (hf)(m1 * idn);
        o4[2] = (hf)(m2 * idn);
        o4[3] = (hf)(m3 * idn);
        ((float2*)(m16 + (size_t)n * D))[l] = *(const float2*)o4;
    }
}

// ---------------- Final: streaming matmuls, 4 nodes per thread + LN ----------------
__global__ __launch_bounds__(512) void final_kernel(
    const float* __restrict__ h,
    const hf* __restrict__ m16,
    const float* __restrict__ W_self_w, const float* __restrict__ W_self_b,
    const float* __restrict__ W_A_w,    const float* __restrict__ W_A_b,
    const float* __restrict__ W_str_w,  const float* __restrict__ W_str_b,
    const float* __restrict__ ln_g,     const float* __restrict__ ln_b,
    float* __restrict__ out,
    int nNodes)
{
    __shared__ hf2 sWs2[32][D];
    __shared__ hf2 sWa2[32][D];
    __shared__ float sWstr[6 * D];
    __shared__ float sBias[D];
    __shared__ float sG[D], sB[D];
    __shared__ hf hall[32][D];
    __shared__ hf mall[32][D];

    const int tid = threadIdx.x;
    for (int idx = tid; idx < 32 * D; idx += 512) {
        const int k2 = idx >> 6, j = idx & 63;
        sWs2[k2][j] = hf2{(hf)W_self_w[(2 * k2) * D + j], (hf)W_self_w[(2 * k2 + 1) * D + j]};
        sWa2[k2][j] = hf2{(hf)W_A_w[(2 * k2) * D + j],    (hf)W_A_w[(2 * k2 + 1) * D + j]};
    }
    for (int i = tid; i < 6 * D; i += 512) sWstr[i] = W_str_w[i];
    if (tid < D) {
        sBias[tid] = W_self_b[tid] + W_A_b[tid] + W_str_b[tid];
        sG[tid] = ln_g[tid];
        sB[tid] = ln_b[tid];
    }

    const int n0 = blockIdx.x * 32;
    {
        const int base = tid * 4;
        const int ln = base >> 6;
        const int col = base & 63;
        const int n = n0 + ln;
        if (n < nNodes) {
            const float4 v = *(const float4*)(h + (size_t)n * D + col);
            hall[ln][col]     = (hf)v.x;
            hall[ln][col + 1] = (hf)v.y;
            hall[ln][col + 2] = (hf)v.z;
            hall[ln][col + 3] = (hf)v.w;
            *(uint2*)&mall[ln][col] = *(const uint2*)(m16 + (size_t)n * D + col);
        }
    }
    __syncthreads();

    const int g = tid >> 6, j = tid & 63;
    const int ln0 = 4 * g;

    float acc[4];
    #pragma unroll
    for (int m = 0; m < 4; ++m) acc[m] = sBias[j];

    const hf2* hr0 = (const hf2*)hall[ln0 + 0];
    const hf2* hr1 = (const hf2*)hall[ln0 + 1];
    const hf2* hr2 = (const hf2*)hall[ln0 + 2];
    const hf2* hr3 = (const hf2*)hall[ln0 + 3];
    const hf2* mr0 = (const hf2*)mall[ln0 + 0];
    const hf2* mr1 = (const hf2*)mall[ln0 + 1];
    const hf2* mr2 = (const hf2*)mall[ln0 + 2];
    const hf2* mr3 = (const hf2*)mall[ln0 + 3];

    #pragma unroll 8
    for (int k2 = 0; k2 < 32; ++k2) {
        const hf2 ws = sWs2[k2][j];
        const hf2 wa = sWa2[k2][j];
        acc[0] = fdot2f(ws, hr0[k2], acc[0]);
        acc[0] = fdot2f(wa, mr0[k2], acc[0]);
        acc[1] = fdot2f(ws, hr1[k2], acc[1]);
        acc[1] = fdot2f(wa, mr1[k2], acc[1]);
        acc[2] = fdot2f(ws, hr2[k2], acc[2]);
        acc[2] = fdot2f(wa, mr2[k2], acc[2]);
        acc[3] = fdot2f(ws, hr3[k2], acc[3]);
        acc[3] = fdot2f(wa, mr3[k2], acc[3]);
    }
    #pragma unroll
    for (int k = 0; k < 6; ++k) {
        const float w = sWstr[k * D + j];
        acc[0] += (float)hall[ln0 + 0][k] * w;
        acc[1] += (float)hall[ln0 + 1][k] * w;
        acc[2] += (float)hall[ln0 + 2][k] * w;
        acc[3] += (float)hall[ln0 + 3][k] * w;
    }

    float pre[4], mu[4], vv[4];
    #pragma unroll
    for (int m = 0; m < 4; ++m)
        pre[m] = fmaxf(acc[m], 0.f) + (float)hall[ln0 + m][j];

    #pragma unroll
    for (int m = 0; m < 4; ++m) mu[m] = pre[m];
    #pragma unroll
    for (int off = 32; off >= 1; off >>= 1) {
        #pragma unroll
        for (int m = 0; m < 4; ++m) mu[m] += __shfl_xor(mu[m], off, 64);
    }
    #pragma unroll
    for (int m = 0; m < 4; ++m) {
        mu[m] *= (1.0f / 64.0f);
        const float diff = pre[m] - mu[m];
        vv[m] = diff * diff;
    }
    #pragma unroll
    for (int off = 32; off >= 1; off >>= 1) {
        #pragma unroll
        for (int m = 0; m < 4; ++m) vv[m] += __shfl_xor(vv[m], off, 64);
    }
    #pragma unroll
    for (int m = 0; m < 4; ++m) {
        const int n = n0 + ln0 + m;
        if (n < nNodes) {
            const float diff = pre[m] - mu[m];
            out[(size_t)n * D + j] = diff * rsqrtf(vv[m] * (1.0f / 64.0f) + 1e-5f) * sG[j] + sB[j];
        }
    }
}

extern "C" void kernel_launch(void* const* d_in, const int* in_sizes, int n_in,
                              void* d_out, int out_size, void* d_ws, size_t ws_size,
                              hipStream_t stream) {
    const int* edge       = (const int*)d_in[0];
    const float* h        = (const float*)d_in[1];
    const float* W_att    = (const float*)d_in[2];
    const float* phi_w    = (const float*)d_in[3];
    const float* phi_b    = (const float*)d_in[4];
    const float* W_p      = (const float*)d_in[5];
    const float* W_pp     = (const float*)d_in[6];
    const float* fdef_w   = (const float*)d_in[7];
    const float* fdef_b   = (const float*)d_in[8];
    const float* W_self_w = (const float*)d_in[9];
    const float* W_self_b = (const float*)d_in[10];
    const float* W_A_w    = (const float*)d_in[11];
    const float* W_A_b    = (const float*)d_in[12];
    const float* W_str_w  = (const float*)d_in[13];
    const float* W_str_b  = (const float*)d_in[14];
    const float* ln_g     = (const float*)d_in[15];
    const float* ln_b     = (const float*)d_in[16];

    const int E = in_sizes[0] / 2;
    const int nNodes = in_sizes[1] / D;
    const int* srcI = edge;
    const int* tgtI = edge + E;
    const int nBkt = (nNodes + 31) / 32;
    const int L = nBkt * NB;
    const int nbNode = (nNodes + 31) / 32;

    char* ws = (char*)d_ws;
    size_t off = 0;
    auto alloc = [&](size_t bytes) { char* p = ws + off; off = (off + bytes + 255) & ~(size_t)255; return p; };

    hf*       AW16      = (hf*)      alloc((size_t)nNodes * 2 * D * 2);
    hf*       P16       = (hf*)      alloc((size_t)nNodes * D * 2);
    hf*       PP16      = (hf*)      alloc((size_t)nNodes * D * 2);
    hf*       m16       = (hf*)      alloc((size_t)nNodes * D * 2);
    float*    enpsi     = (float*)   alloc((size_t)nNodes * 4);
    int*      ghist_t   = (int*)     alloc((size_t)L * 4);
    int*      ghist_s   = (int*)     alloc((size_t)L * 4);
    int*      gsc_t     = (int*)     alloc((size_t)L * 4);
    int*      gsc_s     = (int*)     alloc((size_t)L * 4);
    unsigned* ep_t      = (unsigned*)alloc((size_t)E * 4);
    unsigned* ep_s      = (unsigned*)alloc((size_t)E * 4);
    int*      src_sorted= (int*)     alloc((size_t)E * 4);
    int*      tgt_sorted= (int*)     alloc((size_t)E * 4);
    int*      rowstart_t= (int*)     alloc(((size_t)nNodes + 1) * 4);
    int*      rowstart_s= (int*)     alloc(((size_t)nNodes + 1) * 4);
    int*      bsum      = (int*)     alloc((size_t)2 * SCAN_NB * 4);

    // K1: node_pre || bucket_hist (both directions)
    node_pre_hist_kernel<<<nbNode + 2 * NB, 512, 0, stream>>>(
        h, W_att, W_p, W_pp, phi_w, phi_b, fdef_w, fdef_b,
        tgtI, srcI, ghist_t, ghist_s,
        AW16, P16, PP16, enpsi, nNodes, nbNode, nBkt, E);

    scan_partial_kernel<<<2 * SCAN_NB, 256, 0, stream>>>(ghist_t, ghist_s, bsum, L);
    scan_bsum_kernel<<<1, 2 * SCAN_NB, 0, stream>>>(bsum);
    scan_final_kernel<<<2 * SCAN_NB, 256, 0, stream>>>(
        ghist_t, ghist_s, bsum, gsc_t, gsc_s, L);

    bucket_scatter_kernel<<<2 * NB, 256, 0, stream>>>(
        tgtI, srcI, gsc_t, gsc_s, ep_t, ep_s, nBkt, E);

    bucket_sort_s_kernel<<<nBkt, 256, 0, stream>>>(
        ep_s, gsc_s, tgt_sorted, rowstart_s, nBkt, nNodes, E);

    // K3: pass_src || t-direction sort
    pass_src_sortT_kernel<<<PS_NB + nBkt, 256, 0, stream>>>(
        rowstart_s, tgt_sorted, P16, PP16, enpsi, AW16,
        ep_t, gsc_t, src_sorted, rowstart_t, nBkt, nNodes, E);

    pass_tgt_fused_kernel<<<2048, 256, 0, stream>>>(
        rowstart_t, src_sorted, h, AW16, m16, nNodes);

    final_kernel<<<nbNode, 512, 0, stream>>>(
        h, m16, W_self_w, W_self_b, W_A_w, W_A_b,
        W_str_w, W_str_b, ln_g, ln_b, (float*)d_out, nNodes);
}

// Round 15
// 167.035 us; speedup vs baseline: 2.7964x; 1.0024x over previous
//
#include <hip/hip_runtime.h>
#include <math.h>

#define D 64
#define NB 256        // blocks per direction for bucket hist/scatter
#define SCAN_NB 256   // blocks per scan pass
#define PS_NB 2048    // pass_src blocks in fused launch

typedef _Float16 hf;
typedef _Float16 hf2 __attribute__((ext_vector_type(2)));

__device__ inline float fdot2f(hf2 a, hf2 b, float c) {
#if __has_builtin(__builtin_amdgcn_fdot2)
    return __builtin_amdgcn_fdot2(a, b, c, false);
#else
    return (float)a[0] * (float)b[0] + (float)a[1] * (float)b[1] + c;
#endif
}

// ---------------- K1: node_pre (4 nodes/thread) FUSED with bucket_hist (LDS union) ----------------
__global__ __launch_bounds__(512) void node_pre_hist_kernel(
    const float* __restrict__ h,
    const float* __restrict__ W_att,
    const float* __restrict__ W_p,
    const float* __restrict__ W_pp,
    const float* __restrict__ phi_w,
    const float* __restrict__ phi_b,
    const float* __restrict__ fdef_w,
    const float* __restrict__ fdef_b,
    const int* __restrict__ tgtI, const int* __restrict__ srcI,
    int* __restrict__ ghist_t, int* __restrict__ ghist_s,
    hf* __restrict__ AW16,
    hf* __restrict__ P16,
    hf* __restrict__ PP16,
    float* __restrict__ enpsi,
    int nNodes, int nbNode, int nBkt, int nEdges)
{
    // hist branch aliases the node_pre weight storage (block-disjoint branches)
    union SMem {
        struct {
            hf2 sW2[4][32][D];       // 32 KB
            hf  hall[32][D];         // 4 KB
            float sPhib[D];
            float sFdef[D];
        } np;
        int hist[2048];              // 8 KB
    };
    __shared__ SMem sm;

    const int tid = threadIdx.x;

    if (blockIdx.x >= nbNode) {
        // ---------------- bucket_hist branch ----------------
        const int hb = blockIdx.x - nbNode;
        const int dir = hb / NB;
        const int b = hb % NB;
        const int* keys = dir ? srcI : tgtI;
        int* gh = dir ? ghist_s : ghist_t;
        for (int d = tid; d < nBkt; d += 512) sm.hist[d] = 0;
        __syncthreads();
        const int C = (nEdges + NB - 1) / NB;
        const int beg = b * C;
        const int end = min(beg + C, nEdges);
        for (int e = beg + tid; e < end; e += 512)
            atomicAdd(&sm.hist[keys[e] >> 5], 1);
        __syncthreads();
        for (int d = tid; d < nBkt; d += 512)
            gh[(size_t)d * NB + b] = sm.hist[d];
        return;
    }

    // ---------------- node_pre branch ----------------
    const float* Wm[4] = { W_att, W_p, W_pp, phi_w };
    for (int idx = tid; idx < 4 * 32 * D; idx += 512) {
        const int m  = idx >> 11;
        const int k2 = (idx >> 6) & 31;
        const int j  = idx & 63;
        sm.np.sW2[m][k2][j] = hf2{(hf)Wm[m][(2 * k2) * D + j], (hf)Wm[m][(2 * k2 + 1) * D + j]};
    }
    if (tid < D) { sm.np.sPhib[tid] = phi_b[tid]; sm.np.sFdef[tid] = fdef_w[tid]; }
    __syncthreads();
    const float fb = fdef_b[0];

    const int n0 = blockIdx.x * 32;
    {
        const int base = tid * 4;
        const int ln = base >> 6;
        const int col = base & 63;
        const int n = n0 + ln;
        float ps = 0.f;
        if (n < nNodes) {
            const float4 v = *(const float4*)(h + (size_t)n * D + col);
            sm.np.hall[ln][col]     = (hf)v.x;
            sm.np.hall[ln][col + 1] = (hf)v.y;
            sm.np.hall[ln][col + 2] = (hf)v.z;
            sm.np.hall[ln][col + 3] = (hf)v.w;
            ps = v.x * sm.np.sFdef[col] + v.y * sm.np.sFdef[col + 1]
               + v.z * sm.np.sFdef[col + 2] + v.w * sm.np.sFdef[col + 3];
        }
        #pragma unroll
        for (int off = 8; off >= 1; off >>= 1) ps += __shfl_xor(ps, off, 64);
        if ((tid & 15) == 0 && n < nNodes) enpsi[n] = __expf(-(ps + fb));
    }
    __syncthreads();

    const int g = tid >> 6;
    const int j = tid & 63;
    const int ln0 = 4 * g;

    float acc[4][4];
    #pragma unroll
    for (int m = 0; m < 4; ++m) {
        acc[m][0] = 0.f; acc[m][1] = 0.f; acc[m][2] = 0.f; acc[m][3] = sm.np.sPhib[j];
    }
    const hf2* hr0 = (const hf2*)sm.np.hall[ln0 + 0];
    const hf2* hr1 = (const hf2*)sm.np.hall[ln0 + 1];
    const hf2* hr2 = (const hf2*)sm.np.hall[ln0 + 2];
    const hf2* hr3 = (const hf2*)sm.np.hall[ln0 + 3];

    #pragma unroll 8
    for (int k2 = 0; k2 < 32; ++k2) {
        const hf2 w0 = sm.np.sW2[0][k2][j];
        const hf2 w1 = sm.np.sW2[1][k2][j];
        const hf2 w2 = sm.np.sW2[2][k2][j];
        const hf2 w3 = sm.np.sW2[3][k2][j];
        const hf2 h0 = hr0[k2];
        const hf2 h1 = hr1[k2];
        const hf2 h2 = hr2[k2];
        const hf2 h3 = hr3[k2];
        acc[0][0] = fdot2f(w0, h0, acc[0][0]);
        acc[0][1] = fdot2f(w1, h0, acc[0][1]);
        acc[0][2] = fdot2f(w2, h0, acc[0][2]);
        acc[0][3] = fdot2f(w3, h0, acc[0][3]);
        acc[1][0] = fdot2f(w0, h1, acc[1][0]);
        acc[1][1] = fdot2f(w1, h1, acc[1][1]);
        acc[1][2] = fdot2f(w2, h1, acc[1][2]);
        acc[1][3] = fdot2f(w3, h1, acc[1][3]);
        acc[2][0] = fdot2f(w0, h2, acc[2][0]);
        acc[2][1] = fdot2f(w1, h2, acc[2][1]);
        acc[2][2] = fdot2f(w2, h2, acc[2][2]);
        acc[2][3] = fdot2f(w3, h2, acc[2][3]);
        acc[3][0] = fdot2f(w0, h3, acc[3][0]);
        acc[3][1] = fdot2f(w1, h3, acc[3][1]);
        acc[3][2] = fdot2f(w2, h3, acc[3][2]);
        acc[3][3] = fdot2f(w3, h3, acc[3][3]);
    }

    #pragma unroll
    for (int m = 0; m < 4; ++m) {
        const int n = n0 + ln0 + m;
        if (n < nNodes) {
            float a = acc[m][0];
            if (j < 6) a += (float)sm.np.hall[ln0 + m][j];
            const size_t base = (size_t)n * D + j;
            *(hf2*)(AW16 + ((size_t)n << 7) + 2 * j) = hf2{(hf)a, (hf)acc[m][3]};
            P16[base]  = (hf)acc[m][1];
            PP16[base] = (hf)acc[m][2];
        }
    }
}

// ---------------- Scan step 1 ----------------
__global__ __launch_bounds__(256) void scan_partial_kernel(
    const int* __restrict__ in_t, const int* __restrict__ in_s,
    int* __restrict__ bsum, int L)
{
    const int pass = blockIdx.x >> 8;
    const int b = blockIdx.x & (SCAN_NB - 1);
    const int* in = pass ? in_s : in_t;
    const int C = (L + SCAN_NB - 1) / SCAN_NB;
    const int K = (C + 255) / 256;
    const int base = b * C;
    const int lim = min(base + C, L);
    const int tbeg = base + threadIdx.x * K;
    const int tend = min(tbeg + K, lim);
    int tsum = 0;
    for (int i = tbeg; i < tend; ++i) tsum += in[i];
    __shared__ int red[256];
    red[threadIdx.x] = tsum;
    __syncthreads();
    for (int off = 128; off >= 1; off >>= 1) {
        if (threadIdx.x < off) red[threadIdx.x] += red[threadIdx.x + off];
        __syncthreads();
    }
    if (threadIdx.x == 0) bsum[pass * SCAN_NB + b] = red[0];
}

// ---------------- Scan step 2 ----------------
__global__ __launch_bounds__(512) void scan_bsum_kernel(int* __restrict__ bsum)
{
    __shared__ int s[2 * SCAN_NB];
    const int tid = threadIdx.x;
    const int orig = bsum[tid];
    s[tid] = orig;
    __syncthreads();
    const int seg = tid & (SCAN_NB - 1);
    for (int off = 1; off < SCAN_NB; off <<= 1) {
        const int add = (seg >= off) ? s[tid - off] : 0;
        __syncthreads();
        s[tid] += add;
        __syncthreads();
    }
    bsum[tid] = s[tid] - orig;
}

// ---------------- Scan step 3 ----------------
__global__ __launch_bounds__(256) void scan_final_kernel(
    const int* __restrict__ in_t, const int* __restrict__ in_s,
    const int* __restrict__ bsum,
    int* __restrict__ gsc_t, int* __restrict__ gsc_s, int L)
{
    const int pass = blockIdx.x >> 8;
    const int b = blockIdx.x & (SCAN_NB - 1);
    const int* in = pass ? in_s : in_t;
    int* out = pass ? gsc_s : gsc_t;
    const int C = (L + SCAN_NB - 1) / SCAN_NB;
    const int K = (C + 255) / 256;
    const int base = b * C;
    const int lim = min(base + C, L);
    const int tbeg = base + threadIdx.x * K;
    const int tend = min(tbeg + K, lim);
    int tsum = 0;
    for (int i = tbeg; i < tend; ++i) tsum += in[i];
    __shared__ int s[256];
    s[threadIdx.x] = tsum;
    __syncthreads();
    for (int off = 1; off < 256; off <<= 1) {
        const int add = (threadIdx.x >= off) ? s[threadIdx.x - off] : 0;
        __syncthreads();
        s[threadIdx.x] += add;
        __syncthreads();
    }
    int run = s[threadIdx.x] - tsum + bsum[pass * SCAN_NB + b];
    for (int i = tbeg; i < tend; ++i) { out[i] = run; run += in[i]; }
}

// ---------------- Bucket scatter ----------------
__global__ __launch_bounds__(256) void bucket_scatter_kernel(
    const int* __restrict__ tgtI, const int* __restrict__ srcI,
    const int* __restrict__ gsc_t, const int* __restrict__ gsc_s,
    unsigned* __restrict__ ep_t, unsigned* __restrict__ ep_s,
    int nBkt, int nEdges)
{
    __shared__ int cursor[2048];
    const int dir = blockIdx.x / NB;
    const int b = blockIdx.x % NB;
    const int* keys = dir ? srcI : tgtI;
    const int* pays = dir ? tgtI : srcI;
    const int* gsc = dir ? gsc_s : gsc_t;
    unsigned* ep = dir ? ep_s : ep_t;
    const int tid = threadIdx.x;
    for (int d = tid; d < nBkt; d += 256) cursor[d] = gsc[(size_t)d * NB + b];
    __syncthreads();
    const int C = (nEdges + NB - 1) / NB;
    const int beg = b * C;
    const int end = min(beg + C, nEdges);
    for (int e = beg + tid; e < end; e += 256) {
        const unsigned k = (unsigned)keys[e];
        const unsigned p = (unsigned)pays[e];
        const int pos = atomicAdd(&cursor[k >> 5], 1);
        ep[pos] = (k << 16) | p;
    }
}

// ---------------- Per-bucket counting sort body ----------------
__device__ inline void bucket_sort_body(
    const unsigned* __restrict__ ep, const int* __restrict__ gsc,
    int* __restrict__ out, int* __restrict__ rowstart,
    int b, int nBkt, int nNodes, int nEdges,
    int* hist, int* pref, int* cur, int tid)
{
    if (b == 0 && tid == 0) rowstart[nNodes] = nEdges;

    const int s = gsc[(size_t)b * NB];
    const int e = (b + 1 < nBkt) ? gsc[(size_t)(b + 1) * NB] : nEdges;
    const int size = e - s;

    if (tid < 32) hist[tid] = 0;
    __syncthreads();
    for (int i = tid; i < size; i += 256)
        atomicAdd(&hist[(ep[s + i] >> 16) & 31], 1);
    __syncthreads();
    if (tid == 0) {
        int r = 0;
        for (int k = 0; k < 32; ++k) { pref[k] = r; cur[k] = r; r += hist[k]; }
    }
    __syncthreads();
    if (tid < 32) {
        const int key = (b << 5) + tid;
        if (key < nNodes) rowstart[key] = s + pref[tid];
    }
    __syncthreads();
    for (int i = tid; i < size; i += 256) {
        const unsigned v = ep[s + i];
        const int pos = atomicAdd(&cur[(v >> 16) & 31], 1);
        out[s + pos] = (int)(v & 0xFFFFu);
    }
}

// ---------------- Solo s-direction sort ----------------
__global__ __launch_bounds__(256) void bucket_sort_s_kernel(
    const unsigned* __restrict__ ep_s, const int* __restrict__ gsc_s,
    int* __restrict__ tgt_sorted, int* __restrict__ rowstart_s,
    int nBkt, int nNodes, int nEdges)
{
    __shared__ int hist[32], pref[32], cur[32];
    bucket_sort_body(ep_s, gsc_s, tgt_sorted, rowstart_s,
                     blockIdx.x, nBkt, nNodes, nEdges, hist, pref, cur, threadIdx.x);
}

// ---------------- K3: pass_src (8-deep) FUSED with t-direction sort ----------------
__global__ __launch_bounds__(256) void pass_src_sortT_kernel(
    const int* __restrict__ rowstart_s,
    const int* __restrict__ tgt_sorted,
    const hf* __restrict__ P16,
    const hf* __restrict__ PP16,
    const float* __restrict__ enpsi,
    hf* __restrict__ AW16,
    const unsigned* __restrict__ ep_t, const int* __restrict__ gsc_t,
    int* __restrict__ src_sorted, int* __restrict__ rowstart_t,
    int nBkt, int nNodes, int nEdges)
{
    __shared__ int hist[32], pref[32], cur[32];
    const int tid = threadIdx.x;

    if (blockIdx.x >= PS_NB) {
        bucket_sort_body(ep_t, gsc_t, src_sorted, rowstart_t,
                         blockIdx.x - PS_NB, nBkt, nNodes, nEdges, hist, pref, cur, tid);
        return;
    }

    const int grp = tid >> 4;
    const int l = tid & 15;

    for (int n = blockIdx.x * 16 + grp; n < nNodes; n += PS_NB * 16) {
        const int beg = rowstart_s[n];
        const int end = rowstart_s[n + 1];
        const float2 pr = ((const float2*)(P16 + (size_t)n * D))[l];
        const hf* pq = (const hf*)&pr;
        const float p0 = pq[0], p1 = pq[1], p2 = pq[2], p3 = pq[3];
        float bden = 0.f, ssum = 0.f;

        int k = beg;
        for (; k + 7 < end; k += 8) {
            int tv[8]; float2 rv[8]; float ev[8];
            #pragma unroll
            for (int u = 0; u < 8; ++u) tv[u] = tgt_sorted[k + u];
            #pragma unroll
            for (int u = 0; u < 8; ++u) rv[u] = ((const float2*)(PP16 + (size_t)tv[u] * D))[l];
            #pragma unroll
            for (int u = 0; u < 8; ++u) ev[u] = enpsi[tv[u]];
            float sc[8];
            #pragma unroll
            for (int u = 0; u < 8; ++u) {
                const hf* q = (const hf*)&rv[u];
                sc[u] = (float)q[0] * p0 + (float)q[1] * p1 + (float)q[2] * p2 + (float)q[3] * p3;
            }
            #pragma unroll
            for (int off = 8; off >= 1; off >>= 1) {
                #pragma unroll
                for (int u = 0; u < 8; ++u) sc[u] += __shfl_xor(sc[u], off, 64);
            }
            #pragma unroll
            for (int u = 0; u < 8; ++u) {
                const float bn = __expf(sc[u]);
                bden += bn;
                ssum += bn * ev[u];
            }
        }
        for (; k + 3 < end; k += 4) {
            int tv[4]; float2 rv[4]; float ev[4];
            #pragma unroll
            for (int u = 0; u < 4; ++u) tv[u] = tgt_sorted[k + u];
            #pragma unroll
            for (int u = 0; u < 4; ++u) rv[u] = ((const float2*)(PP16 + (size_t)tv[u] * D))[l];
            #pragma unroll
            for (int u = 0; u < 4; ++u) ev[u] = enpsi[tv[u]];
            float sc[4];
            #pragma unroll
            for (int u = 0; u < 4; ++u) {
                const hf* q = (const hf*)&rv[u];
                sc[u] = (float)q[0] * p0 + (float)q[1] * p1 + (float)q[2] * p2 + (float)q[3] * p3;
            }
            #pragma unroll
            for (int off = 8; off >= 1; off >>= 1) {
                #pragma unroll
                for (int u = 0; u < 4; ++u) sc[u] += __shfl_xor(sc[u], off, 64);
            }
            #pragma unroll
            for (int u = 0; u < 4; ++u) {
                const float bn = __expf(sc[u]);
                bden += bn;
                ssum += bn * ev[u];
            }
        }
        for (; k < end; ++k) {
            const int t = tgt_sorted[k];
            const float2 r = ((const float2*)(PP16 + (size_t)t * D))[l];
            const float et = enpsi[t];
            const hf* q = (const hf*)&r;
            float a2 = (float)q[0] * p0 + (float)q[1] * p1 + (float)q[2] * p2 + (float)q[3] * p3;
            #pragma unroll
            for (int off = 8; off >= 1; off >>= 1) a2 += __shfl_xor(a2, off, 64);
            const float bn = __expf(a2);
            bden += bn;
            ssum += bn * et;
        }
        const float st = ssum / (bden + 1e-9f);
        const float d = -logf(st + 1e-8f);
        const float w = 1.0f - 1.0f / (1.0f + __expf(-(d - 0.5f)));
        float4* rowp = (float4*)(AW16 + ((size_t)n << 7));
        float4 rv = rowp[l];
        hf* q = (hf*)&rv;
        q[1] = (hf)((float)q[1] * w);
        q[3] = (hf)((float)q[3] * w);
        q[5] = (hf)((float)q[5] * w);
        q[7] = (hf)((float)q[7] * w);
        rowp[l] = rv;
    }
}

// ---------------- K4: pass_tgt FUSED with final (matmul + relu + residual + LN) ----------------
__global__ __launch_bounds__(256) void pass_tgt_final_kernel(
    const int* __restrict__ rowstart_t,
    const int* __restrict__ src_sorted,
    const float* __restrict__ h,
    const hf* __restrict__ AW16,
    const float* __restrict__ W_self_w, const float* __restrict__ W_self_b,
    const float* __restrict__ W_A_w,    const float* __restrict__ W_A_b,
    const float* __restrict__ W_str_w,  const float* __restrict__ W_str_b,
    const float* __restrict__ ln_g,     const float* __restrict__ ln_b,
    float* __restrict__ out,
    int nNodes)
{
    __shared__ hf2 sWs2[32][D];     // 8 KB
    __shared__ hf2 sWa2[32][D];     // 8 KB
    __shared__ hf  sWstr[6][D];     // 768 B
    __shared__ float sBias[D], sG[D], sB[D];
    __shared__ hf hrow[16][D];      // 2 KB
    __shared__ hf mrow[16][D];      // 2 KB

    const int tid = threadIdx.x;
    for (int idx = tid; idx < 32 * D; idx += 256) {
        const int k2 = idx >> 6, j = idx & 63;
        sWs2[k2][j] = hf2{(hf)W_self_w[(2 * k2) * D + j], (hf)W_self_w[(2 * k2 + 1) * D + j]};
        sWa2[k2][j] = hf2{(hf)W_A_w[(2 * k2) * D + j],    (hf)W_A_w[(2 * k2 + 1) * D + j]};
    }
    for (int i = tid; i < 6 * D; i += 256) sWstr[i >> 6][i & 63] = (hf)W_str_w[i];
    if (tid < D) {
        sBias[tid] = W_self_b[tid] + W_A_b[tid] + W_str_b[tid];
        sG[tid] = ln_g[tid];
        sB[tid] = ln_b[tid];
    }
    __syncthreads();

    const int grp = tid >> 4;
    const int l = tid & 15;
    const int j0 = 4 * l;

    for (int n = blockIdx.x * 16 + grp; n < nNodes; n += gridDim.x * 16) {
        const int beg = rowstart_t[n];
        const int end = rowstart_t[n + 1];
        const float4 htv = ((const float4*)(h + (size_t)n * D))[l];
        float aden = 0.f;
        float m0 = 0.f, m1 = 0.f, m2 = 0.f, m3 = 0.f;

        int k = beg;
        for (; k + 7 < end; k += 8) {
            int sv[8]; float4 rv[8];
            #pragma unroll
            for (int u = 0; u < 8; ++u) sv[u] = src_sorted[k + u];
            #pragma unroll
            for (int u = 0; u < 8; ++u) rv[u] = ((const float4*)(AW16 + ((size_t)sv[u] << 7)))[l];
            float sc[8];
            #pragma unroll
            for (int u = 0; u < 8; ++u) {
                const hf* q = (const hf*)&rv[u];
                sc[u] = (float)q[0] * htv.x + (float)q[2] * htv.y
                      + (float)q[4] * htv.z + (float)q[6] * htv.w;
            }
            #pragma unroll
            for (int off = 8; off >= 1; off >>= 1) {
                #pragma unroll
                for (int u = 0; u < 8; ++u) sc[u] += __shfl_xor(sc[u], off, 64);
            }
            #pragma unroll
            for (int u = 0; u < 8; ++u) {
                const float an = __expf(sc[u]);
                aden += an;
                const hf* q = (const hf*)&rv[u];
                m0 += an * (float)q[1];
                m1 += an * (float)q[3];
                m2 += an * (float)q[5];
                m3 += an * (float)q[7];
            }
        }
        for (; k + 3 < end; k += 4) {
            int sv[4]; float4 rv[4];
            #pragma unroll
            for (int u = 0; u < 4; ++u) sv[u] = src_sorted[k + u];
            #pragma unroll
            for (int u = 0; u < 4; ++u) rv[u] = ((const float4*)(AW16 + ((size_t)sv[u] << 7)))[l];
            float sc[4];
            #pragma unroll
            for (int u = 0; u < 4; ++u) {
                const hf* q = (const hf*)&rv[u];
                sc[u] = (float)q[0] * htv.x + (float)q[2] * htv.y
                      + (float)q[4] * htv.z + (float)q[6] * htv.w;
            }
            #pragma unroll
            for (int off = 8; off >= 1; off >>= 1) {
                #pragma unroll
                for (int u = 0; u < 4; ++u) sc[u] += __shfl_xor(sc[u], off, 64);
            }
            #pragma unroll
            for (int u = 0; u < 4; ++u) {
                const float an = __expf(sc[u]);
                aden += an;
                const hf* q = (const hf*)&rv[u];
                m0 += an * (float)q[1];
                m1 += an * (float)q[3];
                m2 += an * (float)q[5];
                m3 += an * (float)q[7];
            }
        }
        for (; k < end; ++k) {
            const int s = src_sorted[k];
            const float4 r = ((const float4*)(AW16 + ((size_t)s << 7)))[l];
            const hf* q = (const hf*)&r;
            float a1 = (float)q[0] * htv.x + (float)q[2] * htv.y
                     + (float)q[4] * htv.z + (float)q[6] * htv.w;
            #pragma unroll
            for (int off = 8; off >= 1; off >>= 1) a1 += __shfl_xor(a1, off, 64);
            const float an = __expf(a1);
            aden += an;
            m0 += an * (float)q[1];
            m1 += an * (float)q[3];
            m2 += an * (float)q[5];
            m3 += an * (float)q[7];
        }

        // ---- fused final: stage m,h rows in group LDS (same-wave, no barrier) ----
        const float idn = 1.0f / (aden + 1e-9f);
        {
            hf t4[4];
            t4[0] = (hf)(m0 * idn); t4[1] = (hf)(m1 * idn);
            t4[2] = (hf)(m2 * idn); t4[3] = (hf)(m3 * idn);
            *(float2*)&mrow[grp][j0] = *(const float2*)t4;
            hf h4[4];
            h4[0] = (hf)htv.x; h4[1] = (hf)htv.y; h4[2] = (hf)htv.z; h4[3] = (hf)htv.w;
            *(float2*)&hrow[grp][j0] = *(const float2*)h4;
        }

        float acc0 = sBias[j0], acc1 = sBias[j0 + 1], acc2 = sBias[j0 + 2], acc3 = sBias[j0 + 3];
        const hf2* hv = (const hf2*)hrow[grp];
        const hf2* mv = (const hf2*)mrow[grp];
        #pragma unroll 8
        for (int k2 = 0; k2 < 32; ++k2) {
            const hf2 hh = hv[k2];
            const hf2 mm = mv[k2];
            acc0 = fdot2f(sWs2[k2][j0],     hh, acc0);
            acc0 = fdot2f(sWa2[k2][j0],     mm, acc0);
            acc1 = fdot2f(sWs2[k2][j0 + 1], hh, acc1);
            acc1 = fdot2f(sWa2[k2][j0 + 1], mm, acc1);
            acc2 = fdot2f(sWs2[k2][j0 + 2], hh, acc2);
            acc2 = fdot2f(sWa2[k2][j0 + 2], mm, acc2);
            acc3 = fdot2f(sWs2[k2][j0 + 3], hh, acc3);
            acc3 = fdot2f(sWa2[k2][j0 + 3], mm, acc3);
        }
        #pragma unroll
        for (int k = 0; k < 6; ++k) {
            const float hk = (float)hrow[grp][k];
            acc0 += hk * (float)sWstr[k][j0];
            acc1 += hk * (float)sWstr[k][j0 + 1];
            acc2 += hk * (float)sWstr[k][j0 + 2];
            acc3 += hk * (float)sWstr[k][j0 + 3];
        }

        const float pre0 = fmaxf(acc0, 0.f) + htv.x;
        const float pre1 = fmaxf(acc1, 0.f) + htv.y;
        const float pre2 = fmaxf(acc2, 0.f) + htv.z;
        const float pre3 = fmaxf(acc3, 0.f) + htv.w;

        float mu = pre0 + pre1 + pre2 + pre3;
        #pragma unroll
        for (int off = 8; off >= 1; off >>= 1) mu += __shfl_xor(mu, off, 64);
        mu *= (1.0f / 64.0f);
        const float d0 = pre0 - mu, d1 = pre1 - mu, d2 = pre2 - mu, d3 = pre3 - mu;
        float vv = d0 * d0 + d1 * d1 + d2 * d2 + d3 * d3;
        #pragma unroll
        for (int off = 8; off >= 1; off >>= 1) vv += __shfl_xor(vv, off, 64);
        const float rstd = rsqrtf(vv * (1.0f / 64.0f) + 1e-5f);

        float4 o;
        o.x = d0 * rstd * sG[j0]     + sB[j0];
        o.y = d1 * rstd * sG[j0 + 1] + sB[j0 + 1];
        o.z = d2 * rstd * sG[j0 + 2] + sB[j0 + 2];
        o.w = d3 * rstd * sG[j0 + 3] + sB[j0 + 3];
        *(float4*)(out + (size_t)n * D + j0) = o;
    }
}

extern "C" void kernel_launch(void* const* d_in, const int* in_sizes, int n_in,
                              void* d_out, int out_size, void* d_ws, size_t ws_size,
                              hipStream_t stream) {
    const int* edge       = (const int*)d_in[0];
    const float* h        = (const float*)d_in[1];
    const float* W_att    = (const float*)d_in[2];
    const float* phi_w    = (const float*)d_in[3];
    const float* phi_b    = (const float*)d_in[4];
    const float* W_p      = (const float*)d_in[5];
    const float* W_pp     = (const float*)d_in[6];
    const float* fdef_w   = (const float*)d_in[7];
    const float* fdef_b   = (const float*)d_in[8];
    const float* W_self_w = (const float*)d_in[9];
    const float* W_self_b = (const float*)d_in[10];
    const float* W_A_w    = (const float*)d_in[11];
    const float* W_A_b    = (const float*)d_in[12];
    const float* W_str_w  = (const float*)d_in[13];
    const float* W_str_b  = (const float*)d_in[14];
    const float* ln_g     = (const float*)d_in[15];
    const float* ln_b     = (const float*)d_in[16];

    const int E = in_sizes[0] / 2;
    const int nNodes = in_sizes[1] / D;
    const int* srcI = edge;
    const int* tgtI = edge + E;
    const int nBkt = (nNodes + 31) / 32;
    const int L = nBkt * NB;
    const int nbNode = (nNodes + 31) / 32;

    char* ws = (char*)d_ws;
    size_t off = 0;
    auto alloc = [&](size_t bytes) { char* p = ws + off; off = (off + bytes + 255) & ~(size_t)255; return p; };

    hf*       AW16      = (hf*)      alloc((size_t)nNodes * 2 * D * 2);
    hf*       P16       = (hf*)      alloc((size_t)nNodes * D * 2);
    hf*       PP16      = (hf*)      alloc((size_t)nNodes * D * 2);
    float*    enpsi     = (float*)   alloc((size_t)nNodes * 4);
    int*      ghist_t   = (int*)     alloc((size_t)L * 4);
    int*      ghist_s   = (int*)     alloc((size_t)L * 4);
    int*      gsc_t     = (int*)     alloc((size_t)L * 4);
    int*      gsc_s     = (int*)     alloc((size_t)L * 4);
    unsigned* ep_t      = (unsigned*)alloc((size_t)E * 4);
    unsigned* ep_s      = (unsigned*)alloc((size_t)E * 4);
    int*      src_sorted= (int*)     alloc((size_t)E * 4);
    int*      tgt_sorted= (int*)     alloc((size_t)E * 4);
    int*      rowstart_t= (int*)     alloc(((size_t)nNodes + 1) * 4);
    int*      rowstart_s= (int*)     alloc(((size_t)nNodes + 1) * 4);
    int*      bsum      = (int*)     alloc((size_t)2 * SCAN_NB * 4);

    // K1: node_pre || bucket_hist (both directions)
    node_pre_hist_kernel<<<nbNode + 2 * NB, 512, 0, stream>>>(
        h, W_att, W_p, W_pp, phi_w, phi_b, fdef_w, fdef_b,
        tgtI, srcI, ghist_t, ghist_s,
        AW16, P16, PP16, enpsi, nNodes, nbNode, nBkt, E);

    scan_partial_kernel<<<2 * SCAN_NB, 256, 0, stream>>>(ghist_t, ghist_s, bsum, L);
    scan_bsum_kernel<<<1, 2 * SCAN_NB, 0, stream>>>(bsum);
    scan_final_kernel<<<2 * SCAN_NB, 256, 0, stream>>>(
        ghist_t, ghist_s, bsum, gsc_t, gsc_s, L);

    bucket_scatter_kernel<<<2 * NB, 256, 0, stream>>>(
        tgtI, srcI, gsc_t, gsc_s, ep_t, ep_s, nBkt, E);

    bucket_sort_s_kernel<<<nBkt, 256, 0, stream>>>(
        ep_s, gsc_s, tgt_sorted, rowstart_s, nBkt, nNodes, E);

    // K3: pass_src || t-direction sort
    pass_src_sortT_kernel<<<PS_NB + nBkt, 256, 0, stream>>>(
        rowstart_s, tgt_sorted, P16, PP16, enpsi, AW16,
        ep_t, gsc_t, src_sorted, rowstart_t, nBkt, nNodes, E);

    // K4: pass_tgt + final fused
    pass_tgt_final_kernel<<<2048, 256, 0, stream>>>(
        rowstart_t, src_sorted, h, AW16,
        W_self_w, W_self_b, W_A_w, W_A_b, W_str_w, W_str_b,
        ln_g, ln_b, (float*)d_out, nNodes);
}